// Round 4
// baseline (1586.155 us; speedup 1.0000x reference)
//
#include <hip/hip_runtime.h>
#include <hip/hip_bf16.h>
#include <math.h>

// Geometry (fixed):
//   x: (N=4, C=64, D=32, H=64, W=64); S = 131072 = G*P, G=512, P=256
//   W1 (128,64) b1(128) | W2 (512,512) b2(512) | W3 (256,256) b3(256) | W4 (64,128) b4(64)
// Blocked index: g=(d>>2)*64+(h>>3)*8+(w>>3); p=(d&3)*64+(h&7)*8+(w&7)
//
// Device dtype (bf16 vs fp32) is DETECTED at runtime (k_detect) and stored as a
// flag in ws; all external loads/stores branch uniformly on it. Internal
// intermediates are always bf16.
//
// Workspace layout (ask = 8192 B + 32 MiB = 33.6 MB):
//   float[0..8)   : LN stats (sum,sumsq) per n
//   float[8]      : dtype flag (0=bf16, 1=fp32)
//   float[16..1040): 512x2 LN partials
//   byte 8192     : A (64,512,256) bf16, 16 MiB  (M_u, later overwritten by V)
//   byte 8192+16M : C (64,512,256) bf16, 16 MiB  (U)
// B (M_v, 16 MiB) lives in d_out's sample-n region (dead before k_fc2 writes it).

#define S_PER_N 131072
#define CNT_PER_N 8388608.0f

__device__ __forceinline__ float b2f(unsigned short u) {
    return __uint_as_float(((unsigned int)u) << 16);
}
__device__ __forceinline__ unsigned short f2b(float f) {
    unsigned int i = __float_as_uint(f);
    unsigned int r = i + 0x7FFFu + ((i >> 16) & 1u);
    return (unsigned short)(r >> 16);
}
__device__ __forceinline__ float loadIn(const void* p, long i, bool f32) {
    return f32 ? ((const float*)p)[i] : b2f(((const unsigned short*)p)[i]);
}
__device__ __forceinline__ void storeOut(void* p, long i, float v, bool f32) {
    if (f32) ((float*)p)[i] = v;
    else ((unsigned short*)p)[i] = f2b(v);
}

// Classify device dtype from x's first 4096 16-bit words.
// bf16 N(0,1): exponent field in [110,130] for ~100% of words.
// fp32 N(0,1) viewed as u16: low halves are ~uniform -> ~54% overall.
__global__ void k_detect(const unsigned short* __restrict__ xw, float* __restrict__ flag) {
    __shared__ int sh[256];
    int tid = threadIdx.x;
    int sane = 0;
    for (int i = tid; i < 4096; i += 256) {
        int e = (xw[i] >> 7) & 0xFF;
        sane += (e >= 110 && e <= 130) ? 1 : 0;
    }
    sh[tid] = sane; __syncthreads();
    for (int off = 128; off; off >>= 1) {
        if (tid < off) sh[tid] += sh[tid + off];
        __syncthreads();
    }
    if (tid == 0) flag[0] = (sh[0] >= 3300) ? 0.0f : 1.0f;
}

// 512 blocks x 256 thr; block bid covers elements [bid*65536, (bid+1)*65536)
__global__ __launch_bounds__(256) void k_lnstats(const void* __restrict__ xp,
                                                 const float* __restrict__ flag,
                                                 float* __restrict__ partials) {
    const bool f32 = flag[0] > 0.5f;
    const int bid = blockIdx.x;
    const long base = (long)bid * 65536;
    float s = 0.0f, sq = 0.0f;
    if (f32) {
        const float4* xv = (const float4*)((const float*)xp + base);
        for (int it = 0; it < 64; ++it) {
            float4 v = xv[it * 256 + threadIdx.x];
            s  += v.x + v.y + v.z + v.w;
            sq += v.x*v.x + v.y*v.y + v.z*v.z + v.w*v.w;
        }
    } else {
        const uint4* xv = (const uint4*)((const unsigned short*)xp + base);
        for (int it = 0; it < 32; ++it) {
            uint4 v = xv[it * 256 + threadIdx.x];
            unsigned int ws4[4] = {v.x, v.y, v.z, v.w};
            #pragma unroll
            for (int q = 0; q < 4; ++q) {
                float f0 = b2f((unsigned short)(ws4[q] & 0xFFFFu));
                float f1 = b2f((unsigned short)(ws4[q] >> 16));
                s += f0 + f1;
                sq += f0 * f0 + f1 * f1;
            }
        }
    }
    __shared__ float ls[256], lq[256];
    ls[threadIdx.x] = s; lq[threadIdx.x] = sq;
    __syncthreads();
    for (int off = 128; off > 0; off >>= 1) {
        if (threadIdx.x < off) {
            ls[threadIdx.x] += ls[threadIdx.x + off];
            lq[threadIdx.x] += lq[threadIdx.x + off];
        }
        __syncthreads();
    }
    if (threadIdx.x == 0) {
        partials[bid * 2 + 0] = ls[0];
        partials[bid * 2 + 1] = lq[0];
    }
}

__global__ void k_lnreduce(const float* __restrict__ partials, float* __restrict__ stats) {
    const int t = threadIdx.x;
    if (t < 4) {
        float s = 0.0f, sq = 0.0f;
        for (int i = 0; i < 128; ++i) {
            s  += partials[(t * 128 + i) * 2 + 0];
            sq += partials[(t * 128 + i) * 2 + 1];
        }
        stats[t * 2 + 0] = s;
        stats[t * 2 + 1] = sq;
    }
}

// LN + FC1(64->128) + exact GELU for sample n; ch 0..63 -> A (ws), 64..127 -> B (out region n)
__global__ __launch_bounds__(256) void k_ln_fc1_gelu(const void* __restrict__ xp,
                                                     const float* __restrict__ stats,
                                                     const float* __restrict__ flag,
                                                     const void* __restrict__ W1,
                                                     const void* __restrict__ b1,
                                                     unsigned short* __restrict__ A,
                                                     void* __restrict__ outBase,
                                                     int n) {
    const bool f32 = flag[0] > 0.5f;
    __shared__ float W1s[128 * 64];
    __shared__ float b1s[128];
    for (int i = threadIdx.x; i < 128 * 64; i += 256) W1s[i] = loadIn(W1, i, f32);
    if (threadIdx.x < 128) b1s[threadIdx.x] = loadIn(b1, threadIdx.x, f32);
    __syncthreads();

    unsigned short* B = (unsigned short*)((char*)outBase + (size_t)n * 8388608 * (f32 ? 4 : 2));

    const int s = blockIdx.x * 256 + threadIdx.x;
    const int d = s >> 12, h = (s >> 6) & 63, w = s & 63;

    const float mu   = stats[n * 2 + 0] * (1.0f / CNT_PER_N);
    const float m2   = stats[n * 2 + 1] * (1.0f / CNT_PER_N);
    const float rstd = rsqrtf(m2 - mu * mu + 1e-5f);

    float xh[64];
    #pragma unroll
    for (int c = 0; c < 64; ++c) {
        float v = loadIn(xp, ((long)(n * 64 + c) << 17) + s, f32);
        xh[c] = (v - mu) * rstd;
    }

    const int g = ((d >> 2) << 6) | ((h >> 3) << 3) | (w >> 3);
    const int p = ((d & 3) << 6) | ((h & 7) << 3) | (w & 7);
    const int gp = g * 256 + p;

    for (int k = 0; k < 128; ++k) {
        float acc = b1s[k];
        const float4* wr = (const float4*)&W1s[k * 64];
        #pragma unroll
        for (int c4 = 0; c4 < 16; ++c4) {
            float4 wv = wr[c4];
            acc += wv.x * xh[c4 * 4 + 0] + wv.y * xh[c4 * 4 + 1]
                 + wv.z * xh[c4 * 4 + 2] + wv.w * xh[c4 * 4 + 3];
        }
        float ge = 0.5f * acc * (1.0f + erff(acc * 0.70710678118654752440f));
        unsigned short r = f2b(ge);
        if (k < 64) A[((long)k << 17) + gp] = r;
        else        B[((long)(k - 64) << 17) + gp] = r;
    }
}

// u-mix: per channel c, U[k,p] = sum_g W2[k,g] * A_c[g,p] + b2[k]  -> C
__global__ __launch_bounds__(256) void k_umix(const unsigned short* __restrict__ A,
                                              const void* __restrict__ W2,
                                              const void* __restrict__ b2,
                                              const float* __restrict__ flag,
                                              unsigned short* __restrict__ C) {
    const bool f32 = flag[0] > 0.5f;
    __shared__ float As[64][17];
    __shared__ float Bs[16][64];
    const int bid = blockIdx.x;
    const int c = bid >> 5;
    const int tile = bid & 31;
    const int k0 = (tile >> 2) * 64;
    const int p0 = (tile & 3) * 64;
    const unsigned short* M = A + ((long)c << 17);
    unsigned short* O = C + ((long)c << 17);
    const int tx = threadIdx.x & 15, ty = threadIdx.x >> 4;

    float acc[4][4] = {};
    for (int kb = 0; kb < 512; kb += 16) {
        {
            int t4 = threadIdx.x * 4;
            int row = t4 >> 4, col = t4 & 15;
            long off = (long)(k0 + row) * 512 + kb + col;
            #pragma unroll
            for (int q = 0; q < 4; ++q) As[row][col + q] = loadIn(W2, off + q, f32);
        }
        {
            int kk = threadIdx.x >> 4, j = (threadIdx.x & 15) * 4;
            const unsigned short* src = &M[(kb + kk) * 256 + p0 + j];
            Bs[kk][j + 0] = b2f(src[0]); Bs[kk][j + 1] = b2f(src[1]);
            Bs[kk][j + 2] = b2f(src[2]); Bs[kk][j + 3] = b2f(src[3]);
        }
        __syncthreads();
        #pragma unroll
        for (int kk = 0; kk < 16; ++kk) {
            float a[4], b[4];
            #pragma unroll
            for (int i = 0; i < 4; ++i) a[i] = As[ty * 4 + i][kk];
            #pragma unroll
            for (int j = 0; j < 4; ++j) b[j] = Bs[kk][tx * 4 + j];
            #pragma unroll
            for (int i = 0; i < 4; ++i)
                #pragma unroll
                for (int j = 0; j < 4; ++j) acc[i][j] += a[i] * b[j];
        }
        __syncthreads();
    }
    #pragma unroll
    for (int i = 0; i < 4; ++i) {
        float bias = loadIn(b2, k0 + ty * 4 + i, f32);
        #pragma unroll
        for (int j = 0; j < 4; ++j)
            O[(k0 + ty * 4 + i) * 256 + p0 + tx * 4 + j] = f2b(acc[i][j] + bias);
    }
}

// v-mix: per channel c, V[g,k] = sum_p B_c[g,p] * W3[k,p] + b3[k]  -> overwrites A
__global__ __launch_bounds__(256) void k_vmix(void* __restrict__ outBase,
                                              const void* __restrict__ W3,
                                              const void* __restrict__ b3,
                                              const float* __restrict__ flag,
                                              unsigned short* __restrict__ A,
                                              int n) {
    const bool f32 = flag[0] > 0.5f;
    __shared__ float Ms[64][17];
    __shared__ float Ws[64][17];
    const int bid = blockIdx.x;
    const int c = bid >> 5;
    const int tile = bid & 31;
    const int g0 = (tile >> 2) * 64;
    const int k0 = (tile & 3) * 64;
    const unsigned short* Bbuf = (const unsigned short*)((char*)outBase + (size_t)n * 8388608 * (f32 ? 4 : 2));
    const unsigned short* M = Bbuf + ((long)c << 17);
    unsigned short* O = A + ((long)c << 17);
    const int tx = threadIdx.x & 15, ty = threadIdx.x >> 4;

    float acc[4][4] = {};
    for (int pb = 0; pb < 256; pb += 16) {
        {
            int t4 = threadIdx.x * 4;
            int row = t4 >> 4, col = t4 & 15;
            const unsigned short* src = &M[(g0 + row) * 256 + pb + col];
            Ms[row][col + 0] = b2f(src[0]); Ms[row][col + 1] = b2f(src[1]);
            Ms[row][col + 2] = b2f(src[2]); Ms[row][col + 3] = b2f(src[3]);
            long off = (long)(k0 + row) * 256 + pb + col;
            #pragma unroll
            for (int q = 0; q < 4; ++q) Ws[row][col + q] = loadIn(W3, off + q, f32);
        }
        __syncthreads();
        #pragma unroll
        for (int kk = 0; kk < 16; ++kk) {
            float a[4], b[4];
            #pragma unroll
            for (int i = 0; i < 4; ++i) a[i] = Ms[ty * 4 + i][kk];
            #pragma unroll
            for (int j = 0; j < 4; ++j) b[j] = Ws[tx * 4 + j][kk];
            #pragma unroll
            for (int i = 0; i < 4; ++i)
                #pragma unroll
                for (int j = 0; j < 4; ++j) acc[i][j] += a[i] * b[j];
        }
        __syncthreads();
    }
    #pragma unroll
    for (int i = 0; i < 4; ++i) {
        #pragma unroll
        for (int j = 0; j < 4; ++j) {
            float bias = loadIn(b3, k0 + tx * 4 + j, f32);
            O[(g0 + ty * 4 + i) * 256 + k0 + tx * 4 + j] = f2b(acc[i][j] + bias);
        }
    }
}

// final FC: concat (U from C, V from A) -> 64 ch; writes out region n (B there is dead)
__global__ __launch_bounds__(256) void k_fc2(const unsigned short* __restrict__ C,
                                             const unsigned short* __restrict__ A,
                                             const void* __restrict__ W4,
                                             const void* __restrict__ b4,
                                             const float* __restrict__ flag,
                                             void* __restrict__ out,
                                             int n) {
    const bool f32 = flag[0] > 0.5f;
    __shared__ float W4s[64 * 128];
    __shared__ float b4s[64];
    for (int i = threadIdx.x; i < 64 * 128; i += 256) W4s[i] = loadIn(W4, i, f32);
    if (threadIdx.x < 64) b4s[threadIdx.x] = loadIn(b4, threadIdx.x, f32);
    __syncthreads();

    const int s = blockIdx.x * 256 + threadIdx.x;
    const int d = s >> 12, h = (s >> 6) & 63, w = s & 63;
    const int g = ((d >> 2) << 6) | ((h >> 3) << 3) | (w >> 3);
    const int p = ((d & 3) << 6) | ((h & 7) << 3) | (w & 7);
    const int gp = g * 256 + p;

    float val[128];
    #pragma unroll
    for (int c = 0; c < 64; ++c) val[c] = b2f(C[((long)c << 17) + gp]);
    #pragma unroll
    for (int c = 0; c < 64; ++c) val[64 + c] = b2f(A[((long)c << 17) + gp]);

    for (int k = 0; k < 64; ++k) {
        float acc = b4s[k];
        const float4* wr = (const float4*)&W4s[k * 128];
        #pragma unroll
        for (int c4 = 0; c4 < 32; ++c4) {
            float4 wv = wr[c4];
            acc += wv.x * val[c4 * 4 + 0] + wv.y * val[c4 * 4 + 1]
                 + wv.z * val[c4 * 4 + 2] + wv.w * val[c4 * 4 + 3];
        }
        storeOut(out, ((long)(n * 64 + k) << 17) + s, acc, f32);
    }
}

extern "C" void kernel_launch(void* const* d_in, const int* in_sizes, int n_in,
                              void* d_out, int out_size, void* d_ws, size_t ws_size,
                              hipStream_t stream) {
    const void* x  = d_in[0];
    const void* W1 = d_in[1];
    const void* b1 = d_in[2];
    const void* W2 = d_in[3];
    const void* b2 = d_in[4];
    const void* W3 = d_in[5];
    const void* b3 = d_in[6];
    const void* W4 = d_in[7];
    const void* b4 = d_in[8];

    float* wsf      = (float*)d_ws;
    float* stats    = wsf;            // 8 floats
    float* flag     = wsf + 8;        // 1 float
    float* partials = wsf + 16;       // 1024 floats
    unsigned short* A = (unsigned short*)((char*)d_ws + 8192);
    unsigned short* C = A + (size_t)64 * 512 * 256;   // +16MiB ; total ask ~33.6MB

    hipLaunchKernelGGL(k_detect,   dim3(1),   dim3(256), 0, stream,
                       (const unsigned short*)x, flag);
    hipLaunchKernelGGL(k_lnstats,  dim3(512), dim3(256), 0, stream, x, flag, partials);
    hipLaunchKernelGGL(k_lnreduce, dim3(1),   dim3(64),  0, stream, partials, stats);

    for (int n = 0; n < 4; ++n) {
        hipLaunchKernelGGL(k_ln_fc1_gelu, dim3(512),  dim3(256), 0, stream,
                           x, stats, flag, W1, b1, A, d_out, n);
        hipLaunchKernelGGL(k_umix,        dim3(2048), dim3(256), 0, stream,
                           A, W2, b2, flag, C);
        hipLaunchKernelGGL(k_vmix,        dim3(2048), dim3(256), 0, stream,
                           d_out, W3, b3, flag, A, n);
        hipLaunchKernelGGL(k_fc2,         dim3(512),  dim3(256), 0, stream,
                           C, A, W4, b4, flag, d_out, n);
    }
}

// Round 5
// 902.861 us; speedup vs baseline: 1.7568x; 1.7568x over previous
//
#include <hip/hip_runtime.h>
#include <hip/hip_bf16.h>
#include <math.h>

// Geometry (fixed):
//   x: (N=4, C=64, D=32, H=64, W=64); S = 131072 = G*P, G=512, P=256
//   W1 (128,64) b1(128) | W2 (512,512) b2(512) | W3 (256,256) b3(256) | W4 (64,128) b4(64)
// Blocked index: g=(d>>2)*64+(h>>3)*8+(w>>3); p=(d&3)*64+(h&7)*8+(w&7)
//
// Device dtype (bf16 vs fp32) detected at runtime (k_detect); external loads/
// stores branch uniformly on it. Intermediates always bf16.
//
// Per-sample dataflow (ws ask = 8192 B + 32 MiB, proven OK in round 3):
//   fc1:   x -> A (u-part, [c][g*256+p])  +  d_out region n (v-part, [c][g*256+p])
//   trans: A -> C ([c][p*512+g])          (A dead)
//   umix:  W2 x C -> A  (U, [c][k*256+p]) (C dead)   MFMA GEMM M=512 N=16384 K=512
//   vmix:  B2 x W3^T -> C (V, [c][g*256+k]) (B dead) MFMA GEMM M=32768 N=256 K=256
//   fc2:   A,C -> d_out region n

#define S_PER_N 131072
#define CNT_PER_N 8388608.0f

typedef __attribute__((ext_vector_type(8))) short bf16x8;
typedef __attribute__((ext_vector_type(4))) float f32x4;

__device__ __forceinline__ float b2f(unsigned short u) {
    return __uint_as_float(((unsigned int)u) << 16);
}
__device__ __forceinline__ unsigned short f2b(float f) {
    unsigned int i = __float_as_uint(f);
    unsigned int r = i + 0x7FFFu + ((i >> 16) & 1u);
    return (unsigned short)(r >> 16);
}
__device__ __forceinline__ float loadIn(const void* p, long i, bool f32) {
    return f32 ? ((const float*)p)[i] : b2f(((const unsigned short*)p)[i]);
}
__device__ __forceinline__ void storeOut(void* p, long i, float v, bool f32) {
    if (f32) ((float*)p)[i] = v;
    else ((unsigned short*)p)[i] = f2b(v);
}

// ---------------- dtype detect + LN stats (unchanged, proven) ----------------

__global__ void k_detect(const unsigned short* __restrict__ xw, float* __restrict__ flag) {
    __shared__ int sh[256];
    int tid = threadIdx.x;
    int sane = 0;
    for (int i = tid; i < 4096; i += 256) {
        int e = (xw[i] >> 7) & 0xFF;
        sane += (e >= 110 && e <= 130) ? 1 : 0;
    }
    sh[tid] = sane; __syncthreads();
    for (int off = 128; off; off >>= 1) {
        if (tid < off) sh[tid] += sh[tid + off];
        __syncthreads();
    }
    if (tid == 0) flag[0] = (sh[0] >= 3300) ? 0.0f : 1.0f;
}

__global__ __launch_bounds__(256) void k_lnstats(const void* __restrict__ xp,
                                                 const float* __restrict__ flag,
                                                 float* __restrict__ partials) {
    const bool f32 = flag[0] > 0.5f;
    const int bid = blockIdx.x;
    const long base = (long)bid * 65536;
    float s = 0.0f, sq = 0.0f;
    if (f32) {
        const float4* xv = (const float4*)((const float*)xp + base);
        for (int it = 0; it < 64; ++it) {
            float4 v = xv[it * 256 + threadIdx.x];
            s  += v.x + v.y + v.z + v.w;
            sq += v.x*v.x + v.y*v.y + v.z*v.z + v.w*v.w;
        }
    } else {
        const uint4* xv = (const uint4*)((const unsigned short*)xp + base);
        for (int it = 0; it < 32; ++it) {
            uint4 v = xv[it * 256 + threadIdx.x];
            unsigned int ws4[4] = {v.x, v.y, v.z, v.w};
            #pragma unroll
            for (int q = 0; q < 4; ++q) {
                float f0 = b2f((unsigned short)(ws4[q] & 0xFFFFu));
                float f1 = b2f((unsigned short)(ws4[q] >> 16));
                s += f0 + f1;
                sq += f0 * f0 + f1 * f1;
            }
        }
    }
    __shared__ float ls[256], lq[256];
    ls[threadIdx.x] = s; lq[threadIdx.x] = sq;
    __syncthreads();
    for (int off = 128; off > 0; off >>= 1) {
        if (threadIdx.x < off) {
            ls[threadIdx.x] += ls[threadIdx.x + off];
            lq[threadIdx.x] += lq[threadIdx.x + off];
        }
        __syncthreads();
    }
    if (threadIdx.x == 0) {
        partials[bid * 2 + 0] = ls[0];
        partials[bid * 2 + 1] = lq[0];
    }
}

__global__ void k_lnreduce(const float* __restrict__ partials, float* __restrict__ stats) {
    const int t = threadIdx.x;
    if (t < 4) {
        float s = 0.0f, sq = 0.0f;
        for (int i = 0; i < 128; ++i) {
            s  += partials[(t * 128 + i) * 2 + 0];
            sq += partials[(t * 128 + i) * 2 + 1];
        }
        stats[t * 2 + 0] = s;
        stats[t * 2 + 1] = sq;
    }
}

// ---------------- FC1 (unchanged, proven) ----------------

__global__ __launch_bounds__(256) void k_ln_fc1_gelu(const void* __restrict__ xp,
                                                     const float* __restrict__ stats,
                                                     const float* __restrict__ flag,
                                                     const void* __restrict__ W1,
                                                     const void* __restrict__ b1,
                                                     unsigned short* __restrict__ A,
                                                     void* __restrict__ outBase,
                                                     int n) {
    const bool f32 = flag[0] > 0.5f;
    __shared__ float W1s[128 * 64];
    __shared__ float b1s[128];
    for (int i = threadIdx.x; i < 128 * 64; i += 256) W1s[i] = loadIn(W1, i, f32);
    if (threadIdx.x < 128) b1s[threadIdx.x] = loadIn(b1, threadIdx.x, f32);
    __syncthreads();

    unsigned short* B = (unsigned short*)((char*)outBase + (size_t)n * 8388608 * (f32 ? 4 : 2));

    const int s = blockIdx.x * 256 + threadIdx.x;
    const int d = s >> 12, h = (s >> 6) & 63, w = s & 63;

    const float mu   = stats[n * 2 + 0] * (1.0f / CNT_PER_N);
    const float m2   = stats[n * 2 + 1] * (1.0f / CNT_PER_N);
    const float rstd = rsqrtf(m2 - mu * mu + 1e-5f);

    float xh[64];
    #pragma unroll
    for (int c = 0; c < 64; ++c) {
        float v = loadIn(xp, ((long)(n * 64 + c) << 17) + s, f32);
        xh[c] = (v - mu) * rstd;
    }

    const int g = ((d >> 2) << 6) | ((h >> 3) << 3) | (w >> 3);
    const int p = ((d & 3) << 6) | ((h & 7) << 3) | (w & 7);
    const int gp = g * 256 + p;

    for (int k = 0; k < 128; ++k) {
        float acc = b1s[k];
        const float4* wr = (const float4*)&W1s[k * 64];
        #pragma unroll
        for (int c4 = 0; c4 < 16; ++c4) {
            float4 wv = wr[c4];
            acc += wv.x * xh[c4 * 4 + 0] + wv.y * xh[c4 * 4 + 1]
                 + wv.z * xh[c4 * 4 + 2] + wv.w * xh[c4 * 4 + 3];
        }
        float ge = 0.5f * acc * (1.0f + erff(acc * 0.70710678118654752440f));
        unsigned short r = f2b(ge);
        if (k < 64) A[((long)k << 17) + gp] = r;
        else        B[((long)(k - 64) << 17) + gp] = r;
    }
}

// ---------------- transpose A[c][g][p] -> At[c][p][g] ----------------
// 2048 blocks/sample: bid = c*32 + gt*4 + pt; 64x64 tile via LDS.
__global__ __launch_bounds__(256) void k_transA(const unsigned short* __restrict__ A,
                                                unsigned short* __restrict__ At) {
    __shared__ unsigned short T[64 * 66];
    const int bid = blockIdx.x;
    const int c  = bid >> 5;
    const int gt = (bid >> 2) & 7, pt = bid & 3;
    const int g0 = gt * 64, p0 = pt * 64;
    const int t = threadIdx.x;

    const int gr = t >> 2, pc = (t & 3) * 16;
    const unsigned int* s32 = (const unsigned int*)(A + (long)c * 131072 + (long)(g0 + gr) * 256 + p0 + pc);
    unsigned int* d32 = (unsigned int*)&T[gr * 66 + pc];
    #pragma unroll
    for (int i = 0; i < 8; ++i) d32[i] = s32[i];
    __syncthreads();

    const int pr = t >> 2, gc0 = (t & 3) * 16;
    unsigned int ov[8];
    #pragma unroll
    for (int i = 0; i < 8; ++i) {
        unsigned int lo = T[(gc0 + 2 * i) * 66 + pr];
        unsigned int hi = T[(gc0 + 2 * i + 1) * 66 + pr];
        ov[i] = lo | (hi << 16);
    }
    unsigned int* dst = (unsigned int*)(At + (long)c * 131072 + (long)(p0 + pr) * 512 + g0 + gc0);
    #pragma unroll
    for (int i = 0; i < 8; ++i) dst[i] = ov[i];
}

// ---------------- MFMA GEMM helpers ----------------
// Stage one 16B chunk (8 bf16) into XOR-swizzled LDS: row r (64 bf16/row), chunk c (0..7).
__device__ __forceinline__ void stage8(unsigned short* lds, int r, int c,
                                       const void* gp, long gidx, bool f32) {
    const int dst = r * 64 + ((c ^ (r & 7)) << 3);
    uint4 v;
    if (f32) {
        const float* s = (const float*)gp + gidx;
        float4 a = *(const float4*)s;
        float4 b = *(const float4*)(s + 4);
        v.x = (unsigned int)f2b(a.x) | ((unsigned int)f2b(a.y) << 16);
        v.y = (unsigned int)f2b(a.z) | ((unsigned int)f2b(a.w) << 16);
        v.z = (unsigned int)f2b(b.x) | ((unsigned int)f2b(b.y) << 16);
        v.w = (unsigned int)f2b(b.z) | ((unsigned int)f2b(b.w) << 16);
    } else {
        v = *(const uint4*)((const unsigned short*)gp + gidx);
    }
    *(uint4*)&lds[dst] = v;
}
__device__ __forceinline__ bf16x8 fragLd(const unsigned short* lds, int r, int c) {
    return *(const bf16x8*)&lds[r * 64 + ((c ^ (r & 7)) << 3)];
}

// u-mix GEMM: D[m][n] = sum_k W2[m][k] * Bt[n][k];  M=512, N=16384, K=512 (per sample)
// Bt = At buffer viewed as [n=(c*256+p)][512 g]. Out U[c][m*256+p] += b2[m].
// grid 512: bid = mTile*128 + nTile (mTile 0..3, nTile 0..127)
__global__ __launch_bounds__(256) void k_umix_mfma(const unsigned short* __restrict__ Bt,
                                                   const void* __restrict__ W2,
                                                   const void* __restrict__ b2,
                                                   const float* __restrict__ flag,
                                                   unsigned short* __restrict__ U) {
    const bool f32 = flag[0] > 0.5f;
    __shared__ __align__(16) unsigned short As[128 * 64];
    __shared__ __align__(16) unsigned short Bs[128 * 64];
    const int bid = blockIdx.x;
    const int mTile = bid >> 7;
    const int nTile = bid & 127;
    const int m0 = mTile * 128;
    const long btBase = (long)nTile * 128 * 512;
    const int t = threadIdx.x;
    const int lane = t & 63, wid = t >> 6;
    const int waveM = (wid >> 1) * 64, waveN = (wid & 1) * 64;
    const int lr = lane & 15, lk = lane >> 4;
    const int rS = t >> 1, c0 = (t & 1) * 4;

    f32x4 zero = {0.f, 0.f, 0.f, 0.f};
    f32x4 acc[4][4];
    #pragma unroll
    for (int i = 0; i < 4; ++i)
        #pragma unroll
        for (int j = 0; j < 4; ++j) acc[i][j] = zero;

    for (int kb = 0; kb < 512; kb += 64) {
        #pragma unroll
        for (int q = 0; q < 4; ++q)
            stage8(As, rS, c0 + q, W2, (long)(m0 + rS) * 512 + kb + (c0 + q) * 8, f32);
        #pragma unroll
        for (int q = 0; q < 4; ++q)
            stage8(Bs, rS, c0 + q, Bt, btBase + (long)rS * 512 + kb + (c0 + q) * 8, false);
        __syncthreads();
        #pragma unroll
        for (int kk = 0; kk < 2; ++kk) {
            bf16x8 af[4], bfr[4];
            #pragma unroll
            for (int f = 0; f < 4; ++f) {
                af[f]  = fragLd(As, waveM + f * 16 + lr, kk * 4 + lk);
                bfr[f] = fragLd(Bs, waveN + f * 16 + lr, kk * 4 + lk);
            }
            #pragma unroll
            for (int fm = 0; fm < 4; ++fm)
                #pragma unroll
                for (int fn = 0; fn < 4; ++fn)
                    acc[fm][fn] = __builtin_amdgcn_mfma_f32_16x16x32_bf16(af[fm], bfr[fn], acc[fm][fn], 0, 0, 0);
        }
        __syncthreads();
    }

    const int c = nTile >> 1, p0 = (nTile & 1) * 128;
    #pragma unroll
    for (int fm = 0; fm < 4; ++fm) {
        #pragma unroll
        for (int fn = 0; fn < 4; ++fn) {
            const int col = waveN + fn * 16 + lr;
            #pragma unroll
            for (int i = 0; i < 4; ++i) {
                const int row = waveM + fm * 16 + lk * 4 + i;
                const float bias = loadIn(b2, m0 + row, f32);
                U[(long)c * 131072 + (long)(m0 + row) * 256 + p0 + col] = f2b(acc[fm][fn][i] + bias);
            }
        }
    }
}

// v-mix GEMM: D[m][n] = sum_k B2[m][k] * W3[n][k]; M=32768, N=256, K=256 (per sample)
// B2 = v-part (in d_out region), rows (c*512+g), K=p contiguous. Out V[m*256+n] += b3[n].
// grid 512: bid = mTile*2 + nTile (mTile 0..255, nTile 0..1)
__global__ __launch_bounds__(256) void k_vmix_mfma(void* __restrict__ outBase,
                                                   const void* __restrict__ W3,
                                                   const void* __restrict__ b3,
                                                   const float* __restrict__ flag,
                                                   unsigned short* __restrict__ V,
                                                   int n) {
    const bool f32 = flag[0] > 0.5f;
    __shared__ __align__(16) unsigned short As[128 * 64];
    __shared__ __align__(16) unsigned short Bs[128 * 64];
    const unsigned short* B2 = (const unsigned short*)((char*)outBase + (size_t)n * 8388608 * (f32 ? 4 : 2));
    const int bid = blockIdx.x;
    const int mTile = bid >> 1;
    const int nTile = bid & 1;
    const int m0 = mTile * 128;
    const int n0 = nTile * 128;
    const int t = threadIdx.x;
    const int lane = t & 63, wid = t >> 6;
    const int waveM = (wid >> 1) * 64, waveN = (wid & 1) * 64;
    const int lr = lane & 15, lk = lane >> 4;
    const int rS = t >> 1, c0 = (t & 1) * 4;

    f32x4 zero = {0.f, 0.f, 0.f, 0.f};
    f32x4 acc[4][4];
    #pragma unroll
    for (int i = 0; i < 4; ++i)
        #pragma unroll
        for (int j = 0; j < 4; ++j) acc[i][j] = zero;

    for (int kb = 0; kb < 256; kb += 64) {
        #pragma unroll
        for (int q = 0; q < 4; ++q)
            stage8(As, rS, c0 + q, B2, (long)(m0 + rS) * 256 + kb + (c0 + q) * 8, false);
        #pragma unroll
        for (int q = 0; q < 4; ++q)
            stage8(Bs, rS, c0 + q, W3, (long)(n0 + rS) * 256 + kb + (c0 + q) * 8, f32);
        __syncthreads();
        #pragma unroll
        for (int kk = 0; kk < 2; ++kk) {
            bf16x8 af[4], bfr[4];
            #pragma unroll
            for (int f = 0; f < 4; ++f) {
                af[f]  = fragLd(As, waveM + f * 16 + lr, kk * 4 + lk);
                bfr[f] = fragLd(Bs, waveN + f * 16 + lr, kk * 4 + lk);
            }
            #pragma unroll
            for (int fm = 0; fm < 4; ++fm)
                #pragma unroll
                for (int fn = 0; fn < 4; ++fn)
                    acc[fm][fn] = __builtin_amdgcn_mfma_f32_16x16x32_bf16(af[fm], bfr[fn], acc[fm][fn], 0, 0, 0);
        }
        __syncthreads();
    }

    #pragma unroll
    for (int fm = 0; fm < 4; ++fm) {
        #pragma unroll
        for (int fn = 0; fn < 4; ++fn) {
            const int col = waveN + fn * 16 + lr;
            const float bias = loadIn(b3, n0 + col, f32);
            #pragma unroll
            for (int i = 0; i < 4; ++i) {
                const int row = waveM + fm * 16 + lk * 4 + i;
                V[(long)(m0 + row) * 256 + n0 + col] = f2b(acc[fm][fn][i] + bias);
            }
        }
    }
}

// ---------------- FC2 (unchanged, proven; args: U-source, V-source) ----------------

__global__ __launch_bounds__(256) void k_fc2(const unsigned short* __restrict__ Usrc,
                                             const unsigned short* __restrict__ Vsrc,
                                             const void* __restrict__ W4,
                                             const void* __restrict__ b4,
                                             const float* __restrict__ flag,
                                             void* __restrict__ out,
                                             int n) {
    const bool f32 = flag[0] > 0.5f;
    __shared__ float W4s[64 * 128];
    __shared__ float b4s[64];
    for (int i = threadIdx.x; i < 64 * 128; i += 256) W4s[i] = loadIn(W4, i, f32);
    if (threadIdx.x < 64) b4s[threadIdx.x] = loadIn(b4, threadIdx.x, f32);
    __syncthreads();

    const int s = blockIdx.x * 256 + threadIdx.x;
    const int d = s >> 12, h = (s >> 6) & 63, w = s & 63;
    const int g = ((d >> 2) << 6) | ((h >> 3) << 3) | (w >> 3);
    const int p = ((d & 3) << 6) | ((h & 7) << 3) | (w & 7);
    const int gp = g * 256 + p;

    float val[128];
    #pragma unroll
    for (int c = 0; c < 64; ++c) val[c] = b2f(Usrc[((long)c << 17) + gp]);
    #pragma unroll
    for (int c = 0; c < 64; ++c) val[64 + c] = b2f(Vsrc[((long)c << 17) + gp]);

    for (int k = 0; k < 64; ++k) {
        float acc = b4s[k];
        const float4* wr = (const float4*)&W4s[k * 128];
        #pragma unroll
        for (int c4 = 0; c4 < 32; ++c4) {
            float4 wv = wr[c4];
            acc += wv.x * val[c4 * 4 + 0] + wv.y * val[c4 * 4 + 1]
                 + wv.z * val[c4 * 4 + 2] + wv.w * val[c4 * 4 + 3];
        }
        storeOut(out, ((long)(n * 64 + k) << 17) + s, acc, f32);
    }
}

extern "C" void kernel_launch(void* const* d_in, const int* in_sizes, int n_in,
                              void* d_out, int out_size, void* d_ws, size_t ws_size,
                              hipStream_t stream) {
    const void* x  = d_in[0];
    const void* W1 = d_in[1];
    const void* b1 = d_in[2];
    const void* W2 = d_in[3];
    const void* b2 = d_in[4];
    const void* W3 = d_in[5];
    const void* b3 = d_in[6];
    const void* W4 = d_in[7];
    const void* b4 = d_in[8];

    float* wsf      = (float*)d_ws;
    float* stats    = wsf;            // 8 floats
    float* flag     = wsf + 8;        // 1 float
    float* partials = wsf + 16;       // 1024 floats
    unsigned short* A = (unsigned short*)((char*)d_ws + 8192);
    unsigned short* C = A + (size_t)64 * 512 * 256;   // +16MiB ; total ask ~33.6MB

    hipLaunchKernelGGL(k_detect,   dim3(1),   dim3(256), 0, stream,
                       (const unsigned short*)x, flag);
    hipLaunchKernelGGL(k_lnstats,  dim3(512), dim3(256), 0, stream, x, flag, partials);
    hipLaunchKernelGGL(k_lnreduce, dim3(1),   dim3(64),  0, stream, partials, stats);

    for (int n = 0; n < 4; ++n) {
        hipLaunchKernelGGL(k_ln_fc1_gelu, dim3(512),  dim3(256), 0, stream,
                           x, stats, flag, W1, b1, A, d_out, n);
        hipLaunchKernelGGL(k_transA,      dim3(2048), dim3(256), 0, stream, A, C);
        hipLaunchKernelGGL(k_umix_mfma,   dim3(512),  dim3(256), 0, stream,
                           C, W2, b2, flag, A);
        hipLaunchKernelGGL(k_vmix_mfma,   dim3(512),  dim3(256), 0, stream,
                           d_out, W3, b3, flag, C, n);
        hipLaunchKernelGGL(k_fc2,         dim3(512),  dim3(256), 0, stream,
                           A, C, W4, b4, flag, d_out, n);
    }
}

// Round 6
// 628.644 us; speedup vs baseline: 2.5231x; 1.4362x over previous
//
#include <hip/hip_runtime.h>
#include <hip/hip_bf16.h>
#include <math.h>

// Geometry (fixed):
//   x: (N=4, C=64, D=32, H=64, W=64); S = 131072 = G*P, G=512, P=256
//   W1 (128,64) b1(128) | W2 (512,512) b2(512) | W3 (256,256) b3(256) | W4 (64,128) b4(64)
// Blocked index: g=(d>>2)*64+(h>>3)*8+(w>>3); p=(d&3)*64+(h&7)*8+(w&7)
//
// Full-MFMA pipeline, per sample n (ws ask = 8192 B + 32 MiB, proven size):
//   transX: x[c][s] -> XT[s][c]                      (buf1)
//   fc1:    GEMM W1 x XT^T, LN folded in epilogue, GELU
//           k<64  -> Au[c][g][p]                     (buf2)
//           k>=64 -> Bv[g][c][p]                     (d_out region n)
//   transA: Au -> At'[(p*64+c)][g]                   (buf1, XT dead)
//   umix:   GEMM W2 x At'^T -> T_U[(g'*256+p)*64+c]  (buf2, Au dead)
//   vmix:   GEMM W3 x Bv^T  -> T_V[(g*256+k)*64+c]   (buf1, At' dead)
//   fc2:    GEMM W4 x cat(T_U,T_V)^T + b4 -> out n   (Bv dead)

#define S_PER_N 131072
#define CNT_PER_N 8388608.0f

typedef __attribute__((ext_vector_type(8))) short bf16x8;
typedef __attribute__((ext_vector_type(4))) float f32x4;

__device__ __forceinline__ float b2f(unsigned short u) {
    return __uint_as_float(((unsigned int)u) << 16);
}
__device__ __forceinline__ unsigned short f2b(float f) {
    unsigned int i = __float_as_uint(f);
    unsigned int r = i + 0x7FFFu + ((i >> 16) & 1u);
    return (unsigned short)(r >> 16);
}
__device__ __forceinline__ float loadIn(const void* p, long i, bool f32) {
    return f32 ? ((const float*)p)[i] : b2f(((const unsigned short*)p)[i]);
}
__device__ __forceinline__ void storeOut(void* p, long i, float v, bool f32) {
    if (f32) ((float*)p)[i] = v;
    else ((unsigned short*)p)[i] = f2b(v);
}

// ---------------- dtype detect + LN stats (proven) ----------------

__global__ void k_detect(const unsigned short* __restrict__ xw, float* __restrict__ flag) {
    __shared__ int sh[256];
    int tid = threadIdx.x;
    int sane = 0;
    for (int i = tid; i < 4096; i += 256) {
        int e = (xw[i] >> 7) & 0xFF;
        sane += (e >= 110 && e <= 130) ? 1 : 0;
    }
    sh[tid] = sane; __syncthreads();
    for (int off = 128; off; off >>= 1) {
        if (tid < off) sh[tid] += sh[tid + off];
        __syncthreads();
    }
    if (tid == 0) flag[0] = (sh[0] >= 3300) ? 0.0f : 1.0f;
}

__global__ __launch_bounds__(256) void k_lnstats(const void* __restrict__ xp,
                                                 const float* __restrict__ flag,
                                                 float* __restrict__ partials) {
    const bool f32 = flag[0] > 0.5f;
    const int bid = blockIdx.x;
    const long base = (long)bid * 65536;
    float s = 0.0f, sq = 0.0f;
    if (f32) {
        const float4* xv = (const float4*)((const float*)xp + base);
        for (int it = 0; it < 64; ++it) {
            float4 v = xv[it * 256 + threadIdx.x];
            s  += v.x + v.y + v.z + v.w;
            sq += v.x*v.x + v.y*v.y + v.z*v.z + v.w*v.w;
        }
    } else {
        const uint4* xv = (const uint4*)((const unsigned short*)xp + base);
        for (int it = 0; it < 32; ++it) {
            uint4 v = xv[it * 256 + threadIdx.x];
            unsigned int ws4[4] = {v.x, v.y, v.z, v.w};
            #pragma unroll
            for (int q = 0; q < 4; ++q) {
                float f0 = b2f((unsigned short)(ws4[q] & 0xFFFFu));
                float f1 = b2f((unsigned short)(ws4[q] >> 16));
                s += f0 + f1;
                sq += f0 * f0 + f1 * f1;
            }
        }
    }
    __shared__ float ls[256], lq[256];
    ls[threadIdx.x] = s; lq[threadIdx.x] = sq;
    __syncthreads();
    for (int off = 128; off > 0; off >>= 1) {
        if (threadIdx.x < off) {
            ls[threadIdx.x] += ls[threadIdx.x + off];
            lq[threadIdx.x] += lq[threadIdx.x + off];
        }
        __syncthreads();
    }
    if (threadIdx.x == 0) {
        partials[bid * 2 + 0] = ls[0];
        partials[bid * 2 + 1] = lq[0];
    }
}

__global__ void k_lnreduce(const float* __restrict__ partials, float* __restrict__ stats) {
    const int t = threadIdx.x;
    if (t < 4) {
        float s = 0.0f, sq = 0.0f;
        for (int i = 0; i < 128; ++i) {
            s  += partials[(t * 128 + i) * 2 + 0];
            sq += partials[(t * 128 + i) * 2 + 1];
        }
        stats[t * 2 + 0] = s;
        stats[t * 2 + 1] = sq;
    }
}

// ck[n][k] = b1[k] - rstd_n * mu_n * rowsum(W1[k])
__global__ void k_prep(const void* __restrict__ W1, const void* __restrict__ b1,
                       const float* __restrict__ stats, const float* __restrict__ flag,
                       float* __restrict__ ck) {
    const bool f32 = flag[0] > 0.5f;
    const int k = threadIdx.x;     // 128
    float rs = 0.0f;
    for (int c = 0; c < 64; ++c) rs += loadIn(W1, (long)k * 64 + c, f32);
    const float bb = loadIn(b1, k, f32);
    for (int n = 0; n < 4; ++n) {
        const float mu   = stats[n * 2 + 0] * (1.0f / CNT_PER_N);
        const float m2   = stats[n * 2 + 1] * (1.0f / CNT_PER_N);
        const float rstd = rsqrtf(m2 - mu * mu + 1e-5f);
        ck[n * 128 + k] = bb - rstd * mu * rs;
    }
}

// ---------------- transX: x[c][s] -> XT[s][c] (bf16), per sample ----------------
// grid 2048: s-tile of 64; thread: cpair = t&31 (c0=2*cpair), soct = t>>5 (8 s).
__global__ __launch_bounds__(256) void k_transX(const void* __restrict__ xp,
                                                const float* __restrict__ flag,
                                                unsigned short* __restrict__ XT, int n) {
    const bool f32 = flag[0] > 0.5f;
    const int s0 = blockIdx.x * 64;
    const int t = threadIdx.x;
    const int c0 = (t & 31) * 2;
    const int soct = t >> 5;
    const long base = (long)n * 64 * S_PER_N;
    unsigned short v0[8], v1[8];
    if (f32) {
        const float* r0 = (const float*)xp + base + (long)c0 * S_PER_N + s0 + soct * 8;
        const float* r1 = r0 + S_PER_N;
        float4 a0 = *(const float4*)r0, a1 = *(const float4*)(r0 + 4);
        float4 b0 = *(const float4*)r1, b1v = *(const float4*)(r1 + 4);
        const float* fa = (const float*)&a0;
        #pragma unroll
        for (int j = 0; j < 4; ++j) v0[j] = f2b(fa[j]);
        const float* fb = (const float*)&a1;
        #pragma unroll
        for (int j = 0; j < 4; ++j) v0[4 + j] = f2b(fb[j]);
        const float* fc = (const float*)&b0;
        #pragma unroll
        for (int j = 0; j < 4; ++j) v1[j] = f2b(fc[j]);
        const float* fd = (const float*)&b1v;
        #pragma unroll
        for (int j = 0; j < 4; ++j) v1[4 + j] = f2b(fd[j]);
    } else {
        const unsigned short* xb = (const unsigned short*)xp + base;
        uint4 a = *(const uint4*)(xb + (long)c0 * S_PER_N + s0 + soct * 8);
        uint4 b = *(const uint4*)(xb + (long)(c0 + 1) * S_PER_N + s0 + soct * 8);
        const unsigned short* pa = (const unsigned short*)&a;
        const unsigned short* pb = (const unsigned short*)&b;
        #pragma unroll
        for (int j = 0; j < 8; ++j) { v0[j] = pa[j]; v1[j] = pb[j]; }
    }
    #pragma unroll
    for (int j = 0; j < 8; ++j) {
        unsigned int val = (unsigned int)v0[j] | ((unsigned int)v1[j] << 16);
        *(unsigned int*)(XT + (long)(s0 + soct * 8 + j) * 64 + c0) = val;
    }
}

// ---------------- MFMA staging helpers ----------------
// 64-wide rows (8 chunks of 8 bf16), chunk XOR-swizzled by row.
__device__ __forceinline__ void stage8(unsigned short* lds, int r, int c,
                                       const void* gp, long gidx, bool f32) {
    const int dst = r * 64 + ((c ^ (r & 7)) << 3);
    uint4 v;
    if (f32) {
        const float* s = (const float*)gp + gidx;
        float4 a = *(const float4*)s;
        float4 b = *(const float4*)(s + 4);
        v.x = (unsigned int)f2b(a.x) | ((unsigned int)f2b(a.y) << 16);
        v.y = (unsigned int)f2b(a.z) | ((unsigned int)f2b(a.w) << 16);
        v.z = (unsigned int)f2b(b.x) | ((unsigned int)f2b(b.y) << 16);
        v.w = (unsigned int)f2b(b.z) | ((unsigned int)f2b(b.w) << 16);
    } else {
        v = *(const uint4*)((const unsigned short*)gp + gidx);
    }
    *(uint4*)&lds[dst] = v;
}
__device__ __forceinline__ bf16x8 fragLd(const unsigned short* lds, int r, int c) {
    return *(const bf16x8*)&lds[r * 64 + ((c ^ (r & 7)) << 3)];
}
// 128-wide rows (16 chunks), same swizzle idea.
__device__ __forceinline__ void stage8w(unsigned short* lds, int r, int c,
                                        const void* gp, long gidx, bool f32) {
    const int dst = r * 128 + ((c ^ (r & 7)) << 3);
    uint4 v;
    if (f32) {
        const float* s = (const float*)gp + gidx;
        float4 a = *(const float4*)s;
        float4 b = *(const float4*)(s + 4);
        v.x = (unsigned int)f2b(a.x) | ((unsigned int)f2b(a.y) << 16);
        v.y = (unsigned int)f2b(a.z) | ((unsigned int)f2b(a.w) << 16);
        v.z = (unsigned int)f2b(b.x) | ((unsigned int)f2b(b.y) << 16);
        v.w = (unsigned int)f2b(b.z) | ((unsigned int)f2b(b.w) << 16);
    } else {
        v = *(const uint4*)((const unsigned short*)gp + gidx);
    }
    *(uint4*)&lds[dst] = v;
}
__device__ __forceinline__ bf16x8 fragLd128(const unsigned short* lds, int r, int c) {
    return *(const bf16x8*)&lds[r * 128 + ((c ^ (r & 7)) << 3)];
}

// ---------------- fc1: D[k=128][s-tile=128], K=64; LN folded, GELU ----------------
// grid 1024/sample; XCD-grouped tile order.
__global__ __launch_bounds__(256) void k_fc1_mfma(const unsigned short* __restrict__ XT,
                                                  const float* __restrict__ stats,
                                                  const float* __restrict__ ck,
                                                  const void* __restrict__ W1,
                                                  const float* __restrict__ flag,
                                                  unsigned short* __restrict__ Au,
                                                  void* __restrict__ outBase, int n) {
    const bool f32 = flag[0] > 0.5f;
    __shared__ __align__(16) unsigned short As[128 * 64];
    __shared__ __align__(16) unsigned short Bs[128 * 64];
    const int bid = blockIdx.x;
    const int tile = ((bid & 7) << 7) | (bid >> 3);   // XCD-group s-tiles
    const int s0 = tile * 128;
    const int t = threadIdx.x;
    const int lane = t & 63, wid = t >> 6;
    const int waveM = (wid >> 1) * 64, waveN = (wid & 1) * 64;
    const int lr = lane & 15, lk = lane >> 4;
    const int rS = t >> 1, c0 = (t & 1) * 4;

    unsigned short* Bv = (unsigned short*)((char*)outBase + (size_t)n * 8388608 * (f32 ? 4 : 2));

    #pragma unroll
    for (int q = 0; q < 4; ++q)
        stage8(As, rS, c0 + q, W1, (long)rS * 64 + (c0 + q) * 8, f32);
    #pragma unroll
    for (int q = 0; q < 4; ++q)
        stage8(Bs, rS, c0 + q, XT, (long)(s0 + rS) * 64 + (c0 + q) * 8, false);
    __syncthreads();

    f32x4 zero = {0.f, 0.f, 0.f, 0.f};
    f32x4 acc[4][4];
    #pragma unroll
    for (int i = 0; i < 4; ++i)
        #pragma unroll
        for (int j = 0; j < 4; ++j) acc[i][j] = zero;

    #pragma unroll
    for (int kk = 0; kk < 2; ++kk) {
        bf16x8 af[4], bfr[4];
        #pragma unroll
        for (int f = 0; f < 4; ++f) {
            af[f]  = fragLd(As, waveM + f * 16 + lr, kk * 4 + lk);
            bfr[f] = fragLd(Bs, waveN + f * 16 + lr, kk * 4 + lk);
        }
        #pragma unroll
        for (int fm = 0; fm < 4; ++fm)
            #pragma unroll
            for (int fn = 0; fn < 4; ++fn)
                acc[fm][fn] = __builtin_amdgcn_mfma_f32_16x16x32_bf16(af[fm], bfr[fn], acc[fm][fn], 0, 0, 0);
    }

    const float mu   = stats[n * 2 + 0] * (1.0f / CNT_PER_N);
    const float m2   = stats[n * 2 + 1] * (1.0f / CNT_PER_N);
    const float rstd = rsqrtf(m2 - mu * mu + 1e-5f);

    #pragma unroll
    for (int fn = 0; fn < 4; ++fn) {
        const int s = s0 + waveN + fn * 16 + lr;
        const int d = s >> 12, h = (s >> 6) & 63, w = s & 63;
        const int g = ((d >> 2) << 6) | ((h >> 3) << 3) | (w >> 3);
        const int p = ((d & 3) << 6) | ((h & 7) << 3) | (w & 7);
        const long gp = (long)g * 256 + p;
        #pragma unroll
        for (int fm = 0; fm < 4; ++fm) {
            #pragma unroll
            for (int i = 0; i < 4; ++i) {
                const int k = waveM + fm * 16 + lk * 4 + i;
                float v = acc[fm][fn][i] * rstd + ck[n * 128 + k];
                float ge = 0.5f * v * (1.0f + erff(v * 0.70710678118654752440f));
                unsigned short r = f2b(ge);
                if (k < 64) Au[(long)k * S_PER_N + gp] = r;
                else        Bv[((long)g * 64 + (k - 64)) * 256 + p] = r;
            }
        }
    }
}

// ---------------- transA: Au[c][g][p] -> At'[(p*64+c)][g] ----------------
__global__ __launch_bounds__(256) void k_transA(const unsigned short* __restrict__ A,
                                                unsigned short* __restrict__ At) {
    __shared__ unsigned short T[64 * 66];
    const int bid = blockIdx.x;
    const int c  = bid >> 5;
    const int gt = (bid >> 2) & 7, pt = bid & 3;
    const int g0 = gt * 64, p0 = pt * 64;
    const int t = threadIdx.x;

    const int gr = t >> 2, pc = (t & 3) * 16;
    const unsigned int* s32 = (const unsigned int*)(A + (long)c * S_PER_N + (long)(g0 + gr) * 256 + p0 + pc);
    unsigned int* d32 = (unsigned int*)&T[gr * 66 + pc];
    #pragma unroll
    for (int i = 0; i < 8; ++i) d32[i] = s32[i];
    __syncthreads();

    const int pr = t >> 2, gc0 = (t & 3) * 16;
    unsigned int ov[8];
    #pragma unroll
    for (int i = 0; i < 8; ++i) {
        unsigned int lo = T[(gc0 + 2 * i) * 66 + pr];
        unsigned int hi = T[(gc0 + 2 * i + 1) * 66 + pr];
        ov[i] = lo | (hi << 16);
    }
    unsigned int* dst = (unsigned int*)(At + ((long)(p0 + pr) * 64 + c) * 512 + g0 + gc0);
    #pragma unroll
    for (int i = 0; i < 8; ++i) dst[i] = ov[i];
}

// ---------------- umix: D[m=g'(512)][n=(p*64+c)(16384)], K=g(512) -> T_U token-major ----------------
// grid 512: bid = mTile*128 + nTile
__global__ __launch_bounds__(256) void k_umix_mfma(const unsigned short* __restrict__ Bt,
                                                   const void* __restrict__ W2,
                                                   const void* __restrict__ b2,
                                                   const float* __restrict__ flag,
                                                   unsigned short* __restrict__ TU) {
    const bool f32 = flag[0] > 0.5f;
    __shared__ __align__(16) unsigned short As[128 * 64];
    __shared__ __align__(16) unsigned short Bs[128 * 64];
    const int bid = blockIdx.x;
    const int mTile = bid >> 7;
    const int nTile = bid & 127;
    const int m0 = mTile * 128;
    const long btBase = (long)nTile * 128 * 512;
    const int t = threadIdx.x;
    const int lane = t & 63, wid = t >> 6;
    const int waveM = (wid >> 1) * 64, waveN = (wid & 1) * 64;
    const int lr = lane & 15, lk = lane >> 4;
    const int rS = t >> 1, c0 = (t & 1) * 4;

    f32x4 zero = {0.f, 0.f, 0.f, 0.f};
    f32x4 acc[4][4];
    #pragma unroll
    for (int i = 0; i < 4; ++i)
        #pragma unroll
        for (int j = 0; j < 4; ++j) acc[i][j] = zero;

    for (int kb = 0; kb < 512; kb += 64) {
        #pragma unroll
        for (int q = 0; q < 4; ++q)
            stage8(As, rS, c0 + q, W2, (long)(m0 + rS) * 512 + kb + (c0 + q) * 8, f32);
        #pragma unroll
        for (int q = 0; q < 4; ++q)
            stage8(Bs, rS, c0 + q, Bt, btBase + (long)rS * 512 + kb + (c0 + q) * 8, false);
        __syncthreads();
        #pragma unroll
        for (int kk = 0; kk < 2; ++kk) {
            bf16x8 af[4], bfr[4];
            #pragma unroll
            for (int f = 0; f < 4; ++f) {
                af[f]  = fragLd(As, waveM + f * 16 + lr, kk * 4 + lk);
                bfr[f] = fragLd(Bs, waveN + f * 16 + lr, kk * 4 + lk);
            }
            #pragma unroll
            for (int fm = 0; fm < 4; ++fm)
                #pragma unroll
                for (int fn = 0; fn < 4; ++fn)
                    acc[fm][fn] = __builtin_amdgcn_mfma_f32_16x16x32_bf16(af[fm], bfr[fn], acc[fm][fn], 0, 0, 0);
        }
        __syncthreads();
    }

    #pragma unroll
    for (int fn = 0; fn < 4; ++fn) {
        const int nl = waveN + fn * 16 + lr;       // 0..127
        const int p = nTile * 2 + (nl >> 6);
        const int c = nl & 63;
        #pragma unroll
        for (int fm = 0; fm < 4; ++fm) {
            #pragma unroll
            for (int i = 0; i < 4; ++i) {
                const int row = m0 + waveM + fm * 16 + lk * 4 + i;   // g' 0..511
                const float bias = loadIn(b2, row, f32);
                TU[((long)row * 256 + p) * 64 + c] = f2b(acc[fm][fn][i] + bias);
            }
        }
    }
}

// ---------------- vmix: D[m=k(256)][n=(g*64+c)(32768)], K=p(256) -> T_V token-major ----------------
// grid 512: bid = mTile*256 + nTile
__global__ __launch_bounds__(256) void k_vmix_mfma(void* __restrict__ outBase,
                                                   const void* __restrict__ W3,
                                                   const void* __restrict__ b3,
                                                   const float* __restrict__ flag,
                                                   unsigned short* __restrict__ TV,
                                                   int n) {
    const bool f32 = flag[0] > 0.5f;
    __shared__ __align__(16) unsigned short As[128 * 64];
    __shared__ __align__(16) unsigned short Bs[128 * 64];
    const unsigned short* Bv = (const unsigned short*)((char*)outBase + (size_t)n * 8388608 * (f32 ? 4 : 2));
    const int bid = blockIdx.x;
    const int mTile = bid >> 8;       // 0..1
    const int nTile = bid & 255;      // 0..255
    const int m0 = mTile * 128;
    const int t = threadIdx.x;
    const int lane = t & 63, wid = t >> 6;
    const int waveM = (wid >> 1) * 64, waveN = (wid & 1) * 64;
    const int lr = lane & 15, lk = lane >> 4;
    const int rS = t >> 1, c0 = (t & 1) * 4;

    f32x4 zero = {0.f, 0.f, 0.f, 0.f};
    f32x4 acc[4][4];
    #pragma unroll
    for (int i = 0; i < 4; ++i)
        #pragma unroll
        for (int j = 0; j < 4; ++j) acc[i][j] = zero;

    for (int kb = 0; kb < 256; kb += 64) {
        #pragma unroll
        for (int q = 0; q < 4; ++q)
            stage8(As, rS, c0 + q, W3, (long)(m0 + rS) * 256 + kb + (c0 + q) * 8, f32);
        #pragma unroll
        for (int q = 0; q < 4; ++q)
            stage8(Bs, rS, c0 + q, Bv, ((long)nTile * 128 + rS) * 256 + kb + (c0 + q) * 8, false);
        __syncthreads();
        #pragma unroll
        for (int kk = 0; kk < 2; ++kk) {
            bf16x8 af[4], bfr[4];
            #pragma unroll
            for (int f = 0; f < 4; ++f) {
                af[f]  = fragLd(As, waveM + f * 16 + lr, kk * 4 + lk);
                bfr[f] = fragLd(Bs, waveN + f * 16 + lr, kk * 4 + lk);
            }
            #pragma unroll
            for (int fm = 0; fm < 4; ++fm)
                #pragma unroll
                for (int fn = 0; fn < 4; ++fn)
                    acc[fm][fn] = __builtin_amdgcn_mfma_f32_16x16x32_bf16(af[fm], bfr[fn], acc[fm][fn], 0, 0, 0);
        }
        __syncthreads();
    }

    #pragma unroll
    for (int fn = 0; fn < 4; ++fn) {
        const int nl = waveN + fn * 16 + lr;
        const int g = nTile * 2 + (nl >> 6);
        const int c = nl & 63;
        #pragma unroll
        for (int fm = 0; fm < 4; ++fm) {
            #pragma unroll
            for (int i = 0; i < 4; ++i) {
                const int k = m0 + waveM + fm * 16 + lk * 4 + i;   // p_out 0..255
                const float bias = loadIn(b3, k, f32);
                TV[((long)g * 256 + k) * 64 + c] = f2b(acc[fm][fn][i] + bias);
            }
        }
    }
}

// ---------------- fc2: D[k=64][s-tile=128], K=128 from T_U/T_V ----------------
// grid 1024/sample
__global__ __launch_bounds__(256) void k_fc2_mfma(const unsigned short* __restrict__ TU,
                                                  const unsigned short* __restrict__ TV,
                                                  const void* __restrict__ W4,
                                                  const void* __restrict__ b4,
                                                  const float* __restrict__ flag,
                                                  void* __restrict__ out, int n) {
    const bool f32 = flag[0] > 0.5f;
    __shared__ __align__(16) unsigned short As[64 * 128];    // 16 KB
    __shared__ __align__(16) unsigned short Bs[128 * 128];   // 32 KB
    const int s0 = blockIdx.x * 128;
    const int t = threadIdx.x;
    const int lane = t & 63, wid = t >> 6;
    const int waveN = wid * 32;
    const int lr = lane & 15, lk = lane >> 4;

    {   // stage A: W4 64 rows x 16 chunks
        const int rA = t >> 2, q0 = (t & 3) * 4;
        #pragma unroll
        for (int q = 0; q < 4; ++q)
            stage8w(As, rA, q0 + q, W4, (long)rA * 128 + (q0 + q) * 8, f32);
    }
    {   // stage B: 128 rows x 16 chunks; thread t: row = t&127, chunk-half = t>>7
        const int rB = t & 127, h8 = (t >> 7) * 8;
        const int s = s0 + rB;
        const int d = s >> 12, h = (s >> 6) & 63, w = s & 63;
        const int g = ((d >> 2) << 6) | ((h >> 3) << 3) | (w >> 3);
        const int p = ((d & 3) << 6) | ((h & 7) << 3) | (w & 7);
        const long gp = (long)g * 256 + p;
        const unsigned short* src = (h8 == 0) ? (TU + gp * 64) : (TV + gp * 64);
        #pragma unroll
        for (int q = 0; q < 8; ++q) {
            const int ch = h8 + q;
            uint4 v = *(const uint4*)(src + q * 8);
            *(uint4*)&Bs[rB * 128 + ((ch ^ (rB & 7)) << 3)] = v;
        }
    }
    __syncthreads();

    f32x4 zero = {0.f, 0.f, 0.f, 0.f};
    f32x4 acc[4][2];
    #pragma unroll
    for (int i = 0; i < 4; ++i) { acc[i][0] = zero; acc[i][1] = zero; }

    #pragma unroll
    for (int kk = 0; kk < 4; ++kk) {
        bf16x8 af[4], bfr[2];
        #pragma unroll
        for (int fm = 0; fm < 4; ++fm) af[fm] = fragLd128(As, fm * 16 + lr, kk * 4 + lk);
        #pragma unroll
        for (int fn = 0; fn < 2; ++fn) bfr[fn] = fragLd128(Bs, waveN + fn * 16 + lr, kk * 4 + lk);
        #pragma unroll
        for (int fm = 0; fm < 4; ++fm)
            #pragma unroll
            for (int fn = 0; fn < 2; ++fn)
                acc[fm][fn] = __builtin_amdgcn_mfma_f32_16x16x32_bf16(af[fm], bfr[fn], acc[fm][fn], 0, 0, 0);
    }

    #pragma unroll
    for (int fm = 0; fm < 4; ++fm) {
        #pragma unroll
        for (int fn = 0; fn < 2; ++fn) {
            const int scol = s0 + waveN + fn * 16 + lr;
            #pragma unroll
            for (int i = 0; i < 4; ++i) {
                const int k = fm * 16 + lk * 4 + i;
                const float v = acc[fm][fn][i] + loadIn(b4, k, f32);
                storeOut(out, ((long)(n * 64 + k) << 17) + scol, v, f32);
            }
        }
    }
}

extern "C" void kernel_launch(void* const* d_in, const int* in_sizes, int n_in,
                              void* d_out, int out_size, void* d_ws, size_t ws_size,
                              hipStream_t stream) {
    const void* x  = d_in[0];
    const void* W1 = d_in[1];
    const void* b1 = d_in[2];
    const void* W2 = d_in[3];
    const void* b2 = d_in[4];
    const void* W3 = d_in[5];
    const void* b3 = d_in[6];
    const void* W4 = d_in[7];
    const void* b4 = d_in[8];

    float* wsf      = (float*)d_ws;
    float* stats    = wsf;            // 8 floats
    float* flag     = wsf + 8;        // 1 float
    float* partials = wsf + 16;       // 1024 floats
    float* ck       = wsf + 1040;     // 512 floats (ends < 8192 B)
    unsigned short* buf1 = (unsigned short*)((char*)d_ws + 8192);
    unsigned short* buf2 = buf1 + (size_t)64 * 512 * 256;   // +16 MiB; ask ~33.6 MB

    hipLaunchKernelGGL(k_detect,   dim3(1),   dim3(256), 0, stream,
                       (const unsigned short*)x, flag);
    hipLaunchKernelGGL(k_lnstats,  dim3(512), dim3(256), 0, stream, x, flag, partials);
    hipLaunchKernelGGL(k_lnreduce, dim3(1),   dim3(64),  0, stream, partials, stats);
    hipLaunchKernelGGL(k_prep,     dim3(1),   dim3(128), 0, stream, W1, b1, stats, flag, ck);

    for (int n = 0; n < 4; ++n) {
        hipLaunchKernelGGL(k_transX,    dim3(2048), dim3(256), 0, stream, x, flag, buf1, n);
        hipLaunchKernelGGL(k_fc1_mfma,  dim3(1024), dim3(256), 0, stream,
                           buf1, stats, ck, W1, flag, buf2, d_out, n);
        hipLaunchKernelGGL(k_transA,    dim3(2048), dim3(256), 0, stream, buf2, buf1);
        hipLaunchKernelGGL(k_umix_mfma, dim3(512),  dim3(256), 0, stream,
                           buf1, W2, b2, flag, buf2);
        hipLaunchKernelGGL(k_vmix_mfma, dim3(512),  dim3(256), 0, stream,
                           d_out, W3, b3, flag, buf1, n);
        hipLaunchKernelGGL(k_fc2_mfma,  dim3(1024), dim3(256), 0, stream,
                           buf2, buf1, W4, b4, flag, d_out, n);
    }
}

// Round 7
// 509.877 us; speedup vs baseline: 3.1109x; 1.2329x over previous
//
#include <hip/hip_runtime.h>
#include <hip/hip_bf16.h>
#include <math.h>

// Geometry (fixed):
//   x: (N=4, C=64, D=32, H=64, W=64); S = 131072 = G*P, G=512, P=256
//   W1 (128,64) b1(128) | W2 (512,512) b2(512) | W3 (256,256) b3(256) | W4 (64,128) b4(64)
// Blocked index: g=(d>>2)*64+(h>>3)*8+(w>>3); p=(d&3)*64+(h&7)*8+(w&7)
//
// Full-MFMA pipeline, batched over samples (cnt = 4 if ws fits, else per-sample):
//   fc1:    GEMM W1 x X^T (x staged fp32->bf16 transposed in-kernel), LN folded, GELU
//           k<64  -> Au[c][g][p]      (buf2[nl])
//           k>=64 -> Bv[g][c][p]      (d_out region n)
//   transA: Au -> At'[(p*64+c)][g]    (buf1[nl])
//   umix:   GEMM W2 x At'^T -> T_U[(g'*256+p)*64+c]   (buf2[nl], Au dead)
//   vmix:   GEMM W3 x Bv^T  -> T_V[(g*256+k)*64+c]    (buf1[nl], At' dead)
//   fc2:    GEMM W4 x cat(T_U,T_V)^T + b4 -> out n    (Bv dead)
// ws ask: batched = 8192 B + 128 MiB (ws_size deduced 512 MiB from poison fill);
// falls back to per-sample (8192 B + 32 MiB) if ws_size is smaller.

#define S_PER_N 131072
#define CNT_PER_N 8388608.0f

typedef __attribute__((ext_vector_type(8))) short bf16x8;
typedef __attribute__((ext_vector_type(4))) float f32x4;

__device__ __forceinline__ float b2f(unsigned short u) {
    return __uint_as_float(((unsigned int)u) << 16);
}
__device__ __forceinline__ unsigned short f2b(float f) {
    unsigned int i = __float_as_uint(f);
    unsigned int r = i + 0x7FFFu + ((i >> 16) & 1u);
    return (unsigned short)(r >> 16);
}
__device__ __forceinline__ float loadIn(const void* p, long i, bool f32) {
    return f32 ? ((const float*)p)[i] : b2f(((const unsigned short*)p)[i]);
}
__device__ __forceinline__ void storeOut(void* p, long i, float v, bool f32) {
    if (f32) ((float*)p)[i] = v;
    else ((unsigned short*)p)[i] = f2b(v);
}

// ---------------- dtype detect + LN stats (proven) ----------------

__global__ void k_detect(const unsigned short* __restrict__ xw, float* __restrict__ flag) {
    __shared__ int sh[256];
    int tid = threadIdx.x;
    int sane = 0;
    for (int i = tid; i < 4096; i += 256) {
        int e = (xw[i] >> 7) & 0xFF;
        sane += (e >= 110 && e <= 130) ? 1 : 0;
    }
    sh[tid] = sane; __syncthreads();
    for (int off = 128; off; off >>= 1) {
        if (tid < off) sh[tid] += sh[tid + off];
        __syncthreads();
    }
    if (tid == 0) flag[0] = (sh[0] >= 3300) ? 0.0f : 1.0f;
}

__global__ __launch_bounds__(256) void k_lnstats(const void* __restrict__ xp,
                                                 const float* __restrict__ flag,
                                                 float* __restrict__ partials) {
    const bool f32 = flag[0] > 0.5f;
    const int bid = blockIdx.x;
    const long base = (long)bid * 65536;
    float s = 0.0f, sq = 0.0f;
    if (f32) {
        const float4* xv = (const float4*)((const float*)xp + base);
        for (int it = 0; it < 64; ++it) {
            float4 v = xv[it * 256 + threadIdx.x];
            s  += v.x + v.y + v.z + v.w;
            sq += v.x*v.x + v.y*v.y + v.z*v.z + v.w*v.w;
        }
    } else {
        const uint4* xv = (const uint4*)((const unsigned short*)xp + base);
        for (int it = 0; it < 32; ++it) {
            uint4 v = xv[it * 256 + threadIdx.x];
            unsigned int ws4[4] = {v.x, v.y, v.z, v.w};
            #pragma unroll
            for (int q = 0; q < 4; ++q) {
                float f0 = b2f((unsigned short)(ws4[q] & 0xFFFFu));
                float f1 = b2f((unsigned short)(ws4[q] >> 16));
                s += f0 + f1;
                sq += f0 * f0 + f1 * f1;
            }
        }
    }
    __shared__ float ls[256], lq[256];
    ls[threadIdx.x] = s; lq[threadIdx.x] = sq;
    __syncthreads();
    for (int off = 128; off > 0; off >>= 1) {
        if (threadIdx.x < off) {
            ls[threadIdx.x] += ls[threadIdx.x + off];
            lq[threadIdx.x] += lq[threadIdx.x + off];
        }
        __syncthreads();
    }
    if (threadIdx.x == 0) {
        partials[bid * 2 + 0] = ls[0];
        partials[bid * 2 + 1] = lq[0];
    }
}

__global__ void k_lnreduce(const float* __restrict__ partials, float* __restrict__ stats) {
    const int t = threadIdx.x;
    if (t < 4) {
        float s = 0.0f, sq = 0.0f;
        for (int i = 0; i < 128; ++i) {
            s  += partials[(t * 128 + i) * 2 + 0];
            sq += partials[(t * 128 + i) * 2 + 1];
        }
        stats[t * 2 + 0] = s;
        stats[t * 2 + 1] = sq;
    }
}

// ck[n][k] = b1[k] - rstd_n * mu_n * rowsum(W1[k])
__global__ void k_prep(const void* __restrict__ W1, const void* __restrict__ b1,
                       const float* __restrict__ stats, const float* __restrict__ flag,
                       float* __restrict__ ck) {
    const bool f32 = flag[0] > 0.5f;
    const int k = threadIdx.x;     // 128
    float rs = 0.0f;
    for (int c = 0; c < 64; ++c) rs += loadIn(W1, (long)k * 64 + c, f32);
    const float bb = loadIn(b1, k, f32);
    for (int n = 0; n < 4; ++n) {
        const float mu   = stats[n * 2 + 0] * (1.0f / CNT_PER_N);
        const float m2   = stats[n * 2 + 1] * (1.0f / CNT_PER_N);
        const float rstd = rsqrtf(m2 - mu * mu + 1e-5f);
        ck[n * 128 + k] = bb - rstd * mu * rs;
    }
}

// ---------------- MFMA staging helpers ----------------
// 64-wide rows (8 chunks of 8 bf16), chunk XOR-swizzled by row.
__device__ __forceinline__ void stage8(unsigned short* lds, int r, int c,
                                       const void* gp, long gidx, bool f32) {
    const int dst = r * 64 + ((c ^ (r & 7)) << 3);
    uint4 v;
    if (f32) {
        const float* s = (const float*)gp + gidx;
        float4 a = *(const float4*)s;
        float4 b = *(const float4*)(s + 4);
        v.x = (unsigned int)f2b(a.x) | ((unsigned int)f2b(a.y) << 16);
        v.y = (unsigned int)f2b(a.z) | ((unsigned int)f2b(a.w) << 16);
        v.z = (unsigned int)f2b(b.x) | ((unsigned int)f2b(b.y) << 16);
        v.w = (unsigned int)f2b(b.z) | ((unsigned int)f2b(b.w) << 16);
    } else {
        v = *(const uint4*)((const unsigned short*)gp + gidx);
    }
    *(uint4*)&lds[dst] = v;
}
__device__ __forceinline__ bf16x8 fragLd(const unsigned short* lds, int r, int c) {
    return *(const bf16x8*)&lds[r * 64 + ((c ^ (r & 7)) << 3)];
}
// 128-wide rows (16 chunks), same swizzle idea.
__device__ __forceinline__ void stage8w(unsigned short* lds, int r, int c,
                                        const void* gp, long gidx, bool f32) {
    const int dst = r * 128 + ((c ^ (r & 7)) << 3);
    uint4 v;
    if (f32) {
        const float* s = (const float*)gp + gidx;
        float4 a = *(const float4*)s;
        float4 b = *(const float4*)(s + 4);
        v.x = (unsigned int)f2b(a.x) | ((unsigned int)f2b(a.y) << 16);
        v.y = (unsigned int)f2b(a.z) | ((unsigned int)f2b(a.w) << 16);
        v.z = (unsigned int)f2b(b.x) | ((unsigned int)f2b(b.y) << 16);
        v.w = (unsigned int)f2b(b.z) | ((unsigned int)f2b(b.w) << 16);
    } else {
        v = *(const uint4*)((const unsigned short*)gp + gidx);
    }
    *(uint4*)&lds[dst] = v;
}
__device__ __forceinline__ bf16x8 fragLd128(const unsigned short* lds, int r, int c) {
    return *(const bf16x8*)&lds[r * 128 + ((c ^ (r & 7)) << 3)];
}

// ---------------- fc1: D[k=128][s-tile=128], K=64; x staged transposed in-kernel ----------------
// grid cnt*1024; LN folded in epilogue, exact GELU.
__global__ __launch_bounds__(256) void k_fc1_mfma(const void* __restrict__ xp,
                                                  const float* __restrict__ stats,
                                                  const float* __restrict__ ck,
                                                  const void* __restrict__ W1,
                                                  const float* __restrict__ flag,
                                                  unsigned short* __restrict__ buf2,
                                                  void* __restrict__ outBase, int nBase) {
    const bool f32 = flag[0] > 0.5f;
    __shared__ __align__(16) unsigned short As[128 * 64];
    __shared__ __align__(16) unsigned short Bs[128 * 64];
    const int bid = blockIdx.x;
    const int nl = bid >> 10;
    const int n = nBase + nl;
    const int tileRaw = bid & 1023;
    const int tile = ((tileRaw & 7) << 7) | (tileRaw >> 3);   // XCD-group s-tiles
    const int s0 = tile * 128;
    const int t = threadIdx.x;
    const int lane = t & 63, wid = t >> 6;
    const int waveM = (wid >> 1) * 64, waveN = (wid & 1) * 64;
    const int lr = lane & 15, lk = lane >> 4;

    unsigned short* Au = buf2 + (size_t)nl * 8388608;
    unsigned short* Bv = (unsigned short*)((char*)outBase + (size_t)n * 8388608 * (f32 ? 4 : 2));

    {   // stage A: W1 (128 x 64)
        const int rS = t >> 1, c04 = (t & 1) * 4;
        #pragma unroll
        for (int q = 0; q < 4; ++q)
            stage8(As, rS, c04 + q, W1, (long)rS * 64 + (c04 + q) * 8, f32);
    }
    {   // stage B: x^T tile (128 s x 64 c), fused fp32->bf16 transpose
        const int c0 = (t & 31) * 2;
        const int soct = t >> 5;                  // 0..7, 16 s each
        const long rowBase = (long)(n * 64) * S_PER_N;
        const int sbase = s0 + soct * 16;
        unsigned short v0[16], v1[16];
        if (f32) {
            const float* r0 = (const float*)xp + rowBase + (long)c0 * S_PER_N + sbase;
            const float* r1 = r0 + S_PER_N;
            #pragma unroll
            for (int q = 0; q < 4; ++q) {
                float4 a = *(const float4*)(r0 + q * 4);
                float4 b = *(const float4*)(r1 + q * 4);
                v0[q*4+0]=f2b(a.x); v0[q*4+1]=f2b(a.y); v0[q*4+2]=f2b(a.z); v0[q*4+3]=f2b(a.w);
                v1[q*4+0]=f2b(b.x); v1[q*4+1]=f2b(b.y); v1[q*4+2]=f2b(b.z); v1[q*4+3]=f2b(b.w);
            }
        } else {
            const unsigned short* r0 = (const unsigned short*)xp + rowBase + (long)c0 * S_PER_N + sbase;
            const unsigned short* r1 = r0 + S_PER_N;
            #pragma unroll
            for (int q = 0; q < 2; ++q) {
                uint4 a = *(const uint4*)(r0 + q * 8);
                uint4 b = *(const uint4*)(r1 + q * 8);
                const unsigned short* pa = (const unsigned short*)&a;
                const unsigned short* pb = (const unsigned short*)&b;
                #pragma unroll
                for (int j = 0; j < 8; ++j) { v0[q*8+j] = pa[j]; v1[q*8+j] = pb[j]; }
            }
        }
        const int ch = c0 >> 3, cof = c0 & 7;
        #pragma unroll
        for (int j = 0; j < 16; ++j) {
            const int sl = soct * 16 + j;
            unsigned int val = (unsigned int)v0[j] | ((unsigned int)v1[j] << 16);
            *(unsigned int*)&Bs[sl * 64 + ((ch ^ (sl & 7)) << 3) + cof] = val;
        }
    }
    __syncthreads();

    f32x4 zero = {0.f, 0.f, 0.f, 0.f};
    f32x4 acc[4][4];
    #pragma unroll
    for (int i = 0; i < 4; ++i)
        #pragma unroll
        for (int j = 0; j < 4; ++j) acc[i][j] = zero;

    #pragma unroll
    for (int kk = 0; kk < 2; ++kk) {
        bf16x8 af[4], bfr[4];
        #pragma unroll
        for (int f = 0; f < 4; ++f) {
            af[f]  = fragLd(As, waveM + f * 16 + lr, kk * 4 + lk);
            bfr[f] = fragLd(Bs, waveN + f * 16 + lr, kk * 4 + lk);
        }
        #pragma unroll
        for (int fm = 0; fm < 4; ++fm)
            #pragma unroll
            for (int fn = 0; fn < 4; ++fn)
                acc[fm][fn] = __builtin_amdgcn_mfma_f32_16x16x32_bf16(af[fm], bfr[fn], acc[fm][fn], 0, 0, 0);
    }

    const float mu   = stats[n * 2 + 0] * (1.0f / CNT_PER_N);
    const float m2   = stats[n * 2 + 1] * (1.0f / CNT_PER_N);
    const float rstd = rsqrtf(m2 - mu * mu + 1e-5f);

    #pragma unroll
    for (int fn = 0; fn < 4; ++fn) {
        const int s = s0 + waveN + fn * 16 + lr;
        const int d = s >> 12, h = (s >> 6) & 63, w = s & 63;
        const int g = ((d >> 2) << 6) | ((h >> 3) << 3) | (w >> 3);
        const int p = ((d & 3) << 6) | ((h & 7) << 3) | (w & 7);
        const long gp = (long)g * 256 + p;
        #pragma unroll
        for (int fm = 0; fm < 4; ++fm) {
            #pragma unroll
            for (int i = 0; i < 4; ++i) {
                const int k = waveM + fm * 16 + lk * 4 + i;
                float v = acc[fm][fn][i] * rstd + ck[n * 128 + k];
                float ge = 0.5f * v * (1.0f + erff(v * 0.70710678118654752440f));
                unsigned short r = f2b(ge);
                if (k < 64) Au[(long)k * S_PER_N + gp] = r;
                else        Bv[((long)g * 64 + (k - 64)) * 256 + p] = r;
            }
        }
    }
}

// ---------------- transA: Au[c][g][p] -> At'[(p*64+c)][g] ----------------
// grid cnt*2048
__global__ __launch_bounds__(256) void k_transA(const unsigned short* __restrict__ Abase,
                                                unsigned short* __restrict__ AtBase) {
    __shared__ unsigned short T[64 * 66];
    const int bid = blockIdx.x;
    const int nl = bid >> 11;
    const int inner = bid & 2047;
    const unsigned short* A = Abase + (size_t)nl * 8388608;
    unsigned short* At = AtBase + (size_t)nl * 8388608;
    const int c  = inner >> 5;
    const int gt = (inner >> 2) & 7, pt = inner & 3;
    const int g0 = gt * 64, p0 = pt * 64;
    const int t = threadIdx.x;

    const int gr = t >> 2, pc = (t & 3) * 16;
    const unsigned int* s32 = (const unsigned int*)(A + (long)c * S_PER_N + (long)(g0 + gr) * 256 + p0 + pc);
    unsigned int* d32 = (unsigned int*)&T[gr * 66 + pc];
    #pragma unroll
    for (int i = 0; i < 8; ++i) d32[i] = s32[i];
    __syncthreads();

    const int pr = t >> 2, gc0 = (t & 3) * 16;
    unsigned int ov[8];
    #pragma unroll
    for (int i = 0; i < 8; ++i) {
        unsigned int lo = T[(gc0 + 2 * i) * 66 + pr];
        unsigned int hi = T[(gc0 + 2 * i + 1) * 66 + pr];
        ov[i] = lo | (hi << 16);
    }
    unsigned int* dst = (unsigned int*)(At + ((long)(p0 + pr) * 64 + c) * 512 + g0 + gc0);
    #pragma unroll
    for (int i = 0; i < 8; ++i) dst[i] = ov[i];
}

// ---------------- umix: D[m=g'(512)][n=(p*64+c)(16384)], K=g(512) -> T_U token-major ----------------
// grid cnt*512
__global__ __launch_bounds__(256) void k_umix_mfma(const unsigned short* __restrict__ BtBase,
                                                   const void* __restrict__ W2,
                                                   const void* __restrict__ b2,
                                                   const float* __restrict__ flag,
                                                   unsigned short* __restrict__ TUBase) {
    const bool f32 = flag[0] > 0.5f;
    __shared__ __align__(16) unsigned short As[128 * 64];
    __shared__ __align__(16) unsigned short Bs[128 * 64];
    const int bid = blockIdx.x;
    const int nl = bid >> 9;
    const int inner = bid & 511;
    const unsigned short* Bt = BtBase + (size_t)nl * 8388608;
    unsigned short* TU = TUBase + (size_t)nl * 8388608;
    const int mTile = inner >> 7;
    const int nTile = inner & 127;
    const int m0 = mTile * 128;
    const long btBase = (long)nTile * 128 * 512;
    const int t = threadIdx.x;
    const int lane = t & 63, wid = t >> 6;
    const int waveM = (wid >> 1) * 64, waveN = (wid & 1) * 64;
    const int lr = lane & 15, lk = lane >> 4;
    const int rS = t >> 1, c0 = (t & 1) * 4;

    f32x4 zero = {0.f, 0.f, 0.f, 0.f};
    f32x4 acc[4][4];
    #pragma unroll
    for (int i = 0; i < 4; ++i)
        #pragma unroll
        for (int j = 0; j < 4; ++j) acc[i][j] = zero;

    for (int kb = 0; kb < 512; kb += 64) {
        #pragma unroll
        for (int q = 0; q < 4; ++q)
            stage8(As, rS, c0 + q, W2, (long)(m0 + rS) * 512 + kb + (c0 + q) * 8, f32);
        #pragma unroll
        for (int q = 0; q < 4; ++q)
            stage8(Bs, rS, c0 + q, Bt, btBase + (long)rS * 512 + kb + (c0 + q) * 8, false);
        __syncthreads();
        #pragma unroll
        for (int kk = 0; kk < 2; ++kk) {
            bf16x8 af[4], bfr[4];
            #pragma unroll
            for (int f = 0; f < 4; ++f) {
                af[f]  = fragLd(As, waveM + f * 16 + lr, kk * 4 + lk);
                bfr[f] = fragLd(Bs, waveN + f * 16 + lr, kk * 4 + lk);
            }
            #pragma unroll
            for (int fm = 0; fm < 4; ++fm)
                #pragma unroll
                for (int fn = 0; fn < 4; ++fn)
                    acc[fm][fn] = __builtin_amdgcn_mfma_f32_16x16x32_bf16(af[fm], bfr[fn], acc[fm][fn], 0, 0, 0);
        }
        __syncthreads();
    }

    #pragma unroll
    for (int fn = 0; fn < 4; ++fn) {
        const int nlc = waveN + fn * 16 + lr;       // 0..127
        const int p = nTile * 2 + (nlc >> 6);
        const int c = nlc & 63;
        #pragma unroll
        for (int fm = 0; fm < 4; ++fm) {
            #pragma unroll
            for (int i = 0; i < 4; ++i) {
                const int row = m0 + waveM + fm * 16 + lk * 4 + i;   // g' 0..511
                const float bias = loadIn(b2, row, f32);
                TU[((long)row * 256 + p) * 64 + c] = f2b(acc[fm][fn][i] + bias);
            }
        }
    }
}

// ---------------- vmix: D[m=k(256)][n=(g*64+c)(32768)], K=p(256) -> T_V token-major ----------------
// grid cnt*512
__global__ __launch_bounds__(256) void k_vmix_mfma(void* __restrict__ outBase,
                                                   const void* __restrict__ W3,
                                                   const void* __restrict__ b3,
                                                   const float* __restrict__ flag,
                                                   unsigned short* __restrict__ TVBase,
                                                   int nBase) {
    const bool f32 = flag[0] > 0.5f;
    __shared__ __align__(16) unsigned short As[128 * 64];
    __shared__ __align__(16) unsigned short Bs[128 * 64];
    const int bid = blockIdx.x;
    const int nl = bid >> 9;
    const int n = nBase + nl;
    const int inner = bid & 511;
    const unsigned short* Bv = (const unsigned short*)((char*)outBase + (size_t)n * 8388608 * (f32 ? 4 : 2));
    unsigned short* TV = TVBase + (size_t)nl * 8388608;
    const int mTile = inner >> 8;       // 0..1
    const int nTile = inner & 255;      // 0..255
    const int m0 = mTile * 128;
    const int t = threadIdx.x;
    const int lane = t & 63, wid = t >> 6;
    const int waveM = (wid >> 1) * 64, waveN = (wid & 1) * 64;
    const int lr = lane & 15, lk = lane >> 4;
    const int rS = t >> 1, c0 = (t & 1) * 4;

    f32x4 zero = {0.f, 0.f, 0.f, 0.f};
    f32x4 acc[4][4];
    #pragma unroll
    for (int i = 0; i < 4; ++i)
        #pragma unroll
        for (int j = 0; j < 4; ++j) acc[i][j] = zero;

    for (int kb = 0; kb < 256; kb += 64) {
        #pragma unroll
        for (int q = 0; q < 4; ++q)
            stage8(As, rS, c0 + q, W3, (long)(m0 + rS) * 256 + kb + (c0 + q) * 8, f32);
        #pragma unroll
        for (int q = 0; q < 4; ++q)
            stage8(Bs, rS, c0 + q, Bv, ((long)nTile * 128 + rS) * 256 + kb + (c0 + q) * 8, false);
        __syncthreads();
        #pragma unroll
        for (int kk = 0; kk < 2; ++kk) {
            bf16x8 af[4], bfr[4];
            #pragma unroll
            for (int f = 0; f < 4; ++f) {
                af[f]  = fragLd(As, waveM + f * 16 + lr, kk * 4 + lk);
                bfr[f] = fragLd(Bs, waveN + f * 16 + lr, kk * 4 + lk);
            }
            #pragma unroll
            for (int fm = 0; fm < 4; ++fm)
                #pragma unroll
                for (int fn = 0; fn < 4; ++fn)
                    acc[fm][fn] = __builtin_amdgcn_mfma_f32_16x16x32_bf16(af[fm], bfr[fn], acc[fm][fn], 0, 0, 0);
        }
        __syncthreads();
    }

    #pragma unroll
    for (int fn = 0; fn < 4; ++fn) {
        const int nlc = waveN + fn * 16 + lr;
        const int g = nTile * 2 + (nlc >> 6);
        const int c = nlc & 63;
        #pragma unroll
        for (int fm = 0; fm < 4; ++fm) {
            #pragma unroll
            for (int i = 0; i < 4; ++i) {
                const int k = m0 + waveM + fm * 16 + lk * 4 + i;   // p_out 0..255
                const float bias = loadIn(b3, k, f32);
                TV[((long)g * 256 + k) * 64 + c] = f2b(acc[fm][fn][i] + bias);
            }
        }
    }
}

// ---------------- fc2: D[k=64][s-tile=128], K=128 from T_U/T_V ----------------
// grid cnt*1024
__global__ __launch_bounds__(256) void k_fc2_mfma(const unsigned short* __restrict__ TUBase,
                                                  const unsigned short* __restrict__ TVBase,
                                                  const void* __restrict__ W4,
                                                  const void* __restrict__ b4,
                                                  const float* __restrict__ flag,
                                                  void* __restrict__ out, int nBase) {
    const bool f32 = flag[0] > 0.5f;
    __shared__ __align__(16) unsigned short As[64 * 128];    // 16 KB
    __shared__ __align__(16) unsigned short Bs[128 * 128];   // 32 KB
    const int bid = blockIdx.x;
    const int nl = bid >> 10;
    const int n = nBase + nl;
    const unsigned short* TU = TUBase + (size_t)nl * 8388608;
    const unsigned short* TV = TVBase + (size_t)nl * 8388608;
    const int s0 = (bid & 1023) * 128;
    const int t = threadIdx.x;
    const int lane = t & 63, wid = t >> 6;
    const int waveN = wid * 32;
    const int lr = lane & 15, lk = lane >> 4;

    {   // stage A: W4 64 rows x 16 chunks
        const int rA = t >> 2, q0 = (t & 3) * 4;
        #pragma unroll
        for (int q = 0; q < 4; ++q)
            stage8w(As, rA, q0 + q, W4, (long)rA * 128 + (q0 + q) * 8, f32);
    }
    {   // stage B: 128 rows x 16 chunks; thread t: row = t&127, chunk-half = t>>7
        const int rB = t & 127, h8 = (t >> 7) * 8;
        const int s = s0 + rB;
        const int d = s >> 12, h = (s >> 6) & 63, w = s & 63;
        const int g = ((d >> 2) << 6) | ((h >> 3) << 3) | (w >> 3);
        const int p = ((d & 3) << 6) | ((h & 7) << 3) | (w & 7);
        const long gp = (long)g * 256 + p;
        const unsigned short* src = (h8 == 0) ? (TU + gp * 64) : (TV + gp * 64);
        #pragma unroll
        for (int q = 0; q < 8; ++q) {
            const int ch = h8 + q;
            uint4 v = *(const uint4*)(src + q * 8);
            *(uint4*)&Bs[rB * 128 + ((ch ^ (rB & 7)) << 3)] = v;
        }
    }
    __syncthreads();

    f32x4 zero = {0.f, 0.f, 0.f, 0.f};
    f32x4 acc[4][2];
    #pragma unroll
    for (int i = 0; i < 4; ++i) { acc[i][0] = zero; acc[i][1] = zero; }

    #pragma unroll
    for (int kk = 0; kk < 4; ++kk) {
        bf16x8 af[4], bfr[2];
        #pragma unroll
        for (int fm = 0; fm < 4; ++fm) af[fm] = fragLd128(As, fm * 16 + lr, kk * 4 + lk);
        #pragma unroll
        for (int fn = 0; fn < 2; ++fn) bfr[fn] = fragLd128(Bs, waveN + fn * 16 + lr, kk * 4 + lk);
        #pragma unroll
        for (int fm = 0; fm < 4; ++fm)
            #pragma unroll
            for (int fn = 0; fn < 2; ++fn)
                acc[fm][fn] = __builtin_amdgcn_mfma_f32_16x16x32_bf16(af[fm], bfr[fn], acc[fm][fn], 0, 0, 0);
    }

    #pragma unroll
    for (int fm = 0; fm < 4; ++fm) {
        #pragma unroll
        for (int fn = 0; fn < 2; ++fn) {
            const int scol = s0 + waveN + fn * 16 + lr;
            #pragma unroll
            for (int i = 0; i < 4; ++i) {
                const int k = fm * 16 + lk * 4 + i;
                const float v = acc[fm][fn][i] + loadIn(b4, k, f32);
                storeOut(out, ((long)(n * 64 + k) << 17) + scol, v, f32);
            }
        }
    }
}

extern "C" void kernel_launch(void* const* d_in, const int* in_sizes, int n_in,
                              void* d_out, int out_size, void* d_ws, size_t ws_size,
                              hipStream_t stream) {
    const void* x  = d_in[0];
    const void* W1 = d_in[1];
    const void* b1 = d_in[2];
    const void* W2 = d_in[3];
    const void* b2 = d_in[4];
    const void* W3 = d_in[5];
    const void* b3 = d_in[6];
    const void* W4 = d_in[7];
    const void* b4 = d_in[8];

    float* wsf      = (float*)d_ws;
    float* stats    = wsf;            // 8 floats
    float* flag     = wsf + 8;        // 1 float
    float* partials = wsf + 16;       // 1024 floats
    float* ck       = wsf + 1040;     // 512 floats (ends < 8192 B)

    const size_t perBuf = (size_t)8388608;                       // shorts per sample buffer (16 MiB)
    const size_t need4  = 8192 + 4ull * 2ull * perBuf * 2ull;    // 134.2 MB for full batching
    const int cnt = (ws_size >= need4) ? 4 : 1;

    unsigned short* buf1 = (unsigned short*)((char*)d_ws + 8192);
    unsigned short* buf2 = buf1 + (size_t)cnt * perBuf;

    hipLaunchKernelGGL(k_detect,   dim3(1),   dim3(256), 0, stream,
                       (const unsigned short*)x, flag);
    hipLaunchKernelGGL(k_lnstats,  dim3(512), dim3(256), 0, stream, x, flag, partials);
    hipLaunchKernelGGL(k_lnreduce, dim3(1),   dim3(64),  0, stream, partials, stats);
    hipLaunchKernelGGL(k_prep,     dim3(1),   dim3(128), 0, stream, W1, b1, stats, flag, ck);

    for (int nBase = 0; nBase < 4; nBase += cnt) {
        hipLaunchKernelGGL(k_fc1_mfma,  dim3(cnt * 1024), dim3(256), 0, stream,
                           x, stats, ck, W1, flag, buf2, d_out, nBase);
        hipLaunchKernelGGL(k_transA,    dim3(cnt * 2048), dim3(256), 0, stream, buf2, buf1);
        hipLaunchKernelGGL(k_umix_mfma, dim3(cnt * 512),  dim3(256), 0, stream,
                           buf1, W2, b2, flag, buf2);
        hipLaunchKernelGGL(k_vmix_mfma, dim3(cnt * 512),  dim3(256), 0, stream,
                           d_out, W3, b3, flag, buf1, nBase);
        hipLaunchKernelGGL(k_fc2_mfma,  dim3(cnt * 1024), dim3(256), 0, stream,
                           buf2, buf1, W4, b4, flag, d_out, nBase);
    }
}

// Round 8
// 472.920 us; speedup vs baseline: 3.3540x; 1.0781x over previous
//
#include <hip/hip_runtime.h>
#include <hip/hip_bf16.h>
#include <math.h>

// Geometry (fixed):
//   x: (N=4, C=64, D=32, H=64, W=64); S = 131072 = G*P, G=512, P=256
//   W1 (128,64) b1(128) | W2 (512,512) b2(512) | W3 (256,256) b3(256) | W4 (64,128) b4(64)
// Blocked index: g=(d>>2)*64+(h>>3)*8+(w>>3); p=(d&3)*64+(h&7)*8+(w&7)
//
// Full-MFMA pipeline, batched over samples (cnt = 4 if ws fits, else per-sample):
//   fc1:    per-g-tile GEMM X_g^T(256xK64) x W1^T -> D[p][j]; LN folded, GELU;
//           j<64  -> Au[c][g][p]      (buf2[nl])   (512B-contiguous runs)
//           j>=64 -> Bv[g][c][p]      (d_out region n)
//   transA: Au -> At'[(p*64+c)][g]    (buf1[nl])
//   umix:   GEMM W2 x At'^T -> T_U[(g'*256+p)*64+c]   (buf2[nl], Au dead)
//   vmix:   GEMM W3 x Bv^T  -> T_V[(g*256+k)*64+c]    (buf1[nl], At' dead)
//   fc2:    GEMM W4 x cat(T_U,T_V)^T + b4 -> out n    (Bv dead)

#define S_PER_N 131072
#define CNT_PER_N 8388608.0f

typedef __attribute__((ext_vector_type(8))) short bf16x8;
typedef __attribute__((ext_vector_type(4))) float f32x4;

__device__ __forceinline__ float b2f(unsigned short u) {
    return __uint_as_float(((unsigned int)u) << 16);
}
__device__ __forceinline__ unsigned short f2b(float f) {
    unsigned int i = __float_as_uint(f);
    unsigned int r = i + 0x7FFFu + ((i >> 16) & 1u);
    return (unsigned short)(r >> 16);
}
__device__ __forceinline__ float loadIn(const void* p, long i, bool f32) {
    return f32 ? ((const float*)p)[i] : b2f(((const unsigned short*)p)[i]);
}
__device__ __forceinline__ void storeOut(void* p, long i, float v, bool f32) {
    if (f32) ((float*)p)[i] = v;
    else ((unsigned short*)p)[i] = f2b(v);
}

// ---------------- dtype detect + LN stats (proven) ----------------

__global__ void k_detect(const unsigned short* __restrict__ xw, float* __restrict__ flag) {
    __shared__ int sh[256];
    int tid = threadIdx.x;
    int sane = 0;
    for (int i = tid; i < 4096; i += 256) {
        int e = (xw[i] >> 7) & 0xFF;
        sane += (e >= 110 && e <= 130) ? 1 : 0;
    }
    sh[tid] = sane; __syncthreads();
    for (int off = 128; off; off >>= 1) {
        if (tid < off) sh[tid] += sh[tid + off];
        __syncthreads();
    }
    if (tid == 0) flag[0] = (sh[0] >= 3300) ? 0.0f : 1.0f;
}

__global__ __launch_bounds__(256) void k_lnstats(const void* __restrict__ xp,
                                                 const float* __restrict__ flag,
                                                 float* __restrict__ partials) {
    const bool f32 = flag[0] > 0.5f;
    const int bid = blockIdx.x;
    const long base = (long)bid * 65536;
    float s = 0.0f, sq = 0.0f;
    if (f32) {
        const float4* xv = (const float4*)((const float*)xp + base);
        for (int it = 0; it < 64; ++it) {
            float4 v = xv[it * 256 + threadIdx.x];
            s  += v.x + v.y + v.z + v.w;
            sq += v.x*v.x + v.y*v.y + v.z*v.z + v.w*v.w;
        }
    } else {
        const uint4* xv = (const uint4*)((const unsigned short*)xp + base);
        for (int it = 0; it < 32; ++it) {
            uint4 v = xv[it * 256 + threadIdx.x];
            unsigned int ws4[4] = {v.x, v.y, v.z, v.w};
            #pragma unroll
            for (int q = 0; q < 4; ++q) {
                float f0 = b2f((unsigned short)(ws4[q] & 0xFFFFu));
                float f1 = b2f((unsigned short)(ws4[q] >> 16));
                s += f0 + f1;
                sq += f0 * f0 + f1 * f1;
            }
        }
    }
    __shared__ float ls[256], lq[256];
    ls[threadIdx.x] = s; lq[threadIdx.x] = sq;
    __syncthreads();
    for (int off = 128; off > 0; off >>= 1) {
        if (threadIdx.x < off) {
            ls[threadIdx.x] += ls[threadIdx.x + off];
            lq[threadIdx.x] += lq[threadIdx.x + off];
        }
        __syncthreads();
    }
    if (threadIdx.x == 0) {
        partials[bid * 2 + 0] = ls[0];
        partials[bid * 2 + 1] = lq[0];
    }
}

__global__ void k_lnreduce(const float* __restrict__ partials, float* __restrict__ stats) {
    const int t = threadIdx.x;
    if (t < 4) {
        float s = 0.0f, sq = 0.0f;
        for (int i = 0; i < 128; ++i) {
            s  += partials[(t * 128 + i) * 2 + 0];
            sq += partials[(t * 128 + i) * 2 + 1];
        }
        stats[t * 2 + 0] = s;
        stats[t * 2 + 1] = sq;
    }
}

// ck[n][k] = b1[k] - rstd_n * mu_n * rowsum(W1[k])
__global__ void k_prep(const void* __restrict__ W1, const void* __restrict__ b1,
                       const float* __restrict__ stats, const float* __restrict__ flag,
                       float* __restrict__ ck) {
    const bool f32 = flag[0] > 0.5f;
    const int k = threadIdx.x;     // 128
    float rs = 0.0f;
    for (int c = 0; c < 64; ++c) rs += loadIn(W1, (long)k * 64 + c, f32);
    const float bb = loadIn(b1, k, f32);
    for (int n = 0; n < 4; ++n) {
        const float mu   = stats[n * 2 + 0] * (1.0f / CNT_PER_N);
        const float m2   = stats[n * 2 + 1] * (1.0f / CNT_PER_N);
        const float rstd = rsqrtf(m2 - mu * mu + 1e-5f);
        ck[n * 128 + k] = bb - rstd * mu * rs;
    }
}

// ---------------- MFMA staging helpers ----------------
// 64-wide rows (8 chunks of 8 bf16), chunk XOR-swizzled by row.
__device__ __forceinline__ void stage8(unsigned short* lds, int r, int c,
                                       const void* gp, long gidx, bool f32) {
    const int dst = r * 64 + ((c ^ (r & 7)) << 3);
    uint4 v;
    if (f32) {
        const float* s = (const float*)gp + gidx;
        float4 a = *(const float4*)s;
        float4 b = *(const float4*)(s + 4);
        v.x = (unsigned int)f2b(a.x) | ((unsigned int)f2b(a.y) << 16);
        v.y = (unsigned int)f2b(a.z) | ((unsigned int)f2b(a.w) << 16);
        v.z = (unsigned int)f2b(b.x) | ((unsigned int)f2b(b.y) << 16);
        v.w = (unsigned int)f2b(b.z) | ((unsigned int)f2b(b.w) << 16);
    } else {
        v = *(const uint4*)((const unsigned short*)gp + gidx);
    }
    *(uint4*)&lds[dst] = v;
}
__device__ __forceinline__ bf16x8 fragLd(const unsigned short* lds, int r, int c) {
    return *(const bf16x8*)&lds[r * 64 + ((c ^ (r & 7)) << 3)];
}
// 128-wide rows (16 chunks), same swizzle idea.
__device__ __forceinline__ void stage8w(unsigned short* lds, int r, int c,
                                        const void* gp, long gidx, bool f32) {
    const int dst = r * 128 + ((c ^ (r & 7)) << 3);
    uint4 v;
    if (f32) {
        const float* s = (const float*)gp + gidx;
        float4 a = *(const float4*)s;
        float4 b = *(const float4*)(s + 4);
        v.x = (unsigned int)f2b(a.x) | ((unsigned int)f2b(a.y) << 16);
        v.y = (unsigned int)f2b(a.z) | ((unsigned int)f2b(a.w) << 16);
        v.z = (unsigned int)f2b(b.x) | ((unsigned int)f2b(b.y) << 16);
        v.w = (unsigned int)f2b(b.z) | ((unsigned int)f2b(b.w) << 16);
    } else {
        v = *(const uint4*)((const unsigned short*)gp + gidx);
    }
    *(uint4*)&lds[dst] = v;
}
__device__ __forceinline__ bf16x8 fragLd128(const unsigned short* lds, int r, int c) {
    return *(const bf16x8*)&lds[r * 128 + ((c ^ (r & 7)) << 3)];
}

// ---------------- fc1 (g-tile): D[p=256][j=128], K=64; LN folded, GELU ----------------
// grid cnt*512, one block per (sample, g). XCD swizzle: contiguous g chunks per XCD.
// mfma(bp, aj): D[row=p][col=j] -> per-lane 4 consecutive p at fixed j -> uint2 stores.
__global__ __launch_bounds__(256) void k_fc1_mfma(const void* __restrict__ xp,
                                                  const float* __restrict__ stats,
                                                  const float* __restrict__ ck,
                                                  const void* __restrict__ W1,
                                                  const float* __restrict__ flag,
                                                  unsigned short* __restrict__ AuBase,
                                                  void* __restrict__ outBase, int nBase) {
    const bool f32 = flag[0] > 0.5f;
    __shared__ __align__(16) unsigned short As[128 * 64];   // W1 [j][c]
    __shared__ __align__(16) unsigned short Bs[256 * 64];   // X^T [p][c]
    const int nwg = gridDim.x;
    const int cpx = nwg >> 3;                                // nwg % 8 == 0 (512 or 2048)
    const int work = (blockIdx.x & 7) * cpx + (blockIdx.x >> 3);
    const int nl = work >> 9;
    const int n = nBase + nl;
    const int g = work & 511;
    const int d0 = (g >> 6) * 4, h0 = ((g >> 3) & 7) * 8, w0 = (g & 7) * 8;
    const int t = threadIdx.x;
    const int lane = t & 63, wid = t >> 6;
    const int waveP = wid * 64;
    const int lr = lane & 15, lk = lane >> 4;

    unsigned short* Au = AuBase + (size_t)nl * 8388608;
    unsigned short* Bv = (unsigned short*)((char*)outBase + (size_t)n * 8388608 * (f32 ? 4 : 2));

    {   // stage A: W1 (128 x 64)
        const int rS = t >> 1, c04 = (t & 1) * 4;
        #pragma unroll
        for (int q = 0; q < 4; ++q)
            stage8(As, rS, c04 + q, W1, (long)rS * 64 + (c04 + q) * 8, f32);
    }
    {   // stage B: x g-block -> Bs[p][c], fused fp32->bf16, swizzled u32 writes
        const int c0 = (t & 31) * 2;
        const int rdh = t >> 5;                  // 0..7
        const long cbase = ((long)(n * 64 + c0)) << 17;
        const int ch = c0 >> 3, cof = c0 & 7;
        #pragma unroll
        for (int q = 0; q < 4; ++q) {
            const int dh = rdh * 4 + q;          // 0..31
            const int dp = dh >> 3, hp = dh & 7;
            const long sb = (long)(d0 + dp) * 4096 + (h0 + hp) * 64 + w0;
            unsigned short v0[8], v1[8];
            if (f32) {
                const float* r0 = (const float*)xp + cbase + sb;
                const float* r1 = r0 + S_PER_N;
                float4 a0 = *(const float4*)r0, a1 = *(const float4*)(r0 + 4);
                float4 b0 = *(const float4*)r1, b1v = *(const float4*)(r1 + 4);
                v0[0]=f2b(a0.x); v0[1]=f2b(a0.y); v0[2]=f2b(a0.z); v0[3]=f2b(a0.w);
                v0[4]=f2b(a1.x); v0[5]=f2b(a1.y); v0[6]=f2b(a1.z); v0[7]=f2b(a1.w);
                v1[0]=f2b(b0.x); v1[1]=f2b(b0.y); v1[2]=f2b(b0.z); v1[3]=f2b(b0.w);
                v1[4]=f2b(b1v.x); v1[5]=f2b(b1v.y); v1[6]=f2b(b1v.z); v1[7]=f2b(b1v.w);
            } else {
                const unsigned short* r0 = (const unsigned short*)xp + cbase + sb;
                uint4 a = *(const uint4*)r0;
                uint4 b = *(const uint4*)(r0 + S_PER_N);
                const unsigned short* pa = (const unsigned short*)&a;
                const unsigned short* pb = (const unsigned short*)&b;
                #pragma unroll
                for (int j = 0; j < 8; ++j) { v0[j] = pa[j]; v1[j] = pb[j]; }
            }
            const int pbase = dp * 64 + hp * 8;
            #pragma unroll
            for (int j = 0; j < 8; ++j) {
                const int pj = pbase + j;
                unsigned int val = (unsigned int)v0[j] | ((unsigned int)v1[j] << 16);
                *(unsigned int*)&Bs[pj * 64 + ((ch ^ (pj & 7)) << 3) + cof] = val;
            }
        }
    }
    __syncthreads();

    const float mu   = stats[n * 2 + 0] * (1.0f / CNT_PER_N);
    const float m2   = stats[n * 2 + 1] * (1.0f / CNT_PER_N);
    const float rstd = rsqrtf(m2 - mu * mu + 1e-5f);

    #pragma unroll
    for (int half = 0; half < 2; ++half) {
        f32x4 zero = {0.f, 0.f, 0.f, 0.f};
        f32x4 acc[4][4];
        #pragma unroll
        for (int i = 0; i < 4; ++i)
            #pragma unroll
            for (int j = 0; j < 4; ++j) acc[i][j] = zero;

        #pragma unroll
        for (int kk = 0; kk < 2; ++kk) {
            bf16x8 bp[4], aj[4];
            #pragma unroll
            for (int f = 0; f < 4; ++f) {
                bp[f] = fragLd(Bs, waveP + f * 16 + lr, kk * 4 + lk);
                aj[f] = fragLd(As, half * 64 + f * 16 + lr, kk * 4 + lk);
            }
            #pragma unroll
            for (int fp = 0; fp < 4; ++fp)
                #pragma unroll
                for (int fj = 0; fj < 4; ++fj)
                    acc[fp][fj] = __builtin_amdgcn_mfma_f32_16x16x32_bf16(bp[fp], aj[fj], acc[fp][fj], 0, 0, 0);
        }

        #pragma unroll
        for (int fj = 0; fj < 4; ++fj) {
            const int j = half * 64 + fj * 16 + lr;
            const float ckj = ck[n * 128 + j];
            #pragma unroll
            for (int fp = 0; fp < 4; ++fp) {
                const int pb = waveP + fp * 16 + lk * 4;
                unsigned short o[4];
                #pragma unroll
                for (int i = 0; i < 4; ++i) {
                    float v = acc[fp][fj][i] * rstd + ckj;
                    float ge = 0.5f * v * (1.0f + erff(v * 0.70710678118654752440f));
                    o[i] = f2b(ge);
                }
                uint2 pk;
                pk.x = (unsigned int)o[0] | ((unsigned int)o[1] << 16);
                pk.y = (unsigned int)o[2] | ((unsigned int)o[3] << 16);
                if (half == 0) {
                    *(uint2*)&Au[(long)j * S_PER_N + g * 256 + pb] = pk;
                } else {
                    *(uint2*)&Bv[((long)g * 64 + (j - 64)) * 256 + pb] = pk;
                }
            }
        }
    }
}

// ---------------- transA: Au[c][g][p] -> At'[(p*64+c)][g] ----------------
// grid cnt*2048
__global__ __launch_bounds__(256) void k_transA(const unsigned short* __restrict__ Abase,
                                                unsigned short* __restrict__ AtBase) {
    __shared__ unsigned short T[64 * 66];
    const int bid = blockIdx.x;
    const int nl = bid >> 11;
    const int inner = bid & 2047;
    const unsigned short* A = Abase + (size_t)nl * 8388608;
    unsigned short* At = AtBase + (size_t)nl * 8388608;
    const int c  = inner >> 5;
    const int gt = (inner >> 2) & 7, pt = inner & 3;
    const int g0 = gt * 64, p0 = pt * 64;
    const int t = threadIdx.x;

    const int gr = t >> 2, pc = (t & 3) * 16;
    const unsigned int* s32 = (const unsigned int*)(A + (long)c * S_PER_N + (long)(g0 + gr) * 256 + p0 + pc);
    unsigned int* d32 = (unsigned int*)&T[gr * 66 + pc];
    #pragma unroll
    for (int i = 0; i < 8; ++i) d32[i] = s32[i];
    __syncthreads();

    const int pr = t >> 2, gc0 = (t & 3) * 16;
    unsigned int ov[8];
    #pragma unroll
    for (int i = 0; i < 8; ++i) {
        unsigned int lo = T[(gc0 + 2 * i) * 66 + pr];
        unsigned int hi = T[(gc0 + 2 * i + 1) * 66 + pr];
        ov[i] = lo | (hi << 16);
    }
    unsigned int* dst = (unsigned int*)(At + ((long)(p0 + pr) * 64 + c) * 512 + g0 + gc0);
    #pragma unroll
    for (int i = 0; i < 8; ++i) dst[i] = ov[i];
}

// ---------------- umix: D[m=g'(512)][n=(p*64+c)(16384)], K=g(512) -> T_U token-major ----------------
// grid cnt*512
__global__ __launch_bounds__(256) void k_umix_mfma(const unsigned short* __restrict__ BtBase,
                                                   const void* __restrict__ W2,
                                                   const void* __restrict__ b2,
                                                   const float* __restrict__ flag,
                                                   unsigned short* __restrict__ TUBase) {
    const bool f32 = flag[0] > 0.5f;
    __shared__ __align__(16) unsigned short As[128 * 64];
    __shared__ __align__(16) unsigned short Bs[128 * 64];
    const int bid = blockIdx.x;
    const int nl = bid >> 9;
    const int inner = bid & 511;
    const unsigned short* Bt = BtBase + (size_t)nl * 8388608;
    unsigned short* TU = TUBase + (size_t)nl * 8388608;
    const int mTile = inner >> 7;
    const int nTile = inner & 127;
    const int m0 = mTile * 128;
    const long btBase = (long)nTile * 128 * 512;
    const int t = threadIdx.x;
    const int lane = t & 63, wid = t >> 6;
    const int waveM = (wid >> 1) * 64, waveN = (wid & 1) * 64;
    const int lr = lane & 15, lk = lane >> 4;
    const int rS = t >> 1, c0 = (t & 1) * 4;

    f32x4 zero = {0.f, 0.f, 0.f, 0.f};
    f32x4 acc[4][4];
    #pragma unroll
    for (int i = 0; i < 4; ++i)
        #pragma unroll
        for (int j = 0; j < 4; ++j) acc[i][j] = zero;

    for (int kb = 0; kb < 512; kb += 64) {
        #pragma unroll
        for (int q = 0; q < 4; ++q)
            stage8(As, rS, c0 + q, W2, (long)(m0 + rS) * 512 + kb + (c0 + q) * 8, f32);
        #pragma unroll
        for (int q = 0; q < 4; ++q)
            stage8(Bs, rS, c0 + q, Bt, btBase + (long)rS * 512 + kb + (c0 + q) * 8, false);
        __syncthreads();
        #pragma unroll
        for (int kk = 0; kk < 2; ++kk) {
            bf16x8 af[4], bfr[4];
            #pragma unroll
            for (int f = 0; f < 4; ++f) {
                af[f]  = fragLd(As, waveM + f * 16 + lr, kk * 4 + lk);
                bfr[f] = fragLd(Bs, waveN + f * 16 + lr, kk * 4 + lk);
            }
            #pragma unroll
            for (int fm = 0; fm < 4; ++fm)
                #pragma unroll
                for (int fn = 0; fn < 4; ++fn)
                    acc[fm][fn] = __builtin_amdgcn_mfma_f32_16x16x32_bf16(af[fm], bfr[fn], acc[fm][fn], 0, 0, 0);
        }
        __syncthreads();
    }

    #pragma unroll
    for (int fn = 0; fn < 4; ++fn) {
        const int nlc = waveN + fn * 16 + lr;       // 0..127
        const int p = nTile * 2 + (nlc >> 6);
        const int c = nlc & 63;
        #pragma unroll
        for (int fm = 0; fm < 4; ++fm) {
            #pragma unroll
            for (int i = 0; i < 4; ++i) {
                const int row = m0 + waveM + fm * 16 + lk * 4 + i;   // g' 0..511
                const float bias = loadIn(b2, row, f32);
                TU[((long)row * 256 + p) * 64 + c] = f2b(acc[fm][fn][i] + bias);
            }
        }
    }
}

// ---------------- vmix: D[m=k(256)][n=(g*64+c)(32768)], K=p(256) -> T_V token-major ----------------
// grid cnt*512
__global__ __launch_bounds__(256) void k_vmix_mfma(void* __restrict__ outBase,
                                                   const void* __restrict__ W3,
                                                   const void* __restrict__ b3,
                                                   const float* __restrict__ flag,
                                                   unsigned short* __restrict__ TVBase,
                                                   int nBase) {
    const bool f32 = flag[0] > 0.5f;
    __shared__ __align__(16) unsigned short As[128 * 64];
    __shared__ __align__(16) unsigned short Bs[128 * 64];
    const int bid = blockIdx.x;
    const int nl = bid >> 9;
    const int n = nBase + nl;
    const int inner = bid & 511;
    const unsigned short* Bv = (const unsigned short*)((char*)outBase + (size_t)n * 8388608 * (f32 ? 4 : 2));
    unsigned short* TV = TVBase + (size_t)nl * 8388608;
    const int mTile = inner >> 8;       // 0..1
    const int nTile = inner & 255;      // 0..255
    const int m0 = mTile * 128;
    const int t = threadIdx.x;
    const int lane = t & 63, wid = t >> 6;
    const int waveM = (wid >> 1) * 64, waveN = (wid & 1) * 64;
    const int lr = lane & 15, lk = lane >> 4;
    const int rS = t >> 1, c0 = (t & 1) * 4;

    f32x4 zero = {0.f, 0.f, 0.f, 0.f};
    f32x4 acc[4][4];
    #pragma unroll
    for (int i = 0; i < 4; ++i)
        #pragma unroll
        for (int j = 0; j < 4; ++j) acc[i][j] = zero;

    for (int kb = 0; kb < 256; kb += 64) {
        #pragma unroll
        for (int q = 0; q < 4; ++q)
            stage8(As, rS, c0 + q, W3, (long)(m0 + rS) * 256 + kb + (c0 + q) * 8, f32);
        #pragma unroll
        for (int q = 0; q < 4; ++q)
            stage8(Bs, rS, c0 + q, Bv, ((long)nTile * 128 + rS) * 256 + kb + (c0 + q) * 8, false);
        __syncthreads();
        #pragma unroll
        for (int kk = 0; kk < 2; ++kk) {
            bf16x8 af[4], bfr[4];
            #pragma unroll
            for (int f = 0; f < 4; ++f) {
                af[f]  = fragLd(As, waveM + f * 16 + lr, kk * 4 + lk);
                bfr[f] = fragLd(Bs, waveN + f * 16 + lr, kk * 4 + lk);
            }
            #pragma unroll
            for (int fm = 0; fm < 4; ++fm)
                #pragma unroll
                for (int fn = 0; fn < 4; ++fn)
                    acc[fm][fn] = __builtin_amdgcn_mfma_f32_16x16x32_bf16(af[fm], bfr[fn], acc[fm][fn], 0, 0, 0);
        }
        __syncthreads();
    }

    #pragma unroll
    for (int fn = 0; fn < 4; ++fn) {
        const int nlc = waveN + fn * 16 + lr;
        const int g = nTile * 2 + (nlc >> 6);
        const int c = nlc & 63;
        #pragma unroll
        for (int fm = 0; fm < 4; ++fm) {
            #pragma unroll
            for (int i = 0; i < 4; ++i) {
                const int k = m0 + waveM + fm * 16 + lk * 4 + i;   // p_out 0..255
                const float bias = loadIn(b3, k, f32);
                TV[((long)g * 256 + k) * 64 + c] = f2b(acc[fm][fn][i] + bias);
            }
        }
    }
}

// ---------------- fc2: D[k=64][s-tile=128], K=128 from T_U/T_V ----------------
// grid cnt*1024
__global__ __launch_bounds__(256) void k_fc2_mfma(const unsigned short* __restrict__ TUBase,
                                                  const unsigned short* __restrict__ TVBase,
                                                  const void* __restrict__ W4,
                                                  const void* __restrict__ b4,
                                                  const float* __restrict__ flag,
                                                  void* __restrict__ out, int nBase) {
    const bool f32 = flag[0] > 0.5f;
    __shared__ __align__(16) unsigned short As[64 * 128];    // 16 KB
    __shared__ __align__(16) unsigned short Bs[128 * 128];   // 32 KB
    const int bid = blockIdx.x;
    const int nl = bid >> 10;
    const int n = nBase + nl;
    const unsigned short* TU = TUBase + (size_t)nl * 8388608;
    const unsigned short* TV = TVBase + (size_t)nl * 8388608;
    const int s0 = (bid & 1023) * 128;
    const int t = threadIdx.x;
    const int lane = t & 63, wid = t >> 6;
    const int waveN = wid * 32;
    const int lr = lane & 15, lk = lane >> 4;

    {   // stage A: W4 64 rows x 16 chunks
        const int rA = t >> 2, q0 = (t & 3) * 4;
        #pragma unroll
        for (int q = 0; q < 4; ++q)
            stage8w(As, rA, q0 + q, W4, (long)rA * 128 + (q0 + q) * 8, f32);
    }
    {   // stage B: 128 rows x 16 chunks; thread t: row = t&127, chunk-half = t>>7
        const int rB = t & 127, h8 = (t >> 7) * 8;
        const int s = s0 + rB;
        const int d = s >> 12, h = (s >> 6) & 63, w = s & 63;
        const int g = ((d >> 2) << 6) | ((h >> 3) << 3) | (w >> 3);
        const int p = ((d & 3) << 6) | ((h & 7) << 3) | (w & 7);
        const long gp = (long)g * 256 + p;
        const unsigned short* src = (h8 == 0) ? (TU + gp * 64) : (TV + gp * 64);
        #pragma unroll
        for (int q = 0; q < 8; ++q) {
            const int ch = h8 + q;
            uint4 v = *(const uint4*)(src + q * 8);
            *(uint4*)&Bs[rB * 128 + ((ch ^ (rB & 7)) << 3)] = v;
        }
    }
    __syncthreads();

    f32x4 zero = {0.f, 0.f, 0.f, 0.f};
    f32x4 acc[4][2];
    #pragma unroll
    for (int i = 0; i < 4; ++i) { acc[i][0] = zero; acc[i][1] = zero; }

    #pragma unroll
    for (int kk = 0; kk < 4; ++kk) {
        bf16x8 af[4], bfr[2];
        #pragma unroll
        for (int fm = 0; fm < 4; ++fm) af[fm] = fragLd128(As, fm * 16 + lr, kk * 4 + lk);
        #pragma unroll
        for (int fn = 0; fn < 2; ++fn) bfr[fn] = fragLd128(Bs, waveN + fn * 16 + lr, kk * 4 + lk);
        #pragma unroll
        for (int fm = 0; fm < 4; ++fm)
            #pragma unroll
            for (int fn = 0; fn < 2; ++fn)
                acc[fm][fn] = __builtin_amdgcn_mfma_f32_16x16x32_bf16(af[fm], bfr[fn], acc[fm][fn], 0, 0, 0);
    }

    #pragma unroll
    for (int fm = 0; fm < 4; ++fm) {
        #pragma unroll
        for (int fn = 0; fn < 2; ++fn) {
            const int scol = s0 + waveN + fn * 16 + lr;
            #pragma unroll
            for (int i = 0; i < 4; ++i) {
                const int k = fm * 16 + lk * 4 + i;
                const float v = acc[fm][fn][i] + loadIn(b4, k, f32);
                storeOut(out, ((long)(n * 64 + k) << 17) + scol, v, f32);
            }
        }
    }
}

extern "C" void kernel_launch(void* const* d_in, const int* in_sizes, int n_in,
                              void* d_out, int out_size, void* d_ws, size_t ws_size,
                              hipStream_t stream) {
    const void* x  = d_in[0];
    const void* W1 = d_in[1];
    const void* b1 = d_in[2];
    const void* W2 = d_in[3];
    const void* b2 = d_in[4];
    const void* W3 = d_in[5];
    const void* b3 = d_in[6];
    const void* W4 = d_in[7];
    const void* b4 = d_in[8];

    float* wsf      = (float*)d_ws;
    float* stats    = wsf;            // 8 floats
    float* flag     = wsf + 8;        // 1 float
    float* partials = wsf + 16;       // 1024 floats
    float* ck       = wsf + 1040;     // 512 floats (ends < 8192 B)

    const size_t perBuf = (size_t)8388608;                       // shorts per sample buffer (16 MiB)
    const size_t need4  = 8192 + 4ull * 2ull * perBuf * 2ull;    // 134.2 MB for full batching
    const int cnt = (ws_size >= need4) ? 4 : 1;

    unsigned short* buf1 = (unsigned short*)((char*)d_ws + 8192);
    unsigned short* buf2 = buf1 + (size_t)cnt * perBuf;

    hipLaunchKernelGGL(k_detect,   dim3(1),   dim3(256), 0, stream,
                       (const unsigned short*)x, flag);
    hipLaunchKernelGGL(k_lnstats,  dim3(512), dim3(256), 0, stream, x, flag, partials);
    hipLaunchKernelGGL(k_lnreduce, dim3(1),   dim3(64),  0, stream, partials, stats);
    hipLaunchKernelGGL(k_prep,     dim3(1),   dim3(128), 0, stream, W1, b1, stats, flag, ck);

    for (int nBase = 0; nBase < 4; nBase += cnt) {
        hipLaunchKernelGGL(k_fc1_mfma,  dim3(cnt * 512),  dim3(256), 0, stream,
                           x, stats, ck, W1, flag, buf2, d_out, nBase);
        hipLaunchKernelGGL(k_transA,    dim3(cnt * 2048), dim3(256), 0, stream, buf2, buf1);
        hipLaunchKernelGGL(k_umix_mfma, dim3(cnt * 512),  dim3(256), 0, stream,
                           buf1, W2, b2, flag, buf2);
        hipLaunchKernelGGL(k_vmix_mfma, dim3(cnt * 512),  dim3(256), 0, stream,
                           d_out, W3, b3, flag, buf1, nBase);
        hipLaunchKernelGGL(k_fc2_mfma,  dim3(cnt * 1024), dim3(256), 0, stream,
                           buf2, buf1, W4, b4, flag, d_out, nBase);
    }
}

// Round 9
// 361.874 us; speedup vs baseline: 4.3832x; 1.3069x over previous
//
#include <hip/hip_runtime.h>
#include <hip/hip_bf16.h>
#include <math.h>

// Geometry (fixed):
//   x: (N=4, C=64, D=32, H=64, W=64); S = 131072 = G*P, G=512, P=256
//   W1 (128,64) b1(128) | W2 (512,512) b2(512) | W3 (256,256) b3(256) | W4 (64,128) b4(64)
// Blocked index: g=(d>>2)*64+(h>>3)*8+(w>>3); p=(d&3)*64+(h&7)*8+(w&7)
//
// Pipeline (batched over samples; cnt=4 if ws fits):
//   prepW:  W2,W3 -> bf16 copies in ws (once)
//   fc1:    per-g GEMM, LN folded, GELU -> Au[c][g][p] (buf2), Bv[g][c][p] (d_out n)
//   transA: Au -> At'[(p*64+c)][g]    (buf1)
//   umix:   GEMM (global_load_lds staged) -> T_U[(g'*256+p)*64+c] (buf2)
//   vmix:   GEMM (global_load_lds staged) -> T_V[(g*256+k)*64+c]  (buf1)
//   fc2:    GEMM W4 x cat(T_U,T_V)^T + b4 -> out n

#define S_PER_N 131072
#define CNT_PER_N 8388608.0f

typedef __attribute__((ext_vector_type(8))) short bf16x8;
typedef __attribute__((ext_vector_type(4))) float f32x4;

__device__ __forceinline__ float b2f(unsigned short u) {
    return __uint_as_float(((unsigned int)u) << 16);
}
__device__ __forceinline__ unsigned short f2b(float f) {
    unsigned int i = __float_as_uint(f);
    unsigned int r = i + 0x7FFFu + ((i >> 16) & 1u);
    return (unsigned short)(r >> 16);
}
__device__ __forceinline__ float loadIn(const void* p, long i, bool f32) {
    return f32 ? ((const float*)p)[i] : b2f(((const unsigned short*)p)[i]);
}
__device__ __forceinline__ void storeOut(void* p, long i, float v, bool f32) {
    if (f32) ((float*)p)[i] = v;
    else ((unsigned short*)p)[i] = f2b(v);
}
// async global->LDS, 16B per lane; LDS dest = uniform base + lane*16
__device__ __forceinline__ void gld16(const unsigned short* g, unsigned short* l) {
    __builtin_amdgcn_global_load_lds(
        (const __attribute__((address_space(1))) void*)g,
        (__attribute__((address_space(3))) void*)l,
        16, 0, 0);
}

// ---------------- dtype detect + LN stats (proven) ----------------

__global__ void k_detect(const unsigned short* __restrict__ xw, float* __restrict__ flag) {
    __shared__ int sh[256];
    int tid = threadIdx.x;
    int sane = 0;
    for (int i = tid; i < 4096; i += 256) {
        int e = (xw[i] >> 7) & 0xFF;
        sane += (e >= 110 && e <= 130) ? 1 : 0;
    }
    sh[tid] = sane; __syncthreads();
    for (int off = 128; off; off >>= 1) {
        if (tid < off) sh[tid] += sh[tid + off];
        __syncthreads();
    }
    if (tid == 0) flag[0] = (sh[0] >= 3300) ? 0.0f : 1.0f;
}

__global__ __launch_bounds__(256) void k_lnstats(const void* __restrict__ xp,
                                                 const float* __restrict__ flag,
                                                 float* __restrict__ partials) {
    const bool f32 = flag[0] > 0.5f;
    const int bid = blockIdx.x;
    const long base = (long)bid * 65536;
    float s = 0.0f, sq = 0.0f;
    if (f32) {
        const float4* xv = (const float4*)((const float*)xp + base);
        for (int it = 0; it < 64; ++it) {
            float4 v = xv[it * 256 + threadIdx.x];
            s  += v.x + v.y + v.z + v.w;
            sq += v.x*v.x + v.y*v.y + v.z*v.z + v.w*v.w;
        }
    } else {
        const uint4* xv = (const uint4*)((const unsigned short*)xp + base);
        for (int it = 0; it < 32; ++it) {
            uint4 v = xv[it * 256 + threadIdx.x];
            unsigned int ws4[4] = {v.x, v.y, v.z, v.w};
            #pragma unroll
            for (int q = 0; q < 4; ++q) {
                float f0 = b2f((unsigned short)(ws4[q] & 0xFFFFu));
                float f1 = b2f((unsigned short)(ws4[q] >> 16));
                s += f0 + f1;
                sq += f0 * f0 + f1 * f1;
            }
        }
    }
    __shared__ float ls[256], lq[256];
    ls[threadIdx.x] = s; lq[threadIdx.x] = sq;
    __syncthreads();
    for (int off = 128; off > 0; off >>= 1) {
        if (threadIdx.x < off) {
            ls[threadIdx.x] += ls[threadIdx.x + off];
            lq[threadIdx.x] += lq[threadIdx.x + off];
        }
        __syncthreads();
    }
    if (threadIdx.x == 0) {
        partials[bid * 2 + 0] = ls[0];
        partials[bid * 2 + 1] = lq[0];
    }
}

__global__ void k_lnreduce(const float* __restrict__ partials, float* __restrict__ stats) {
    const int t = threadIdx.x;
    if (t < 4) {
        float s = 0.0f, sq = 0.0f;
        for (int i = 0; i < 128; ++i) {
            s  += partials[(t * 128 + i) * 2 + 0];
            sq += partials[(t * 128 + i) * 2 + 1];
        }
        stats[t * 2 + 0] = s;
        stats[t * 2 + 1] = sq;
    }
}

// ck[n][k] = b1[k] - rstd_n * mu_n * rowsum(W1[k])
__global__ void k_prep(const void* __restrict__ W1, const void* __restrict__ b1,
                       const float* __restrict__ stats, const float* __restrict__ flag,
                       float* __restrict__ ck) {
    const bool f32 = flag[0] > 0.5f;
    const int k = threadIdx.x;     // 128
    float rs = 0.0f;
    for (int c = 0; c < 64; ++c) rs += loadIn(W1, (long)k * 64 + c, f32);
    const float bb = loadIn(b1, k, f32);
    for (int n = 0; n < 4; ++n) {
        const float mu   = stats[n * 2 + 0] * (1.0f / CNT_PER_N);
        const float m2   = stats[n * 2 + 1] * (1.0f / CNT_PER_N);
        const float rstd = rsqrtf(m2 - mu * mu + 1e-5f);
        ck[n * 128 + k] = bb - rstd * mu * rs;
    }
}

// W2 (512x512), W3 (256x256) -> bf16 copies
__global__ __launch_bounds__(256) void k_prepW(const void* __restrict__ W2,
                                               const void* __restrict__ W3,
                                               const float* __restrict__ flag,
                                               unsigned short* __restrict__ W2b,
                                               unsigned short* __restrict__ W3b) {
    const bool f32 = flag[0] > 0.5f;
    const int i = blockIdx.x * 256 + threadIdx.x;
    if (i < 512 * 512) W2b[i] = f32 ? f2b(((const float*)W2)[i]) : ((const unsigned short*)W2)[i];
    if (i < 256 * 256) W3b[i] = f32 ? f2b(((const float*)W3)[i]) : ((const unsigned short*)W3)[i];
}

// ---------------- MFMA staging helpers (reg path, used by fc1/fc2) ----------------
__device__ __forceinline__ void stage8(unsigned short* lds, int r, int c,
                                       const void* gp, long gidx, bool f32) {
    const int dst = r * 64 + ((c ^ (r & 7)) << 3);
    uint4 v;
    if (f32) {
        const float* s = (const float*)gp + gidx;
        float4 a = *(const float4*)s;
        float4 b = *(const float4*)(s + 4);
        v.x = (unsigned int)f2b(a.x) | ((unsigned int)f2b(a.y) << 16);
        v.y = (unsigned int)f2b(a.z) | ((unsigned int)f2b(a.w) << 16);
        v.z = (unsigned int)f2b(b.x) | ((unsigned int)f2b(b.y) << 16);
        v.w = (unsigned int)f2b(b.z) | ((unsigned int)f2b(b.w) << 16);
    } else {
        v = *(const uint4*)((const unsigned short*)gp + gidx);
    }
    *(uint4*)&lds[dst] = v;
}
__device__ __forceinline__ bf16x8 fragLd(const unsigned short* lds, int r, int c) {
    return *(const bf16x8*)&lds[r * 64 + ((c ^ (r & 7)) << 3)];
}
__device__ __forceinline__ void stage8w(unsigned short* lds, int r, int c,
                                        const void* gp, long gidx, bool f32) {
    const int dst = r * 128 + ((c ^ (r & 7)) << 3);
    uint4 v;
    if (f32) {
        const float* s = (const float*)gp + gidx;
        float4 a = *(const float4*)s;
        float4 b = *(const float4*)(s + 4);
        v.x = (unsigned int)f2b(a.x) | ((unsigned int)f2b(a.y) << 16);
        v.y = (unsigned int)f2b(a.z) | ((unsigned int)f2b(a.w) << 16);
        v.z = (unsigned int)f2b(b.x) | ((unsigned int)f2b(b.y) << 16);
        v.w = (unsigned int)f2b(b.z) | ((unsigned int)f2b(b.w) << 16);
    } else {
        v = *(const uint4*)((const unsigned short*)gp + gidx);
    }
    *(uint4*)&lds[dst] = v;
}
__device__ __forceinline__ bf16x8 fragLd128(const unsigned short* lds, int r, int c) {
    return *(const bf16x8*)&lds[r * 128 + ((c ^ (r & 7)) << 3)];
}

// ---------------- fc1 (g-tile): D[p=256][j=128], K=64; LN folded, GELU ----------------
__global__ __launch_bounds__(256) void k_fc1_mfma(const void* __restrict__ xp,
                                                  const float* __restrict__ stats,
                                                  const float* __restrict__ ck,
                                                  const void* __restrict__ W1,
                                                  const float* __restrict__ flag,
                                                  unsigned short* __restrict__ AuBase,
                                                  void* __restrict__ outBase, int nBase) {
    const bool f32 = flag[0] > 0.5f;
    __shared__ __align__(16) unsigned short As[128 * 64];   // W1 [j][c]
    __shared__ __align__(16) unsigned short Bs[256 * 64];   // X^T [p][c]
    const int nwg = gridDim.x;
    const int cpx = nwg >> 3;
    const int work = (blockIdx.x & 7) * cpx + (blockIdx.x >> 3);
    const int nl = work >> 9;
    const int n = nBase + nl;
    const int g = work & 511;
    const int d0 = (g >> 6) * 4, h0 = ((g >> 3) & 7) * 8, w0 = (g & 7) * 8;
    const int t = threadIdx.x;
    const int lane = t & 63, wid = t >> 6;
    const int waveP = wid * 64;
    const int lr = lane & 15, lk = lane >> 4;

    unsigned short* Au = AuBase + (size_t)nl * 8388608;
    unsigned short* Bv = (unsigned short*)((char*)outBase + (size_t)n * 8388608 * (f32 ? 4 : 2));

    {   // stage A: W1 (128 x 64)
        const int rS = t >> 1, c04 = (t & 1) * 4;
        #pragma unroll
        for (int q = 0; q < 4; ++q)
            stage8(As, rS, c04 + q, W1, (long)rS * 64 + (c04 + q) * 8, f32);
    }
    {   // stage B: x g-block -> Bs[p][c], fused fp32->bf16, swizzled u32 writes
        const int c0 = (t & 31) * 2;
        const int rdh = t >> 5;
        const long cbase = ((long)(n * 64 + c0)) << 17;
        const int ch = c0 >> 3, cof = c0 & 7;
        #pragma unroll
        for (int q = 0; q < 4; ++q) {
            const int dh = rdh * 4 + q;
            const int dp = dh >> 3, hp = dh & 7;
            const long sb = (long)(d0 + dp) * 4096 + (h0 + hp) * 64 + w0;
            unsigned short v0[8], v1[8];
            if (f32) {
                const float* r0 = (const float*)xp + cbase + sb;
                const float* r1 = r0 + S_PER_N;
                float4 a0 = *(const float4*)r0, a1 = *(const float4*)(r0 + 4);
                float4 b0 = *(const float4*)r1, b1v = *(const float4*)(r1 + 4);
                v0[0]=f2b(a0.x); v0[1]=f2b(a0.y); v0[2]=f2b(a0.z); v0[3]=f2b(a0.w);
                v0[4]=f2b(a1.x); v0[5]=f2b(a1.y); v0[6]=f2b(a1.z); v0[7]=f2b(a1.w);
                v1[0]=f2b(b0.x); v1[1]=f2b(b0.y); v1[2]=f2b(b0.z); v1[3]=f2b(b0.w);
                v1[4]=f2b(b1v.x); v1[5]=f2b(b1v.y); v1[6]=f2b(b1v.z); v1[7]=f2b(b1v.w);
            } else {
                const unsigned short* r0 = (const unsigned short*)xp + cbase + sb;
                uint4 a = *(const uint4*)r0;
                uint4 b = *(const uint4*)(r0 + S_PER_N);
                const unsigned short* pa = (const unsigned short*)&a;
                const unsigned short* pb = (const unsigned short*)&b;
                #pragma unroll
                for (int j = 0; j < 8; ++j) { v0[j] = pa[j]; v1[j] = pb[j]; }
            }
            const int pbase = dp * 64 + hp * 8;
            #pragma unroll
            for (int j = 0; j < 8; ++j) {
                const int pj = pbase + j;
                unsigned int val = (unsigned int)v0[j] | ((unsigned int)v1[j] << 16);
                *(unsigned int*)&Bs[pj * 64 + ((ch ^ (pj & 7)) << 3) + cof] = val;
            }
        }
    }
    __syncthreads();

    const float mu   = stats[n * 2 + 0] * (1.0f / CNT_PER_N);
    const float m2   = stats[n * 2 + 1] * (1.0f / CNT_PER_N);
    const float rstd = rsqrtf(m2 - mu * mu + 1e-5f);

    #pragma unroll
    for (int half = 0; half < 2; ++half) {
        f32x4 zero = {0.f, 0.f, 0.f, 0.f};
        f32x4 acc[4][4];
        #pragma unroll
        for (int i = 0; i < 4; ++i)
            #pragma unroll
            for (int j = 0; j < 4; ++j) acc[i][j] = zero;

        #pragma unroll
        for (int kk = 0; kk < 2; ++kk) {
            bf16x8 bp[4], aj[4];
            #pragma unroll
            for (int f = 0; f < 4; ++f) {
                bp[f] = fragLd(Bs, waveP + f * 16 + lr, kk * 4 + lk);
                aj[f] = fragLd(As, half * 64 + f * 16 + lr, kk * 4 + lk);
            }
            #pragma unroll
            for (int fp = 0; fp < 4; ++fp)
                #pragma unroll
                for (int fj = 0; fj < 4; ++fj)
                    acc[fp][fj] = __builtin_amdgcn_mfma_f32_16x16x32_bf16(bp[fp], aj[fj], acc[fp][fj], 0, 0, 0);
        }

        #pragma unroll
        for (int fj = 0; fj < 4; ++fj) {
            const int j = half * 64 + fj * 16 + lr;
            const float ckj = ck[n * 128 + j];
            #pragma unroll
            for (int fp = 0; fp < 4; ++fp) {
                const int pb = waveP + fp * 16 + lk * 4;
                unsigned short o[4];
                #pragma unroll
                for (int i = 0; i < 4; ++i) {
                    float v = acc[fp][fj][i] * rstd + ckj;
                    float ge = 0.5f * v * (1.0f + erff(v * 0.70710678118654752440f));
                    o[i] = f2b(ge);
                }
                uint2 pk;
                pk.x = (unsigned int)o[0] | ((unsigned int)o[1] << 16);
                pk.y = (unsigned int)o[2] | ((unsigned int)o[3] << 16);
                if (half == 0) {
                    *(uint2*)&Au[(long)j * S_PER_N + g * 256 + pb] = pk;
                } else {
                    *(uint2*)&Bv[((long)g * 64 + (j - 64)) * 256 + pb] = pk;
                }
            }
        }
    }
}

// ---------------- transA: Au[c][g][p] -> At'[(p*64+c)][g] ----------------
__global__ __launch_bounds__(256) void k_transA(const unsigned short* __restrict__ Abase,
                                                unsigned short* __restrict__ AtBase) {
    __shared__ unsigned short T[64 * 66];
    const int bid = blockIdx.x;
    const int nl = bid >> 11;
    const int inner = bid & 2047;
    const unsigned short* A = Abase + (size_t)nl * 8388608;
    unsigned short* At = AtBase + (size_t)nl * 8388608;
    const int c  = inner >> 5;
    const int gt = (inner >> 2) & 7, pt = inner & 3;
    const int g0 = gt * 64, p0 = pt * 64;
    const int t = threadIdx.x;

    const int gr = t >> 2, pc = (t & 3) * 16;
    const unsigned int* s32 = (const unsigned int*)(A + (long)c * S_PER_N + (long)(g0 + gr) * 256 + p0 + pc);
    unsigned int* d32 = (unsigned int*)&T[gr * 66 + pc];
    #pragma unroll
    for (int i = 0; i < 8; ++i) d32[i] = s32[i];
    __syncthreads();

    const int pr = t >> 2, gc0 = (t & 3) * 16;
    unsigned int ov[8];
    #pragma unroll
    for (int i = 0; i < 8; ++i) {
        unsigned int lo = T[(gc0 + 2 * i) * 66 + pr];
        unsigned int hi = T[(gc0 + 2 * i + 1) * 66 + pr];
        ov[i] = lo | (hi << 16);
    }
    unsigned int* dst = (unsigned int*)(At + ((long)(p0 + pr) * 64 + c) * 512 + g0 + gc0);
    #pragma unroll
    for (int i = 0; i < 8; ++i) dst[i] = ov[i];
}

// ---------------- umix: global_load_lds staged GEMM; D[nlc][g'] swapped ----------------
// grid cnt*512: inner = mTile*128 + nTile. Output T_U[(g'*256+p)*64+c], 128B runs.
__global__ __launch_bounds__(256) void k_umix_mfma(const unsigned short* __restrict__ BtBase,
                                                   const unsigned short* __restrict__ W2b,
                                                   const void* __restrict__ b2,
                                                   const float* __restrict__ flag,
                                                   unsigned short* __restrict__ TUBase) {
    const bool f32 = flag[0] > 0.5f;
    __shared__ __align__(16) unsigned short smem[17408];   // 34816 B
    unsigned short* As = smem;           // [128][64] W2 tile (swizzled)
    unsigned short* Bs = smem + 8192;    // [128][64] token tile (swizzled)
    unsigned short* Ot = smem;           // [128][136] output staging (aliases)
    const int bid = blockIdx.x;
    const int nl = bid >> 9;
    const int inner = bid & 511;
    const unsigned short* Bt = BtBase + (size_t)nl * 8388608;
    unsigned short* TU = TUBase + (size_t)nl * 8388608;
    const int mTile = inner >> 7;
    const int nTile = inner & 127;
    const int m0 = mTile * 128;
    const int t = threadIdx.x;
    const int lane = t & 63, wid = t >> 6;
    const int waveM = (wid >> 1) * 64, waveN = (wid & 1) * 64;
    const int lr = lane & 15, lk = lane >> 4;
    const int rIn8 = lane >> 3;                       // 0..7
    const int swzOff = ((lane & 7) ^ rIn8) << 3;      // pre-swizzled source chunk (shorts)

    f32x4 zero = {0.f, 0.f, 0.f, 0.f};
    f32x4 acc[4][4];
    #pragma unroll
    for (int i = 0; i < 4; ++i)
        #pragma unroll
        for (int j = 0; j < 4; ++j) acc[i][j] = zero;

    for (int kb = 0; kb < 512; kb += 64) {
        #pragma unroll
        for (int call = 0; call < 4; ++call) {
            const int rowBase = call * 32 + wid * 8;
            gld16(W2b + (long)(m0 + rowBase + rIn8) * 512 + kb + swzOff, As + rowBase * 64);
            gld16(Bt + (long)(nTile * 128 + rowBase + rIn8) * 512 + kb + swzOff, Bs + rowBase * 64);
        }
        __syncthreads();
        #pragma unroll
        for (int kk = 0; kk < 2; ++kk) {
            bf16x8 tok[4], wf[4];
            #pragma unroll
            for (int f = 0; f < 4; ++f) {
                tok[f] = fragLd(Bs, waveN + f * 16 + lr, kk * 4 + lk);
                wf[f]  = fragLd(As, waveM + f * 16 + lr, kk * 4 + lk);
            }
            #pragma unroll
            for (int fm = 0; fm < 4; ++fm)
                #pragma unroll
                for (int fn = 0; fn < 4; ++fn)
                    acc[fm][fn] = __builtin_amdgcn_mfma_f32_16x16x32_bf16(tok[fm], wf[fn], acc[fm][fn], 0, 0, 0);
        }
        __syncthreads();
    }

    // acc -> Ot[g'][nlc] (row=g' col index, col=nlc) with bias, uint2 packed
    #pragma unroll
    for (int fn = 0; fn < 4; ++fn) {
        const int gp = waveM + fn * 16 + lr;          // g' within tile
        const float bias = loadIn(b2, m0 + gp, f32);
        #pragma unroll
        for (int fm = 0; fm < 4; ++fm) {
            const int nb = waveN + fm * 16 + lk * 4;  // nlc base
            unsigned short o[4];
            #pragma unroll
            for (int i = 0; i < 4; ++i) o[i] = f2b(acc[fm][fn][i] + bias);
            uint2 pk;
            pk.x = (unsigned int)o[0] | ((unsigned int)o[1] << 16);
            pk.y = (unsigned int)o[2] | ((unsigned int)o[3] << 16);
            *(uint2*)&Ot[gp * 136 + nb] = pk;
        }
    }
    __syncthreads();
    // coalesced write: thread t -> (m = t>>1, half = t&1), 128 B contiguous
    {
        const int m = t >> 1, half = t & 1;
        const unsigned short* src = &Ot[m * 136 + half * 64];
        unsigned short* dst = TU + ((long)(m0 + m) * 256 + nTile * 2 + half) * 64;
        #pragma unroll
        for (int q = 0; q < 8; ++q)
            *(uint4*)(dst + q * 8) = *(const uint4*)(src + q * 8);
    }
}

// ---------------- vmix: global_load_lds staged GEMM; D[nlc][k] swapped ----------------
// grid cnt*512: inner = mTile*256 + nTile. Output T_V[(g*256+k)*64+c], 128B runs.
__global__ __launch_bounds__(256) void k_vmix_mfma(void* __restrict__ outBase,
                                                   const unsigned short* __restrict__ W3b,
                                                   const void* __restrict__ b3,
                                                   const float* __restrict__ flag,
                                                   unsigned short* __restrict__ TVBase,
                                                   int nBase) {
    const bool f32 = flag[0] > 0.5f;
    __shared__ __align__(16) unsigned short smem[17408];
    unsigned short* As = smem;           // [128][64] W3 tile
    unsigned short* Bs = smem + 8192;    // [128][64] Bv token tile
    unsigned short* Ot = smem;           // [128][136]
    const int bid = blockIdx.x;
    const int nl = bid >> 9;
    const int n = nBase + nl;
    const int inner = bid & 511;
    const unsigned short* Bv = (const unsigned short*)((char*)outBase + (size_t)n * 8388608 * (f32 ? 4 : 2));
    unsigned short* TV = TVBase + (size_t)nl * 8388608;
    const int mTile = inner >> 8;       // 0..1
    const int nTile = inner & 255;      // 0..255
    const int m0 = mTile * 128;
    const int t = threadIdx.x;
    const int lane = t & 63, wid = t >> 6;
    const int waveM = (wid >> 1) * 64, waveN = (wid & 1) * 64;
    const int lr = lane & 15, lk = lane >> 4;
    const int rIn8 = lane >> 3;
    const int swzOff = ((lane & 7) ^ rIn8) << 3;

    f32x4 zero = {0.f, 0.f, 0.f, 0.f};
    f32x4 acc[4][4];
    #pragma unroll
    for (int i = 0; i < 4; ++i)
        #pragma unroll
        for (int j = 0; j < 4; ++j) acc[i][j] = zero;

    for (int kb = 0; kb < 256; kb += 64) {
        #pragma unroll
        for (int call = 0; call < 4; ++call) {
            const int rowBase = call * 32 + wid * 8;
            gld16(W3b + (long)(m0 + rowBase + rIn8) * 256 + kb + swzOff, As + rowBase * 64);
            gld16(Bv + (long)(nTile * 128 + rowBase + rIn8) * 256 + kb + swzOff, Bs + rowBase * 64);
        }
        __syncthreads();
        #pragma unroll
        for (int kk = 0; kk < 2; ++kk) {
            bf16x8 tok[4], wf[4];
            #pragma unroll
            for (int f = 0; f < 4; ++f) {
                tok[f] = fragLd(Bs, waveN + f * 16 + lr, kk * 4 + lk);
                wf[f]  = fragLd(As, waveM + f * 16 + lr, kk * 4 + lk);
            }
            #pragma unroll
            for (int fm = 0; fm < 4; ++fm)
                #pragma unroll
                for (int fn = 0; fn < 4; ++fn)
                    acc[fm][fn] = __builtin_amdgcn_mfma_f32_16x16x32_bf16(tok[fm], wf[fn], acc[fm][fn], 0, 0, 0);
        }
        __syncthreads();
    }

    #pragma unroll
    for (int fn = 0; fn < 4; ++fn) {
        const int kp = waveM + fn * 16 + lr;          // output-p (k) within tile
        const float bias = loadIn(b3, m0 + kp, f32);
        #pragma unroll
        for (int fm = 0; fm < 4; ++fm) {
            const int nb = waveN + fm * 16 + lk * 4;  // nlc base (g,c)
            unsigned short o[4];
            #pragma unroll
            for (int i = 0; i < 4; ++i) o[i] = f2b(acc[fm][fn][i] + bias);
            uint2 pk;
            pk.x = (unsigned int)o[0] | ((unsigned int)o[1] << 16);
            pk.y = (unsigned int)o[2] | ((unsigned int)o[3] << 16);
            *(uint2*)&Ot[kp * 136 + nb] = pk;
        }
    }
    __syncthreads();
    {
        const int m = t >> 1, half = t & 1;
        const unsigned short* src = &Ot[m * 136 + half * 64];
        unsigned short* dst = TV + ((long)(nTile * 2 + half) * 256 + m0 + m) * 64;
        #pragma unroll
        for (int q = 0; q < 8; ++q)
            *(uint4*)(dst + q * 8) = *(const uint4*)(src + q * 8);
    }
}

// ---------------- fc2: D[k=64][s-tile=128], K=128 from T_U/T_V ----------------
__global__ __launch_bounds__(256) void k_fc2_mfma(const unsigned short* __restrict__ TUBase,
                                                  const unsigned short* __restrict__ TVBase,
                                                  const void* __restrict__ W4,
                                                  const void* __restrict__ b4,
                                                  const float* __restrict__ flag,
                                                  void* __restrict__ out, int nBase) {
    const bool f32 = flag[0] > 0.5f;
    __shared__ __align__(16) unsigned short As[64 * 128];
    __shared__ __align__(16) unsigned short Bs[128 * 128];
    const int bid = blockIdx.x;
    const int nl = bid >> 10;
    const int n = nBase + nl;
    const unsigned short* TU = TUBase + (size_t)nl * 8388608;
    const unsigned short* TV = TVBase + (size_t)nl * 8388608;
    const int s0 = (bid & 1023) * 128;
    const int t = threadIdx.x;
    const int lane = t & 63, wid = t >> 6;
    const int waveN = wid * 32;
    const int lr = lane & 15, lk = lane >> 4;

    {
        const int rA = t >> 2, q0 = (t & 3) * 4;
        #pragma unroll
        for (int q = 0; q < 4; ++q)
            stage8w(As, rA, q0 + q, W4, (long)rA * 128 + (q0 + q) * 8, f32);
    }
    {
        const int rB = t & 127, h8 = (t >> 7) * 8;
        const int s = s0 + rB;
        const int d = s >> 12, h = (s >> 6) & 63, w = s & 63;
        const int g = ((d >> 2) << 6) | ((h >> 3) << 3) | (w >> 3);
        const int p = ((d & 3) << 6) | ((h & 7) << 3) | (w & 7);
        const long gp = (long)g * 256 + p;
        const unsigned short* src = (h8 == 0) ? (TU + gp * 64) : (TV + gp * 64);
        #pragma unroll
        for (int q = 0; q < 8; ++q) {
            const int ch = h8 + q;
            uint4 v = *(const uint4*)(src + q * 8);
            *(uint4*)&Bs[rB * 128 + ((ch ^ (rB & 7)) << 3)] = v;
        }
    }
    __syncthreads();

    f32x4 zero = {0.f, 0.f, 0.f, 0.f};
    f32x4 acc[4][2];
    #pragma unroll
    for (int i = 0; i < 4; ++i) { acc[i][0] = zero; acc[i][1] = zero; }

    #pragma unroll
    for (int kk = 0; kk < 4; ++kk) {
        bf16x8 af[4], bfr[2];
        #pragma unroll
        for (int fm = 0; fm < 4; ++fm) af[fm] = fragLd128(As, fm * 16 + lr, kk * 4 + lk);
        #pragma unroll
        for (int fn = 0; fn < 2; ++fn) bfr[fn] = fragLd128(Bs, waveN + fn * 16 + lr, kk * 4 + lk);
        #pragma unroll
        for (int fm = 0; fm < 4; ++fm)
            #pragma unroll
            for (int fn = 0; fn < 2; ++fn)
                acc[fm][fn] = __builtin_amdgcn_mfma_f32_16x16x32_bf16(af[fm], bfr[fn], acc[fm][fn], 0, 0, 0);
    }

    #pragma unroll
    for (int fm = 0; fm < 4; ++fm) {
        #pragma unroll
        for (int fn = 0; fn < 2; ++fn) {
            const int scol = s0 + waveN + fn * 16 + lr;
            #pragma unroll
            for (int i = 0; i < 4; ++i) {
                const int k = fm * 16 + lk * 4 + i;
                const float v = acc[fm][fn][i] + loadIn(b4, k, f32);
                storeOut(out, ((long)(n * 64 + k) << 17) + scol, v, f32);
            }
        }
    }
}

extern "C" void kernel_launch(void* const* d_in, const int* in_sizes, int n_in,
                              void* d_out, int out_size, void* d_ws, size_t ws_size,
                              hipStream_t stream) {
    const void* x  = d_in[0];
    const void* W1 = d_in[1];
    const void* b1 = d_in[2];
    const void* W2 = d_in[3];
    const void* b2 = d_in[4];
    const void* W3 = d_in[5];
    const void* b3 = d_in[6];
    const void* W4 = d_in[7];
    const void* b4 = d_in[8];

    float* wsf      = (float*)d_ws;
    float* stats    = wsf;            // 8 floats
    float* flag     = wsf + 8;        // 1 float
    float* partials = wsf + 16;       // 1024 floats
    float* ck       = wsf + 1040;     // 512 floats (ends < 8192 B)

    unsigned short* W2bf = (unsigned short*)((char*)d_ws + 8192);   // 512 KB
    unsigned short* W3bf = W2bf + 512 * 512;                        // 128 KB (ends < 1 MiB)

    const size_t perBuf = (size_t)8388608;                          // shorts per sample buffer
    const size_t need4  = (1u << 20) + 4ull * 2ull * perBuf * 2ull; // 1 MiB + 128 MiB
    const int cnt = (ws_size >= need4) ? 4 : 1;

    unsigned short* buf1 = (unsigned short*)((char*)d_ws + (1u << 20));
    unsigned short* buf2 = buf1 + (size_t)cnt * perBuf;

    hipLaunchKernelGGL(k_detect,   dim3(1),    dim3(256), 0, stream,
                       (const unsigned short*)x, flag);
    hipLaunchKernelGGL(k_lnstats,  dim3(512),  dim3(256), 0, stream, x, flag, partials);
    hipLaunchKernelGGL(k_lnreduce, dim3(1),    dim3(64),  0, stream, partials, stats);
    hipLaunchKernelGGL(k_prep,     dim3(1),    dim3(128), 0, stream, W1, b1, stats, flag, ck);
    hipLaunchKernelGGL(k_prepW,    dim3(1024), dim3(256), 0, stream, W2, W3, flag, W2bf, W3bf);

    for (int nBase = 0; nBase < 4; nBase += cnt) {
        hipLaunchKernelGGL(k_fc1_mfma,  dim3(cnt * 512),  dim3(256), 0, stream,
                           x, stats, ck, W1, flag, buf2, d_out, nBase);
        hipLaunchKernelGGL(k_transA,    dim3(cnt * 2048), dim3(256), 0, stream, buf2, buf1);
        hipLaunchKernelGGL(k_umix_mfma, dim3(cnt * 512),  dim3(256), 0, stream,
                           buf1, W2bf, b2, flag, buf2);
        hipLaunchKernelGGL(k_vmix_mfma, dim3(cnt * 512),  dim3(256), 0, stream,
                           d_out, W3bf, b3, flag, buf1, nBase);
        hipLaunchKernelGGL(k_fc2_mfma,  dim3(cnt * 1024), dim3(256), 0, stream,
                           buf2, buf1, W4, b4, flag, d_out, nBase);
    }
}

// Round 10
// 338.419 us; speedup vs baseline: 4.6870x; 1.0693x over previous
//
#include <hip/hip_runtime.h>
#include <hip/hip_bf16.h>
#include <math.h>

// Geometry (fixed):
//   x: (N=4, C=64, D=32, H=64, W=64); S = 131072 = G*P, G=512, P=256
//   W1 (128,64) b1(128) | W2 (512,512) b2(512) | W3 (256,256) b3(256) | W4 (64,128) b4(64)
// Blocked index: g=(d>>2)*64+(h>>3)*8+(w>>3); p=(d&3)*64+(h&7)*8+(w&7)
//
// Pipeline (batched over samples; cnt=4 if ws fits):
//   prepW:  W2,W3 -> bf16 copies in ws (once)
//   fc1:    per-g GEMM, LN folded, fast-erf GELU -> Au[c][g][p] (buf2), Bv[g][c][p] (d_out n)
//   transA: Au -> At'[(p*64+c)][g]    (buf1)
//   umix:   GEMM (global_load_lds staged) -> T_U[(g'*256+p)*64+c] (buf2)
//   vmix:   GEMM (global_load_lds staged) -> T_V[(g*256+k)*64+c]  (buf1)
//   fc2:    GEMM W4 x cat(T_U,T_V)^T + b4 -> out n

#define S_PER_N 131072
#define CNT_PER_N 8388608.0f

typedef __attribute__((ext_vector_type(8))) short bf16x8;
typedef __attribute__((ext_vector_type(4))) float f32x4;

__device__ __forceinline__ float b2f(unsigned short u) {
    return __uint_as_float(((unsigned int)u) << 16);
}
__device__ __forceinline__ unsigned short f2b(float f) {
    unsigned int i = __float_as_uint(f);
    unsigned int r = i + 0x7FFFu + ((i >> 16) & 1u);
    return (unsigned short)(r >> 16);
}
__device__ __forceinline__ float loadIn(const void* p, long i, bool f32) {
    return f32 ? ((const float*)p)[i] : b2f(((const unsigned short*)p)[i]);
}
__device__ __forceinline__ void storeOut(void* p, long i, float v, bool f32) {
    if (f32) ((float*)p)[i] = v;
    else ((unsigned short*)p)[i] = f2b(v);
}
// async global->LDS, 16B per lane; LDS dest = uniform base + lane*16
__device__ __forceinline__ void gld16(const unsigned short* g, unsigned short* l) {
    __builtin_amdgcn_global_load_lds(
        (const __attribute__((address_space(1))) void*)g,
        (__attribute__((address_space(3))) void*)l,
        16, 0, 0);
}
// GELU with A&S 7.1.26 erf (max abs err 1.5e-7, branch-free):
// erf(x) = sign(x) * (1 - poly(t)*exp(-x^2)), t = 1/(1+0.3275911|x|)
__device__ __forceinline__ float fast_gelu(float x) {
    const float ax = fabsf(x);
    const float xs = x * 0.70710678118654752440f;        // x/sqrt(2)
    const float axs = ax * 0.70710678118654752440f;
    const float t = __builtin_amdgcn_rcpf(1.0f + 0.3275911f * axs);
    float poly = 1.061405429f;
    poly = poly * t - 1.453152027f;
    poly = poly * t + 1.421413741f;
    poly = poly * t - 0.284496736f;
    poly = poly * t + 0.254829592f;
    const float e = __expf(-xs * xs);
    float erf_a = 1.0f - poly * t * e;
    erf_a = (x < 0.0f) ? -erf_a : erf_a;
    return 0.5f * x * (1.0f + erf_a);
}

// ---------------- dtype detect + LN stats (proven) ----------------

__global__ void k_detect(const unsigned short* __restrict__ xw, float* __restrict__ flag) {
    __shared__ int sh[256];
    int tid = threadIdx.x;
    int sane = 0;
    for (int i = tid; i < 4096; i += 256) {
        int e = (xw[i] >> 7) & 0xFF;
        sane += (e >= 110 && e <= 130) ? 1 : 0;
    }
    sh[tid] = sane; __syncthreads();
    for (int off = 128; off; off >>= 1) {
        if (tid < off) sh[tid] += sh[tid + off];
        __syncthreads();
    }
    if (tid == 0) flag[0] = (sh[0] >= 3300) ? 0.0f : 1.0f;
}

__global__ __launch_bounds__(256) void k_lnstats(const void* __restrict__ xp,
                                                 const float* __restrict__ flag,
                                                 float* __restrict__ partials) {
    const bool f32 = flag[0] > 0.5f;
    const int bid = blockIdx.x;
    const long base = (long)bid * 65536;
    float s = 0.0f, sq = 0.0f;
    if (f32) {
        const float4* xv = (const float4*)((const float*)xp + base);
        for (int it = 0; it < 64; ++it) {
            float4 v = xv[it * 256 + threadIdx.x];
            s  += v.x + v.y + v.z + v.w;
            sq += v.x*v.x + v.y*v.y + v.z*v.z + v.w*v.w;
        }
    } else {
        const uint4* xv = (const uint4*)((const unsigned short*)xp + base);
        for (int it = 0; it < 32; ++it) {
            uint4 v = xv[it * 256 + threadIdx.x];
            unsigned int ws4[4] = {v.x, v.y, v.z, v.w};
            #pragma unroll
            for (int q = 0; q < 4; ++q) {
                float f0 = b2f((unsigned short)(ws4[q] & 0xFFFFu));
                float f1 = b2f((unsigned short)(ws4[q] >> 16));
                s += f0 + f1;
                sq += f0 * f0 + f1 * f1;
            }
        }
    }
    __shared__ float ls[256], lq[256];
    ls[threadIdx.x] = s; lq[threadIdx.x] = sq;
    __syncthreads();
    for (int off = 128; off > 0; off >>= 1) {
        if (threadIdx.x < off) {
            ls[threadIdx.x] += ls[threadIdx.x + off];
            lq[threadIdx.x] += lq[threadIdx.x + off];
        }
        __syncthreads();
    }
    if (threadIdx.x == 0) {
        partials[bid * 2 + 0] = ls[0];
        partials[bid * 2 + 1] = lq[0];
    }
}

__global__ void k_lnreduce(const float* __restrict__ partials, float* __restrict__ stats) {
    const int t = threadIdx.x;
    if (t < 4) {
        float s = 0.0f, sq = 0.0f;
        for (int i = 0; i < 128; ++i) {
            s  += partials[(t * 128 + i) * 2 + 0];
            sq += partials[(t * 128 + i) * 2 + 1];
        }
        stats[t * 2 + 0] = s;
        stats[t * 2 + 1] = sq;
    }
}

// ck[n][k] = b1[k] - rstd_n * mu_n * rowsum(W1[k])
__global__ void k_prep(const void* __restrict__ W1, const void* __restrict__ b1,
                       const float* __restrict__ stats, const float* __restrict__ flag,
                       float* __restrict__ ck) {
    const bool f32 = flag[0] > 0.5f;
    const int k = threadIdx.x;     // 128
    float rs = 0.0f;
    for (int c = 0; c < 64; ++c) rs += loadIn(W1, (long)k * 64 + c, f32);
    const float bb = loadIn(b1, k, f32);
    for (int n = 0; n < 4; ++n) {
        const float mu   = stats[n * 2 + 0] * (1.0f / CNT_PER_N);
        const float m2   = stats[n * 2 + 1] * (1.0f / CNT_PER_N);
        const float rstd = rsqrtf(m2 - mu * mu + 1e-5f);
        ck[n * 128 + k] = bb - rstd * mu * rs;
    }
}

// W2 (512x512), W3 (256x256) -> bf16 copies
__global__ __launch_bounds__(256) void k_prepW(const void* __restrict__ W2,
                                               const void* __restrict__ W3,
                                               const float* __restrict__ flag,
                                               unsigned short* __restrict__ W2b,
                                               unsigned short* __restrict__ W3b) {
    const bool f32 = flag[0] > 0.5f;
    const int i = blockIdx.x * 256 + threadIdx.x;
    if (i < 512 * 512) W2b[i] = f32 ? f2b(((const float*)W2)[i]) : ((const unsigned short*)W2)[i];
    if (i < 256 * 256) W3b[i] = f32 ? f2b(((const float*)W3)[i]) : ((const unsigned short*)W3)[i];
}

// ---------------- MFMA staging helpers (reg path, used by fc1/fc2) ----------------
__device__ __forceinline__ void stage8(unsigned short* lds, int r, int c,
                                       const void* gp, long gidx, bool f32) {
    const int dst = r * 64 + ((c ^ (r & 7)) << 3);
    uint4 v;
    if (f32) {
        const float* s = (const float*)gp + gidx;
        float4 a = *(const float4*)s;
        float4 b = *(const float4*)(s + 4);
        v.x = (unsigned int)f2b(a.x) | ((unsigned int)f2b(a.y) << 16);
        v.y = (unsigned int)f2b(a.z) | ((unsigned int)f2b(a.w) << 16);
        v.z = (unsigned int)f2b(b.x) | ((unsigned int)f2b(b.y) << 16);
        v.w = (unsigned int)f2b(b.z) | ((unsigned int)f2b(b.w) << 16);
    } else {
        v = *(const uint4*)((const unsigned short*)gp + gidx);
    }
    *(uint4*)&lds[dst] = v;
}
__device__ __forceinline__ bf16x8 fragLd(const unsigned short* lds, int r, int c) {
    return *(const bf16x8*)&lds[r * 64 + ((c ^ (r & 7)) << 3)];
}
__device__ __forceinline__ void stage8w(unsigned short* lds, int r, int c,
                                        const void* gp, long gidx, bool f32) {
    const int dst = r * 128 + ((c ^ (r & 7)) << 3);
    uint4 v;
    if (f32) {
        const float* s = (const float*)gp + gidx;
        float4 a = *(const float4*)s;
        float4 b = *(const float4*)(s + 4);
        v.x = (unsigned int)f2b(a.x) | ((unsigned int)f2b(a.y) << 16);
        v.y = (unsigned int)f2b(a.z) | ((unsigned int)f2b(a.w) << 16);
        v.z = (unsigned int)f2b(b.x) | ((unsigned int)f2b(b.y) << 16);
        v.w = (unsigned int)f2b(b.z) | ((unsigned int)f2b(b.w) << 16);
    } else {
        v = *(const uint4*)((const unsigned short*)gp + gidx);
    }
    *(uint4*)&lds[dst] = v;
}
__device__ __forceinline__ bf16x8 fragLd128(const unsigned short* lds, int r, int c) {
    return *(const bf16x8*)&lds[r * 128 + ((c ^ (r & 7)) << 3)];
}

// ---------------- fc1 (g-tile): D[p=256][j=128], K=64; LN folded, fast GELU ----------------
__global__ __launch_bounds__(256) void k_fc1_mfma(const void* __restrict__ xp,
                                                  const float* __restrict__ stats,
                                                  const float* __restrict__ ck,
                                                  const void* __restrict__ W1,
                                                  const float* __restrict__ flag,
                                                  unsigned short* __restrict__ AuBase,
                                                  void* __restrict__ outBase, int nBase) {
    const bool f32 = flag[0] > 0.5f;
    __shared__ __align__(16) unsigned short As[128 * 64];   // W1 [j][c]
    __shared__ __align__(16) unsigned short Bs[256 * 64];   // X^T [p][c]
    const int nwg = gridDim.x;
    const int cpx = nwg >> 3;
    const int work = (blockIdx.x & 7) * cpx + (blockIdx.x >> 3);
    const int nl = work >> 9;
    const int n = nBase + nl;
    const int g = work & 511;
    const int d0 = (g >> 6) * 4, h0 = ((g >> 3) & 7) * 8, w0 = (g & 7) * 8;
    const int t = threadIdx.x;
    const int lane = t & 63, wid = t >> 6;
    const int waveP = wid * 64;
    const int lr = lane & 15, lk = lane >> 4;

    unsigned short* Au = AuBase + (size_t)nl * 8388608;
    unsigned short* Bv = (unsigned short*)((char*)outBase + (size_t)n * 8388608 * (f32 ? 4 : 2));

    {   // stage A: W1 (128 x 64)
        const int rS = t >> 1, c04 = (t & 1) * 4;
        #pragma unroll
        for (int q = 0; q < 4; ++q)
            stage8(As, rS, c04 + q, W1, (long)rS * 64 + (c04 + q) * 8, f32);
    }
    {   // stage B: x g-block -> Bs[p][c], fused fp32->bf16, swizzled u32 writes
        const int c0 = (t & 31) * 2;
        const int rdh = t >> 5;
        const long cbase = ((long)(n * 64 + c0)) << 17;
        const int ch = c0 >> 3, cof = c0 & 7;
        #pragma unroll
        for (int q = 0; q < 4; ++q) {
            const int dh = rdh * 4 + q;
            const int dp = dh >> 3, hp = dh & 7;
            const long sb = (long)(d0 + dp) * 4096 + (h0 + hp) * 64 + w0;
            unsigned short v0[8], v1[8];
            if (f32) {
                const float* r0 = (const float*)xp + cbase + sb;
                const float* r1 = r0 + S_PER_N;
                float4 a0 = *(const float4*)r0, a1 = *(const float4*)(r0 + 4);
                float4 b0 = *(const float4*)r1, b1v = *(const float4*)(r1 + 4);
                v0[0]=f2b(a0.x); v0[1]=f2b(a0.y); v0[2]=f2b(a0.z); v0[3]=f2b(a0.w);
                v0[4]=f2b(a1.x); v0[5]=f2b(a1.y); v0[6]=f2b(a1.z); v0[7]=f2b(a1.w);
                v1[0]=f2b(b0.x); v1[1]=f2b(b0.y); v1[2]=f2b(b0.z); v1[3]=f2b(b0.w);
                v1[4]=f2b(b1v.x); v1[5]=f2b(b1v.y); v1[6]=f2b(b1v.z); v1[7]=f2b(b1v.w);
            } else {
                const unsigned short* r0 = (const unsigned short*)xp + cbase + sb;
                uint4 a = *(const uint4*)r0;
                uint4 b = *(const uint4*)(r0 + S_PER_N);
                const unsigned short* pa = (const unsigned short*)&a;
                const unsigned short* pb = (const unsigned short*)&b;
                #pragma unroll
                for (int j = 0; j < 8; ++j) { v0[j] = pa[j]; v1[j] = pb[j]; }
            }
            const int pbase = dp * 64 + hp * 8;
            #pragma unroll
            for (int j = 0; j < 8; ++j) {
                const int pj = pbase + j;
                unsigned int val = (unsigned int)v0[j] | ((unsigned int)v1[j] << 16);
                *(unsigned int*)&Bs[pj * 64 + ((ch ^ (pj & 7)) << 3) + cof] = val;
            }
        }
    }
    __syncthreads();

    const float mu   = stats[n * 2 + 0] * (1.0f / CNT_PER_N);
    const float m2   = stats[n * 2 + 1] * (1.0f / CNT_PER_N);
    const float rstd = rsqrtf(m2 - mu * mu + 1e-5f);

    #pragma unroll
    for (int half = 0; half < 2; ++half) {
        f32x4 zero = {0.f, 0.f, 0.f, 0.f};
        f32x4 acc[4][4];
        #pragma unroll
        for (int i = 0; i < 4; ++i)
            #pragma unroll
            for (int j = 0; j < 4; ++j) acc[i][j] = zero;

        #pragma unroll
        for (int kk = 0; kk < 2; ++kk) {
            bf16x8 bp[4], aj[4];
            #pragma unroll
            for (int f = 0; f < 4; ++f) {
                bp[f] = fragLd(Bs, waveP + f * 16 + lr, kk * 4 + lk);
                aj[f] = fragLd(As, half * 64 + f * 16 + lr, kk * 4 + lk);
            }
            #pragma unroll
            for (int fp = 0; fp < 4; ++fp)
                #pragma unroll
                for (int fj = 0; fj < 4; ++fj)
                    acc[fp][fj] = __builtin_amdgcn_mfma_f32_16x16x32_bf16(bp[fp], aj[fj], acc[fp][fj], 0, 0, 0);
        }

        #pragma unroll
        for (int fj = 0; fj < 4; ++fj) {
            const int j = half * 64 + fj * 16 + lr;
            const float ckj = ck[n * 128 + j];
            #pragma unroll
            for (int fp = 0; fp < 4; ++fp) {
                const int pb = waveP + fp * 16 + lk * 4;
                unsigned short o[4];
                #pragma unroll
                for (int i = 0; i < 4; ++i) {
                    float v = acc[fp][fj][i] * rstd + ckj;
                    o[i] = f2b(fast_gelu(v));
                }
                uint2 pk;
                pk.x = (unsigned int)o[0] | ((unsigned int)o[1] << 16);
                pk.y = (unsigned int)o[2] | ((unsigned int)o[3] << 16);
                if (half == 0) {
                    *(uint2*)&Au[(long)j * S_PER_N + g * 256 + pb] = pk;
                } else {
                    *(uint2*)&Bv[((long)g * 64 + (j - 64)) * 256 + pb] = pk;
                }
            }
        }
    }
}

// ---------------- transA: Au[c][g][p] -> At'[(p*64+c)][g] ----------------
__global__ __launch_bounds__(256) void k_transA(const unsigned short* __restrict__ Abase,
                                                unsigned short* __restrict__ AtBase) {
    __shared__ unsigned short T[64 * 66];
    const int bid = blockIdx.x;
    const int nl = bid >> 11;
    const int inner = bid & 2047;
    const unsigned short* A = Abase + (size_t)nl * 8388608;
    unsigned short* At = AtBase + (size_t)nl * 8388608;
    const int c  = inner >> 5;
    const int gt = (inner >> 2) & 7, pt = inner & 3;
    const int g0 = gt * 64, p0 = pt * 64;
    const int t = threadIdx.x;

    const int gr = t >> 2, pc = (t & 3) * 16;
    const unsigned int* s32 = (const unsigned int*)(A + (long)c * S_PER_N + (long)(g0 + gr) * 256 + p0 + pc);
    unsigned int* d32 = (unsigned int*)&T[gr * 66 + pc];
    #pragma unroll
    for (int i = 0; i < 8; ++i) d32[i] = s32[i];
    __syncthreads();

    const int pr = t >> 2, gc0 = (t & 3) * 16;
    unsigned int ov[8];
    #pragma unroll
    for (int i = 0; i < 8; ++i) {
        unsigned int lo = T[(gc0 + 2 * i) * 66 + pr];
        unsigned int hi = T[(gc0 + 2 * i + 1) * 66 + pr];
        ov[i] = lo | (hi << 16);
    }
    unsigned int* dst = (unsigned int*)(At + ((long)(p0 + pr) * 64 + c) * 512 + g0 + gc0);
    #pragma unroll
    for (int i = 0; i < 8; ++i) dst[i] = ov[i];
}

// ---------------- umix: global_load_lds staged GEMM; D[nlc][g'] swapped ----------------
__global__ __launch_bounds__(256) void k_umix_mfma(const unsigned short* __restrict__ BtBase,
                                                   const unsigned short* __restrict__ W2b,
                                                   const void* __restrict__ b2,
                                                   const float* __restrict__ flag,
                                                   unsigned short* __restrict__ TUBase) {
    const bool f32 = flag[0] > 0.5f;
    __shared__ __align__(16) unsigned short smem[17408];
    unsigned short* As = smem;
    unsigned short* Bs = smem + 8192;
    unsigned short* Ot = smem;
    const int bid = blockIdx.x;
    const int nl = bid >> 9;
    const int inner = bid & 511;
    const unsigned short* Bt = BtBase + (size_t)nl * 8388608;
    unsigned short* TU = TUBase + (size_t)nl * 8388608;
    const int mTile = inner >> 7;
    const int nTile = inner & 127;
    const int m0 = mTile * 128;
    const int t = threadIdx.x;
    const int lane = t & 63, wid = t >> 6;
    const int waveM = (wid >> 1) * 64, waveN = (wid & 1) * 64;
    const int lr = lane & 15, lk = lane >> 4;
    const int rIn8 = lane >> 3;
    const int swzOff = ((lane & 7) ^ rIn8) << 3;

    f32x4 zero = {0.f, 0.f, 0.f, 0.f};
    f32x4 acc[4][4];
    #pragma unroll
    for (int i = 0; i < 4; ++i)
        #pragma unroll
        for (int j = 0; j < 4; ++j) acc[i][j] = zero;

    for (int kb = 0; kb < 512; kb += 64) {
        #pragma unroll
        for (int call = 0; call < 4; ++call) {
            const int rowBase = call * 32 + wid * 8;
            gld16(W2b + (long)(m0 + rowBase + rIn8) * 512 + kb + swzOff, As + rowBase * 64);
            gld16(Bt + (long)(nTile * 128 + rowBase + rIn8) * 512 + kb + swzOff, Bs + rowBase * 64);
        }
        __syncthreads();
        #pragma unroll
        for (int kk = 0; kk < 2; ++kk) {
            bf16x8 tok[4], wf[4];
            #pragma unroll
            for (int f = 0; f < 4; ++f) {
                tok[f] = fragLd(Bs, waveN + f * 16 + lr, kk * 4 + lk);
                wf[f]  = fragLd(As, waveM + f * 16 + lr, kk * 4 + lk);
            }
            #pragma unroll
            for (int fm = 0; fm < 4; ++fm)
                #pragma unroll
                for (int fn = 0; fn < 4; ++fn)
                    acc[fm][fn] = __builtin_amdgcn_mfma_f32_16x16x32_bf16(tok[fm], wf[fn], acc[fm][fn], 0, 0, 0);
        }
        __syncthreads();
    }

    #pragma unroll
    for (int fn = 0; fn < 4; ++fn) {
        const int gp = waveM + fn * 16 + lr;
        const float bias = loadIn(b2, m0 + gp, f32);
        #pragma unroll
        for (int fm = 0; fm < 4; ++fm) {
            const int nb = waveN + fm * 16 + lk * 4;
            unsigned short o[4];
            #pragma unroll
            for (int i = 0; i < 4; ++i) o[i] = f2b(acc[fm][fn][i] + bias);
            uint2 pk;
            pk.x = (unsigned int)o[0] | ((unsigned int)o[1] << 16);
            pk.y = (unsigned int)o[2] | ((unsigned int)o[3] << 16);
            *(uint2*)&Ot[gp * 136 + nb] = pk;
        }
    }
    __syncthreads();
    {
        const int m = t >> 1, half = t & 1;
        const unsigned short* src = &Ot[m * 136 + half * 64];
        unsigned short* dst = TU + ((long)(m0 + m) * 256 + nTile * 2 + half) * 64;
        #pragma unroll
        for (int q = 0; q < 8; ++q)
            *(uint4*)(dst + q * 8) = *(const uint4*)(src + q * 8);
    }
}

// ---------------- vmix: global_load_lds staged GEMM; D[nlc][k] swapped ----------------
__global__ __launch_bounds__(256) void k_vmix_mfma(void* __restrict__ outBase,
                                                   const unsigned short* __restrict__ W3b,
                                                   const void* __restrict__ b3,
                                                   const float* __restrict__ flag,
                                                   unsigned short* __restrict__ TVBase,
                                                   int nBase) {
    const bool f32 = flag[0] > 0.5f;
    __shared__ __align__(16) unsigned short smem[17408];
    unsigned short* As = smem;
    unsigned short* Bs = smem + 8192;
    unsigned short* Ot = smem;
    const int bid = blockIdx.x;
    const int nl = bid >> 9;
    const int n = nBase + nl;
    const int inner = bid & 511;
    const unsigned short* Bv = (const unsigned short*)((char*)outBase + (size_t)n * 8388608 * (f32 ? 4 : 2));
    unsigned short* TV = TVBase + (size_t)nl * 8388608;
    const int mTile = inner >> 8;
    const int nTile = inner & 255;
    const int m0 = mTile * 128;
    const int t = threadIdx.x;
    const int lane = t & 63, wid = t >> 6;
    const int waveM = (wid >> 1) * 64, waveN = (wid & 1) * 64;
    const int lr = lane & 15, lk = lane >> 4;
    const int rIn8 = lane >> 3;
    const int swzOff = ((lane & 7) ^ rIn8) << 3;

    f32x4 zero = {0.f, 0.f, 0.f, 0.f};
    f32x4 acc[4][4];
    #pragma unroll
    for (int i = 0; i < 4; ++i)
        #pragma unroll
        for (int j = 0; j < 4; ++j) acc[i][j] = zero;

    for (int kb = 0; kb < 256; kb += 64) {
        #pragma unroll
        for (int call = 0; call < 4; ++call) {
            const int rowBase = call * 32 + wid * 8;
            gld16(W3b + (long)(m0 + rowBase + rIn8) * 256 + kb + swzOff, As + rowBase * 64);
            gld16(Bv + (long)(nTile * 128 + rowBase + rIn8) * 256 + kb + swzOff, Bs + rowBase * 64);
        }
        __syncthreads();
        #pragma unroll
        for (int kk = 0; kk < 2; ++kk) {
            bf16x8 tok[4], wf[4];
            #pragma unroll
            for (int f = 0; f < 4; ++f) {
                tok[f] = fragLd(Bs, waveN + f * 16 + lr, kk * 4 + lk);
                wf[f]  = fragLd(As, waveM + f * 16 + lr, kk * 4 + lk);
            }
            #pragma unroll
            for (int fm = 0; fm < 4; ++fm)
                #pragma unroll
                for (int fn = 0; fn < 4; ++fn)
                    acc[fm][fn] = __builtin_amdgcn_mfma_f32_16x16x32_bf16(tok[fm], wf[fn], acc[fm][fn], 0, 0, 0);
        }
        __syncthreads();
    }

    #pragma unroll
    for (int fn = 0; fn < 4; ++fn) {
        const int kp = waveM + fn * 16 + lr;
        const float bias = loadIn(b3, m0 + kp, f32);
        #pragma unroll
        for (int fm = 0; fm < 4; ++fm) {
            const int nb = waveN + fm * 16 + lk * 4;
            unsigned short o[4];
            #pragma unroll
            for (int i = 0; i < 4; ++i) o[i] = f2b(acc[fm][fn][i] + bias);
            uint2 pk;
            pk.x = (unsigned int)o[0] | ((unsigned int)o[1] << 16);
            pk.y = (unsigned int)o[2] | ((unsigned int)o[3] << 16);
            *(uint2*)&Ot[kp * 136 + nb] = pk;
        }
    }
    __syncthreads();
    {
        const int m = t >> 1, half = t & 1;
        const unsigned short* src = &Ot[m * 136 + half * 64];
        unsigned short* dst = TV + ((long)(nTile * 2 + half) * 256 + m0 + m) * 64;
        #pragma unroll
        for (int q = 0; q < 8; ++q)
            *(uint4*)(dst + q * 8) = *(const uint4*)(src + q * 8);
    }
}

// ---------------- fc2: D[k=64][s-tile=128], K=128 from T_U/T_V ----------------
__global__ __launch_bounds__(256) void k_fc2_mfma(const unsigned short* __restrict__ TUBase,
                                                  const unsigned short* __restrict__ TVBase,
                                                  const void* __restrict__ W4,
                                                  const void* __restrict__ b4,
                                                  const float* __restrict__ flag,
                                                  void* __restrict__ out, int nBase) {
    const bool f32 = flag[0] > 0.5f;
    __shared__ __align__(16) unsigned short As[64 * 128];
    __shared__ __align__(16) unsigned short Bs[128 * 128];
    const int bid = blockIdx.x;
    const int nl = bid >> 10;
    const int n = nBase + nl;
    const unsigned short* TU = TUBase + (size_t)nl * 8388608;
    const unsigned short* TV = TVBase + (size_t)nl * 8388608;
    const int s0 = (bid & 1023) * 128;
    const int t = threadIdx.x;
    const int lane = t & 63, wid = t >> 6;
    const int waveN = wid * 32;
    const int lr = lane & 15, lk = lane >> 4;

    {
        const int rA = t >> 2, q0 = (t & 3) * 4;
        #pragma unroll
        for (int q = 0; q < 4; ++q)
            stage8w(As, rA, q0 + q, W4, (long)rA * 128 + (q0 + q) * 8, f32);
    }
    {
        const int rB = t & 127, h8 = (t >> 7) * 8;
        const int s = s0 + rB;
        const int d = s >> 12, h = (s >> 6) & 63, w = s & 63;
        const int g = ((d >> 2) << 6) | ((h >> 3) << 3) | (w >> 3);
        const int p = ((d & 3) << 6) | ((h & 7) << 3) | (w & 7);
        const long gp = (long)g * 256 + p;
        const unsigned short* src = (h8 == 0) ? (TU + gp * 64) : (TV + gp * 64);
        #pragma unroll
        for (int q = 0; q < 8; ++q) {
            const int ch = h8 + q;
            uint4 v = *(const uint4*)(src + q * 8);
            *(uint4*)&Bs[rB * 128 + ((ch ^ (rB & 7)) << 3)] = v;
        }
    }
    __syncthreads();

    f32x4 zero = {0.f, 0.f, 0.f, 0.f};
    f32x4 acc[4][2];
    #pragma unroll
    for (int i = 0; i < 4; ++i) { acc[i][0] = zero; acc[i][1] = zero; }

    #pragma unroll
    for (int kk = 0; kk < 4; ++kk) {
        bf16x8 af[4], bfr[2];
        #pragma unroll
        for (int fm = 0; fm < 4; ++fm) af[fm] = fragLd128(As, fm * 16 + lr, kk * 4 + lk);
        #pragma unroll
        for (int fn = 0; fn < 2; ++fn) bfr[fn] = fragLd128(Bs, waveN + fn * 16 + lr, kk * 4 + lk);
        #pragma unroll
        for (int fm = 0; fm < 4; ++fm)
            #pragma unroll
            for (int fn = 0; fn < 2; ++fn)
                acc[fm][fn] = __builtin_amdgcn_mfma_f32_16x16x32_bf16(af[fm], bfr[fn], acc[fm][fn], 0, 0, 0);
    }

    #pragma unroll
    for (int fm = 0; fm < 4; ++fm) {
        #pragma unroll
        for (int fn = 0; fn < 2; ++fn) {
            const int scol = s0 + waveN + fn * 16 + lr;
            #pragma unroll
            for (int i = 0; i < 4; ++i) {
                const int k = fm * 16 + lk * 4 + i;
                const float v = acc[fm][fn][i] + loadIn(b4, k, f32);
                storeOut(out, ((long)(n * 64 + k) << 17) + scol, v, f32);
            }
        }
    }
}

extern "C" void kernel_launch(void* const* d_in, const int* in_sizes, int n_in,
                              void* d_out, int out_size, void* d_ws, size_t ws_size,
                              hipStream_t stream) {
    const void* x  = d_in[0];
    const void* W1 = d_in[1];
    const void* b1 = d_in[2];
    const void* W2 = d_in[3];
    const void* b2 = d_in[4];
    const void* W3 = d_in[5];
    const void* b3 = d_in[6];
    const void* W4 = d_in[7];
    const void* b4 = d_in[8];

    float* wsf      = (float*)d_ws;
    float* stats    = wsf;            // 8 floats
    float* flag     = wsf + 8;        // 1 float
    float* partials = wsf + 16;       // 1024 floats
    float* ck       = wsf + 1040;     // 512 floats (ends < 8192 B)

    unsigned short* W2bf = (unsigned short*)((char*)d_ws + 8192);   // 512 KB
    unsigned short* W3bf = W2bf + 512 * 512;                        // 128 KB (ends < 1 MiB)

    const size_t perBuf = (size_t)8388608;                          // shorts per sample buffer
    const size_t need4  = (1u << 20) + 4ull * 2ull * perBuf * 2ull; // 1 MiB + 128 MiB
    const int cnt = (ws_size >= need4) ? 4 : 1;

    unsigned short* buf1 = (unsigned short*)((char*)d_ws + (1u << 20));
    unsigned short* buf2 = buf1 + (size_t)cnt * perBuf;

    hipLaunchKernelGGL(k_detect,   dim3(1),    dim3(256), 0, stream,
                       (const unsigned short*)x, flag);
    hipLaunchKernelGGL(k_lnstats,  dim3(512),  dim3(256), 0, stream, x, flag, partials);
    hipLaunchKernelGGL(k_lnreduce, dim3(1),    dim3(64),  0, stream, partials, stats);
    hipLaunchKernelGGL(k_prep,     dim3(1),    dim3(128), 0, stream, W1, b1, stats, flag, ck);
    hipLaunchKernelGGL(k_prepW,    dim3(1024), dim3(256), 0, stream, W2, W3, flag, W2bf, W3bf);

    for (int nBase = 0; nBase < 4; nBase += cnt) {
        hipLaunchKernelGGL(k_fc1_mfma,  dim3(cnt * 512),  dim3(256), 0, stream,
                           x, stats, ck, W1, flag, buf2, d_out, nBase);
        hipLaunchKernelGGL(k_transA,    dim3(cnt * 2048), dim3(256), 0, stream, buf2, buf1);
        hipLaunchKernelGGL(k_umix_mfma, dim3(cnt * 512),  dim3(256), 0, stream,
                           buf1, W2bf, b2, flag, buf2);
        hipLaunchKernelGGL(k_vmix_mfma, dim3(cnt * 512),  dim3(256), 0, stream,
                           d_out, W3bf, b3, flag, buf1, nBase);
        hipLaunchKernelGGL(k_fc2_mfma,  dim3(cnt * 1024), dim3(256), 0, stream,
                           buf2, buf1, W4, b4, flag, d_out, nBase);
    }
}

// Round 11
// 336.605 us; speedup vs baseline: 4.7122x; 1.0054x over previous
//
#include <hip/hip_runtime.h>
#include <hip/hip_bf16.h>
#include <math.h>

// Geometry (fixed):
//   x: (N=4, C=64, D=32, H=64, W=64); S = 131072 = G*P, G=512, P=256
//   W1 (128,64) b1(128) | W2 (512,512) b2(512) | W3 (256,256) b3(256) | W4 (64,128) b4(64)
// Blocked index: g=(d>>2)*64+(h>>3)*8+(w>>3); p=(d&3)*64+(h&7)*8+(w&7)
//
// Pipeline (batched over samples; cnt=4 if ws fits):
//   prepW:  W1,W2,W3,W4 -> bf16 copies in ws (once)
//   fc1:    per-g GEMM (W1 frags direct from global bf16), LN folded, fast GELU
//           -> Au[c][g][p] (buf2), Bv[g][c][p] (d_out n)
//   transA: Au -> At'[(p*64+c)][g]    (buf1)
//   umix:   GEMM (global_load_lds staged) -> T_U[(g'*256+p)*64+c] (buf2)
//   vmix:   GEMM (global_load_lds staged) -> T_V[(g*256+k)*64+c]  (buf1)
//   fc2:    LDS-free GEMM: W4/TU/TV fragments direct from global -> out n

#define S_PER_N 131072
#define CNT_PER_N 8388608.0f

typedef __attribute__((ext_vector_type(8))) short bf16x8;
typedef __attribute__((ext_vector_type(4))) float f32x4;

__device__ __forceinline__ float b2f(unsigned short u) {
    return __uint_as_float(((unsigned int)u) << 16);
}
__device__ __forceinline__ unsigned short f2b(float f) {
    unsigned int i = __float_as_uint(f);
    unsigned int r = i + 0x7FFFu + ((i >> 16) & 1u);
    return (unsigned short)(r >> 16);
}
__device__ __forceinline__ float loadIn(const void* p, long i, bool f32) {
    return f32 ? ((const float*)p)[i] : b2f(((const unsigned short*)p)[i]);
}
__device__ __forceinline__ void storeOut(void* p, long i, float v, bool f32) {
    if (f32) ((float*)p)[i] = v;
    else ((unsigned short*)p)[i] = f2b(v);
}
// async global->LDS, 16B per lane; LDS dest = uniform base + lane*16
__device__ __forceinline__ void gld16(const unsigned short* g, unsigned short* l) {
    __builtin_amdgcn_global_load_lds(
        (const __attribute__((address_space(1))) void*)g,
        (__attribute__((address_space(3))) void*)l,
        16, 0, 0);
}
// GELU with A&S 7.1.26 erf (max abs err 1.5e-7, branch-free)
__device__ __forceinline__ float fast_gelu(float x) {
    const float ax = fabsf(x);
    const float xs = x * 0.70710678118654752440f;
    const float axs = ax * 0.70710678118654752440f;
    const float t = __builtin_amdgcn_rcpf(1.0f + 0.3275911f * axs);
    float poly = 1.061405429f;
    poly = poly * t - 1.453152027f;
    poly = poly * t + 1.421413741f;
    poly = poly * t - 0.284496736f;
    poly = poly * t + 0.254829592f;
    const float e = __expf(-xs * xs);
    float erf_a = 1.0f - poly * t * e;
    erf_a = (x < 0.0f) ? -erf_a : erf_a;
    return 0.5f * x * (1.0f + erf_a);
}

// ---------------- dtype detect + LN stats (proven) ----------------

__global__ void k_detect(const unsigned short* __restrict__ xw, float* __restrict__ flag) {
    __shared__ int sh[256];
    int tid = threadIdx.x;
    int sane = 0;
    for (int i = tid; i < 4096; i += 256) {
        int e = (xw[i] >> 7) & 0xFF;
        sane += (e >= 110 && e <= 130) ? 1 : 0;
    }
    sh[tid] = sane; __syncthreads();
    for (int off = 128; off; off >>= 1) {
        if (tid < off) sh[tid] += sh[tid + off];
        __syncthreads();
    }
    if (tid == 0) flag[0] = (sh[0] >= 3300) ? 0.0f : 1.0f;
}

__global__ __launch_bounds__(256) void k_lnstats(const void* __restrict__ xp,
                                                 const float* __restrict__ flag,
                                                 float* __restrict__ partials) {
    const bool f32 = flag[0] > 0.5f;
    const int bid = blockIdx.x;
    const long base = (long)bid * 65536;
    float s = 0.0f, sq = 0.0f;
    if (f32) {
        const float4* xv = (const float4*)((const float*)xp + base);
        for (int it = 0; it < 64; ++it) {
            float4 v = xv[it * 256 + threadIdx.x];
            s  += v.x + v.y + v.z + v.w;
            sq += v.x*v.x + v.y*v.y + v.z*v.z + v.w*v.w;
        }
    } else {
        const uint4* xv = (const uint4*)((const unsigned short*)xp + base);
        for (int it = 0; it < 32; ++it) {
            uint4 v = xv[it * 256 + threadIdx.x];
            unsigned int ws4[4] = {v.x, v.y, v.z, v.w};
            #pragma unroll
            for (int q = 0; q < 4; ++q) {
                float f0 = b2f((unsigned short)(ws4[q] & 0xFFFFu));
                float f1 = b2f((unsigned short)(ws4[q] >> 16));
                s += f0 + f1;
                sq += f0 * f0 + f1 * f1;
            }
        }
    }
    __shared__ float ls[256], lq[256];
    ls[threadIdx.x] = s; lq[threadIdx.x] = sq;
    __syncthreads();
    for (int off = 128; off > 0; off >>= 1) {
        if (threadIdx.x < off) {
            ls[threadIdx.x] += ls[threadIdx.x + off];
            lq[threadIdx.x] += lq[threadIdx.x + off];
        }
        __syncthreads();
    }
    if (threadIdx.x == 0) {
        partials[bid * 2 + 0] = ls[0];
        partials[bid * 2 + 1] = lq[0];
    }
}

__global__ void k_lnreduce(const float* __restrict__ partials, float* __restrict__ stats) {
    const int t = threadIdx.x;
    if (t < 4) {
        float s = 0.0f, sq = 0.0f;
        for (int i = 0; i < 128; ++i) {
            s  += partials[(t * 128 + i) * 2 + 0];
            sq += partials[(t * 128 + i) * 2 + 1];
        }
        stats[t * 2 + 0] = s;
        stats[t * 2 + 1] = sq;
    }
}

// ck[n][k] = b1[k] - rstd_n * mu_n * rowsum(W1[k])
__global__ void k_prep(const void* __restrict__ W1, const void* __restrict__ b1,
                       const float* __restrict__ stats, const float* __restrict__ flag,
                       float* __restrict__ ck) {
    const bool f32 = flag[0] > 0.5f;
    const int k = threadIdx.x;     // 128
    float rs = 0.0f;
    for (int c = 0; c < 64; ++c) rs += loadIn(W1, (long)k * 64 + c, f32);
    const float bb = loadIn(b1, k, f32);
    for (int n = 0; n < 4; ++n) {
        const float mu   = stats[n * 2 + 0] * (1.0f / CNT_PER_N);
        const float m2   = stats[n * 2 + 1] * (1.0f / CNT_PER_N);
        const float rstd = rsqrtf(m2 - mu * mu + 1e-5f);
        ck[n * 128 + k] = bb - rstd * mu * rs;
    }
}

// W1 (128x64), W2 (512x512), W3 (256x256), W4 (64x128) -> bf16 copies
__global__ __launch_bounds__(256) void k_prepW(const void* __restrict__ W1,
                                               const void* __restrict__ W2,
                                               const void* __restrict__ W3,
                                               const void* __restrict__ W4,
                                               const float* __restrict__ flag,
                                               unsigned short* __restrict__ W1b,
                                               unsigned short* __restrict__ W2b,
                                               unsigned short* __restrict__ W3b,
                                               unsigned short* __restrict__ W4b) {
    const bool f32 = flag[0] > 0.5f;
    const int i = blockIdx.x * 256 + threadIdx.x;
    if (i < 512 * 512) W2b[i] = f32 ? f2b(((const float*)W2)[i]) : ((const unsigned short*)W2)[i];
    if (i < 256 * 256) W3b[i] = f32 ? f2b(((const float*)W3)[i]) : ((const unsigned short*)W3)[i];
    if (i < 128 * 64)  W1b[i] = f32 ? f2b(((const float*)W1)[i]) : ((const unsigned short*)W1)[i];
    if (i < 64 * 128)  W4b[i] = f32 ? f2b(((const float*)W4)[i]) : ((const unsigned short*)W4)[i];
}

// ---------------- LDS swizzle helpers ----------------
__device__ __forceinline__ bf16x8 fragLd(const unsigned short* lds, int r, int c) {
    return *(const bf16x8*)&lds[r * 64 + ((c ^ (r & 7)) << 3)];
}

// ---------------- fc1 (g-tile): D[p=256][j=128], K=64; LN folded, fast GELU ----------------
// W1 A-fragments loaded direct from bf16 global (L2-hot); only X staged in LDS (32KB).
__global__ __launch_bounds__(256) void k_fc1_mfma(const void* __restrict__ xp,
                                                  const float* __restrict__ stats,
                                                  const float* __restrict__ ck,
                                                  const unsigned short* __restrict__ W1b,
                                                  const float* __restrict__ flag,
                                                  unsigned short* __restrict__ AuBase,
                                                  void* __restrict__ outBase, int nBase) {
    const bool f32 = flag[0] > 0.5f;
    __shared__ __align__(16) unsigned short Bs[256 * 64];   // X^T [p][c]
    const int nwg = gridDim.x;
    const int cpx = nwg >> 3;
    const int work = (blockIdx.x & 7) * cpx + (blockIdx.x >> 3);
    const int nl = work >> 9;
    const int n = nBase + nl;
    const int g = work & 511;
    const int d0 = (g >> 6) * 4, h0 = ((g >> 3) & 7) * 8, w0 = (g & 7) * 8;
    const int t = threadIdx.x;
    const int lane = t & 63, wid = t >> 6;
    const int waveP = wid * 64;
    const int lr = lane & 15, lk = lane >> 4;

    unsigned short* Au = AuBase + (size_t)nl * 8388608;
    unsigned short* Bv = (unsigned short*)((char*)outBase + (size_t)n * 8388608 * (f32 ? 4 : 2));

    {   // stage B: x g-block -> Bs[p][c], fused fp32->bf16, swizzled u32 writes
        const int c0 = (t & 31) * 2;
        const int rdh = t >> 5;
        const long cbase = ((long)(n * 64 + c0)) << 17;
        const int ch = c0 >> 3, cof = c0 & 7;
        #pragma unroll
        for (int q = 0; q < 4; ++q) {
            const int dh = rdh * 4 + q;
            const int dp = dh >> 3, hp = dh & 7;
            const long sb = (long)(d0 + dp) * 4096 + (h0 + hp) * 64 + w0;
            unsigned short v0[8], v1[8];
            if (f32) {
                const float* r0 = (const float*)xp + cbase + sb;
                const float* r1 = r0 + S_PER_N;
                float4 a0 = *(const float4*)r0, a1 = *(const float4*)(r0 + 4);
                float4 b0 = *(const float4*)r1, b1v = *(const float4*)(r1 + 4);
                v0[0]=f2b(a0.x); v0[1]=f2b(a0.y); v0[2]=f2b(a0.z); v0[3]=f2b(a0.w);
                v0[4]=f2b(a1.x); v0[5]=f2b(a1.y); v0[6]=f2b(a1.z); v0[7]=f2b(a1.w);
                v1[0]=f2b(b0.x); v1[1]=f2b(b0.y); v1[2]=f2b(b0.z); v1[3]=f2b(b0.w);
                v1[4]=f2b(b1v.x); v1[5]=f2b(b1v.y); v1[6]=f2b(b1v.z); v1[7]=f2b(b1v.w);
            } else {
                const unsigned short* r0 = (const unsigned short*)xp + cbase + sb;
                uint4 a = *(const uint4*)r0;
                uint4 b = *(const uint4*)(r0 + S_PER_N);
                const unsigned short* pa = (const unsigned short*)&a;
                const unsigned short* pb = (const unsigned short*)&b;
                #pragma unroll
                for (int j = 0; j < 8; ++j) { v0[j] = pa[j]; v1[j] = pb[j]; }
            }
            const int pbase = dp * 64 + hp * 8;
            #pragma unroll
            for (int j = 0; j < 8; ++j) {
                const int pj = pbase + j;
                unsigned int val = (unsigned int)v0[j] | ((unsigned int)v1[j] << 16);
                *(unsigned int*)&Bs[pj * 64 + ((ch ^ (pj & 7)) << 3) + cof] = val;
            }
        }
    }
    __syncthreads();

    const float mu   = stats[n * 2 + 0] * (1.0f / CNT_PER_N);
    const float m2   = stats[n * 2 + 1] * (1.0f / CNT_PER_N);
    const float rstd = rsqrtf(m2 - mu * mu + 1e-5f);

    #pragma unroll
    for (int half = 0; half < 2; ++half) {
        f32x4 zero = {0.f, 0.f, 0.f, 0.f};
        f32x4 acc[4][4];
        #pragma unroll
        for (int i = 0; i < 4; ++i)
            #pragma unroll
            for (int j = 0; j < 4; ++j) acc[i][j] = zero;

        #pragma unroll
        for (int kk = 0; kk < 2; ++kk) {
            bf16x8 bp[4], aj[4];
            #pragma unroll
            for (int f = 0; f < 4; ++f) {
                bp[f] = fragLd(Bs, waveP + f * 16 + lr, kk * 4 + lk);
                aj[f] = *(const bf16x8*)(W1b + (long)(half * 64 + f * 16 + lr) * 64 + (kk * 4 + lk) * 8);
            }
            #pragma unroll
            for (int fp = 0; fp < 4; ++fp)
                #pragma unroll
                for (int fj = 0; fj < 4; ++fj)
                    acc[fp][fj] = __builtin_amdgcn_mfma_f32_16x16x32_bf16(bp[fp], aj[fj], acc[fp][fj], 0, 0, 0);
        }

        #pragma unroll
        for (int fj = 0; fj < 4; ++fj) {
            const int j = half * 64 + fj * 16 + lr;
            const float ckj = ck[n * 128 + j];
            #pragma unroll
            for (int fp = 0; fp < 4; ++fp) {
                const int pb = waveP + fp * 16 + lk * 4;
                unsigned short o[4];
                #pragma unroll
                for (int i = 0; i < 4; ++i) {
                    float v = acc[fp][fj][i] * rstd + ckj;
                    o[i] = f2b(fast_gelu(v));
                }
                uint2 pk;
                pk.x = (unsigned int)o[0] | ((unsigned int)o[1] << 16);
                pk.y = (unsigned int)o[2] | ((unsigned int)o[3] << 16);
                if (half == 0) {
                    *(uint2*)&Au[(long)j * S_PER_N + g * 256 + pb] = pk;
                } else {
                    *(uint2*)&Bv[((long)g * 64 + (j - 64)) * 256 + pb] = pk;
                }
            }
        }
    }
}

// ---------------- transA: Au[c][g][p] -> At'[(p*64+c)][g] ----------------
__global__ __launch_bounds__(256) void k_transA(const unsigned short* __restrict__ Abase,
                                                unsigned short* __restrict__ AtBase) {
    __shared__ unsigned short T[64 * 66];
    const int bid = blockIdx.x;
    const int nl = bid >> 11;
    const int inner = bid & 2047;
    const unsigned short* A = Abase + (size_t)nl * 8388608;
    unsigned short* At = AtBase + (size_t)nl * 8388608;
    const int c  = inner >> 5;
    const int gt = (inner >> 2) & 7, pt = inner & 3;
    const int g0 = gt * 64, p0 = pt * 64;
    const int t = threadIdx.x;

    const int gr = t >> 2, pc = (t & 3) * 16;
    const unsigned int* s32 = (const unsigned int*)(A + (long)c * S_PER_N + (long)(g0 + gr) * 256 + p0 + pc);
    unsigned int* d32 = (unsigned int*)&T[gr * 66 + pc];
    #pragma unroll
    for (int i = 0; i < 8; ++i) d32[i] = s32[i];
    __syncthreads();

    const int pr = t >> 2, gc0 = (t & 3) * 16;
    unsigned int ov[8];
    #pragma unroll
    for (int i = 0; i < 8; ++i) {
        unsigned int lo = T[(gc0 + 2 * i) * 66 + pr];
        unsigned int hi = T[(gc0 + 2 * i + 1) * 66 + pr];
        ov[i] = lo | (hi << 16);
    }
    unsigned int* dst = (unsigned int*)(At + ((long)(p0 + pr) * 64 + c) * 512 + g0 + gc0);
    #pragma unroll
    for (int i = 0; i < 8; ++i) dst[i] = ov[i];
}

// ---------------- umix: global_load_lds staged GEMM; D[nlc][g'] swapped ----------------
__global__ __launch_bounds__(256) void k_umix_mfma(const unsigned short* __restrict__ BtBase,
                                                   const unsigned short* __restrict__ W2b,
                                                   const void* __restrict__ b2,
                                                   const float* __restrict__ flag,
                                                   unsigned short* __restrict__ TUBase) {
    const bool f32 = flag[0] > 0.5f;
    __shared__ __align__(16) unsigned short smem[17408];
    unsigned short* As = smem;
    unsigned short* Bs = smem + 8192;
    unsigned short* Ot = smem;
    const int bid = blockIdx.x;
    const int nl = bid >> 9;
    const int inner = bid & 511;
    const unsigned short* Bt = BtBase + (size_t)nl * 8388608;
    unsigned short* TU = TUBase + (size_t)nl * 8388608;
    const int mTile = inner >> 7;
    const int nTile = inner & 127;
    const int m0 = mTile * 128;
    const int t = threadIdx.x;
    const int lane = t & 63, wid = t >> 6;
    const int waveM = (wid >> 1) * 64, waveN = (wid & 1) * 64;
    const int lr = lane & 15, lk = lane >> 4;
    const int rIn8 = lane >> 3;
    const int swzOff = ((lane & 7) ^ rIn8) << 3;

    f32x4 zero = {0.f, 0.f, 0.f, 0.f};
    f32x4 acc[4][4];
    #pragma unroll
    for (int i = 0; i < 4; ++i)
        #pragma unroll
        for (int j = 0; j < 4; ++j) acc[i][j] = zero;

    for (int kb = 0; kb < 512; kb += 64) {
        #pragma unroll
        for (int call = 0; call < 4; ++call) {
            const int rowBase = call * 32 + wid * 8;
            gld16(W2b + (long)(m0 + rowBase + rIn8) * 512 + kb + swzOff, As + rowBase * 64);
            gld16(Bt + (long)(nTile * 128 + rowBase + rIn8) * 512 + kb + swzOff, Bs + rowBase * 64);
        }
        __syncthreads();
        #pragma unroll
        for (int kk = 0; kk < 2; ++kk) {
            bf16x8 tok[4], wf[4];
            #pragma unroll
            for (int f = 0; f < 4; ++f) {
                tok[f] = fragLd(Bs, waveN + f * 16 + lr, kk * 4 + lk);
                wf[f]  = fragLd(As, waveM + f * 16 + lr, kk * 4 + lk);
            }
            #pragma unroll
            for (int fm = 0; fm < 4; ++fm)
                #pragma unroll
                for (int fn = 0; fn < 4; ++fn)
                    acc[fm][fn] = __builtin_amdgcn_mfma_f32_16x16x32_bf16(tok[fm], wf[fn], acc[fm][fn], 0, 0, 0);
        }
        __syncthreads();
    }

    #pragma unroll
    for (int fn = 0; fn < 4; ++fn) {
        const int gp = waveM + fn * 16 + lr;
        const float bias = loadIn(b2, m0 + gp, f32);
        #pragma unroll
        for (int fm = 0; fm < 4; ++fm) {
            const int nb = waveN + fm * 16 + lk * 4;
            unsigned short o[4];
            #pragma unroll
            for (int i = 0; i < 4; ++i) o[i] = f2b(acc[fm][fn][i] + bias);
            uint2 pk;
            pk.x = (unsigned int)o[0] | ((unsigned int)o[1] << 16);
            pk.y = (unsigned int)o[2] | ((unsigned int)o[3] << 16);
            *(uint2*)&Ot[gp * 136 + nb] = pk;
        }
    }
    __syncthreads();
    {
        const int m = t >> 1, half = t & 1;
        const unsigned short* src = &Ot[m * 136 + half * 64];
        unsigned short* dst = TU + ((long)(m0 + m) * 256 + nTile * 2 + half) * 64;
        #pragma unroll
        for (int q = 0; q < 8; ++q)
            *(uint4*)(dst + q * 8) = *(const uint4*)(src + q * 8);
    }
}

// ---------------- vmix: global_load_lds staged GEMM; D[nlc][k] swapped ----------------
__global__ __launch_bounds__(256) void k_vmix_mfma(void* __restrict__ outBase,
                                                   const unsigned short* __restrict__ W3b,
                                                   const void* __restrict__ b3,
                                                   const float* __restrict__ flag,
                                                   unsigned short* __restrict__ TVBase,
                                                   int nBase) {
    const bool f32 = flag[0] > 0.5f;
    __shared__ __align__(16) unsigned short smem[17408];
    unsigned short* As = smem;
    unsigned short* Bs = smem + 8192;
    unsigned short* Ot = smem;
    const int bid = blockIdx.x;
    const int nl = bid >> 9;
    const int n = nBase + nl;
    const int inner = bid & 511;
    const unsigned short* Bv = (const unsigned short*)((char*)outBase + (size_t)n * 8388608 * (f32 ? 4 : 2));
    unsigned short* TV = TVBase + (size_t)nl * 8388608;
    const int mTile = inner >> 8;
    const int nTile = inner & 255;
    const int m0 = mTile * 128;
    const int t = threadIdx.x;
    const int lane = t & 63, wid = t >> 6;
    const int waveM = (wid >> 1) * 64, waveN = (wid & 1) * 64;
    const int lr = lane & 15, lk = lane >> 4;
    const int rIn8 = lane >> 3;
    const int swzOff = ((lane & 7) ^ rIn8) << 3;

    f32x4 zero = {0.f, 0.f, 0.f, 0.f};
    f32x4 acc[4][4];
    #pragma unroll
    for (int i = 0; i < 4; ++i)
        #pragma unroll
        for (int j = 0; j < 4; ++j) acc[i][j] = zero;

    for (int kb = 0; kb < 256; kb += 64) {
        #pragma unroll
        for (int call = 0; call < 4; ++call) {
            const int rowBase = call * 32 + wid * 8;
            gld16(W3b + (long)(m0 + rowBase + rIn8) * 256 + kb + swzOff, As + rowBase * 64);
            gld16(Bv + (long)(nTile * 128 + rowBase + rIn8) * 256 + kb + swzOff, Bs + rowBase * 64);
        }
        __syncthreads();
        #pragma unroll
        for (int kk = 0; kk < 2; ++kk) {
            bf16x8 tok[4], wf[4];
            #pragma unroll
            for (int f = 0; f < 4; ++f) {
                tok[f] = fragLd(Bs, waveN + f * 16 + lr, kk * 4 + lk);
                wf[f]  = fragLd(As, waveM + f * 16 + lr, kk * 4 + lk);
            }
            #pragma unroll
            for (int fm = 0; fm < 4; ++fm)
                #pragma unroll
                for (int fn = 0; fn < 4; ++fn)
                    acc[fm][fn] = __builtin_amdgcn_mfma_f32_16x16x32_bf16(tok[fm], wf[fn], acc[fm][fn], 0, 0, 0);
        }
        __syncthreads();
    }

    #pragma unroll
    for (int fn = 0; fn < 4; ++fn) {
        const int kp = waveM + fn * 16 + lr;
        const float bias = loadIn(b3, m0 + kp, f32);
        #pragma unroll
        for (int fm = 0; fm < 4; ++fm) {
            const int nb = waveN + fm * 16 + lk * 4;
            unsigned short o[4];
            #pragma unroll
            for (int i = 0; i < 4; ++i) o[i] = f2b(acc[fm][fn][i] + bias);
            uint2 pk;
            pk.x = (unsigned int)o[0] | ((unsigned int)o[1] << 16);
            pk.y = (unsigned int)o[2] | ((unsigned int)o[3] << 16);
            *(uint2*)&Ot[kp * 136 + nb] = pk;
        }
    }
    __syncthreads();
    {
        const int m = t >> 1, half = t & 1;
        const unsigned short* src = &Ot[m * 136 + half * 64];
        unsigned short* dst = TV + ((long)(nTile * 2 + half) * 256 + m0 + m) * 64;
        #pragma unroll
        for (int q = 0; q < 8; ++q)
            *(uint4*)(dst + q * 8) = *(const uint4*)(src + q * 8);
    }
}

// ---------------- fc2: LDS-free. D[k=64][s-tile=128], K=128; all fragments direct ----------------
__global__ __launch_bounds__(256) void k_fc2_mfma(const unsigned short* __restrict__ TUBase,
                                                  const unsigned short* __restrict__ TVBase,
                                                  const unsigned short* __restrict__ W4b,
                                                  const void* __restrict__ b4,
                                                  const float* __restrict__ flag,
                                                  void* __restrict__ out, int nBase) {
    const bool f32 = flag[0] > 0.5f;
    const int bid = blockIdx.x;
    const int nl = bid >> 10;
    const int n = nBase + nl;
    const unsigned short* TU = TUBase + (size_t)nl * 8388608;
    const unsigned short* TV = TVBase + (size_t)nl * 8388608;
    const int s0 = (bid & 1023) * 128;
    const int t = threadIdx.x;
    const int lane = t & 63, wid = t >> 6;
    const int waveN = wid * 32;
    const int lr = lane & 15, lk = lane >> 4;

    // per-fn token index and its blocked (g,p) offset
    long gpv[2];
    #pragma unroll
    for (int fn = 0; fn < 2; ++fn) {
        const int s = s0 + waveN + fn * 16 + lr;
        const int d = s >> 12, h = (s >> 6) & 63, w = s & 63;
        const int g = ((d >> 2) << 6) | ((h >> 3) << 3) | (w >> 3);
        const int p = ((d & 3) << 6) | ((h & 7) << 3) | (w & 7);
        gpv[fn] = (long)g * 256 + p;
    }

    f32x4 zero = {0.f, 0.f, 0.f, 0.f};
    f32x4 acc[4][2];
    #pragma unroll
    for (int i = 0; i < 4; ++i) { acc[i][0] = zero; acc[i][1] = zero; }

    #pragma unroll
    for (int kk = 0; kk < 4; ++kk) {
        const unsigned short* base = (kk < 2) ? TU : TV;
        const int choff = ((kk & 1) * 4 + lk) * 8;          // chunk within the 64-ch half
        bf16x8 af[4], bfr[2];
        #pragma unroll
        for (int fm = 0; fm < 4; ++fm)
            af[fm] = *(const bf16x8*)(W4b + (long)(fm * 16 + lr) * 128 + (kk * 4 + lk) * 8);
        #pragma unroll
        for (int fn = 0; fn < 2; ++fn)
            bfr[fn] = *(const bf16x8*)(base + gpv[fn] * 64 + choff);
        #pragma unroll
        for (int fm = 0; fm < 4; ++fm)
            #pragma unroll
            for (int fn = 0; fn < 2; ++fn)
                acc[fm][fn] = __builtin_amdgcn_mfma_f32_16x16x32_bf16(af[fm], bfr[fn], acc[fm][fn], 0, 0, 0);
    }

    #pragma unroll
    for (int fm = 0; fm < 4; ++fm) {
        #pragma unroll
        for (int fn = 0; fn < 2; ++fn) {
            const int scol = s0 + waveN + fn * 16 + lr;
            #pragma unroll
            for (int i = 0; i < 4; ++i) {
                const int k = fm * 16 + lk * 4 + i;
                const float v = acc[fm][fn][i] + loadIn(b4, k, f32);
                storeOut(out, ((long)(n * 64 + k) << 17) + scol, v, f32);
            }
        }
    }
}

extern "C" void kernel_launch(void* const* d_in, const int* in_sizes, int n_in,
                              void* d_out, int out_size, void* d_ws, size_t ws_size,
                              hipStream_t stream) {
    const void* x  = d_in[0];
    const void* W1 = d_in[1];
    const void* b1 = d_in[2];
    const void* W2 = d_in[3];
    const void* b2 = d_in[4];
    const void* W3 = d_in[5];
    const void* b3 = d_in[6];
    const void* W4 = d_in[7];
    const void* b4 = d_in[8];

    float* wsf      = (float*)d_ws;
    float* stats    = wsf;            // 8 floats
    float* flag     = wsf + 8;        // 1 float
    float* partials = wsf + 16;       // 1024 floats
    float* ck       = wsf + 1040;     // 512 floats (ends < 8192 B)

    unsigned short* W2bf = (unsigned short*)((char*)d_ws + 8192);   // 512 KB
    unsigned short* W3bf = W2bf + 512 * 512;                        // 128 KB
    unsigned short* W1bf = W3bf + 256 * 256;                        // 16 KB
    unsigned short* W4bf = W1bf + 128 * 64;                         // 16 KB (ends < 1 MiB)

    const size_t perBuf = (size_t)8388608;                          // shorts per sample buffer
    const size_t need4  = (1u << 20) + 4ull * 2ull * perBuf * 2ull; // 1 MiB + 128 MiB
    const int cnt = (ws_size >= need4) ? 4 : 1;

    unsigned short* buf1 = (unsigned short*)((char*)d_ws + (1u << 20));
    unsigned short* buf2 = buf1 + (size_t)cnt * perBuf;

    hipLaunchKernelGGL(k_detect,   dim3(1),    dim3(256), 0, stream,
                       (const unsigned short*)x, flag);
    hipLaunchKernelGGL(k_lnstats,  dim3(512),  dim3(256), 0, stream, x, flag, partials);
    hipLaunchKernelGGL(k_lnreduce, dim3(1),    dim3(64),  0, stream, partials, stats);
    hipLaunchKernelGGL(k_prep,     dim3(1),    dim3(128), 0, stream, W1, b1, stats, flag, ck);
    hipLaunchKernelGGL(k_prepW,    dim3(1024), dim3(256), 0, stream,
                       W1, W2, W3, W4, flag, W1bf, W2bf, W3bf, W4bf);

    for (int nBase = 0; nBase < 4; nBase += cnt) {
        hipLaunchKernelGGL(k_fc1_mfma,  dim3(cnt * 512),  dim3(256), 0, stream,
                           x, stats, ck, W1bf, flag, buf2, d_out, nBase);
        hipLaunchKernelGGL(k_transA,    dim3(cnt * 2048), dim3(256), 0, stream, buf2, buf1);
        hipLaunchKernelGGL(k_umix_mfma, dim3(cnt * 512),  dim3(256), 0, stream,
                           buf1, W2bf, b2, flag, buf2);
        hipLaunchKernelGGL(k_vmix_mfma, dim3(cnt * 512),  dim3(256), 0, stream,
                           d_out, W3bf, b3, flag, buf1, nBase);
        hipLaunchKernelGGL(k_fc2_mfma,  dim3(cnt * 1024), dim3(256), 0, stream,
                           buf2, buf1, W4bf, b4, flag, d_out, nBase);
    }
}